// Round 2
// baseline (3317.393 us; speedup 1.0000x reference)
//
#include <hip/hip_runtime.h>
#include <math.h>

// TransFusionHead anchor matching — fp32 pipeline, round 2: parallelism fix.
// conv tiles 32x2 px -> 2160 blocks (was 540) to kill the dispatch tail;
// NMS compacts candidates so topk scans ~36k entries instead of 324k.

#define HW 180
#define NPIX 32400          // 180*180
#define NCLS 10
#define NPROP 200
#define HID 128
#define TDIM 60
#define NBIG (NCLS*NPIX)    // 324000 per batch

// linspace(log(ANCHORS).min()-0.1, log(ANCHORS).max()-0.1, 20), tiled x3
#define TH_LO  (-0.9915981193)
#define TH_STEP (0.1789675812)

__constant__ float c_anchors[10][3] = {
  {4.63f,1.97f,1.74f},{6.93f,2.51f,2.84f},{6.37f,2.85f,3.19f},{10.5f,2.94f,3.47f},
  {12.29f,2.9f,3.87f},{0.5f,2.53f,0.98f},{2.11f,0.77f,1.47f},{1.7f,0.6f,1.28f},
  {0.73f,0.67f,1.77f},{0.41f,0.41f,1.07f}};

// dst[c][t][co] = src[co][c][t]  (zero-pad co >= cout)
__global__ void transpose_w_kernel(const float* __restrict__ src, float* __restrict__ dst,
                                   int cin, int cout, int cobt) {
  int i = blockIdx.x * 256 + threadIdx.x;
  int n = cin * 9 * cobt;
  if (i >= n) return;
  int co = i % cobt;
  int t  = (i / cobt) % 9;
  int c  = i / (cobt * 9);
  dst[i] = (co < cout) ? src[((size_t)co * cin + c) * 9 + t] : 0.f;
}

// 3x3 SAME conv. Tile: 2 rows x 32 cols x 64 couts. 256 thr: co_g=t&15 (4 couts),
// pg=t>>4: colg=pg&7 (4 cols), rowg=pg>>3 (1 row). EPI 0: +bias. EPI 1: relu(x*g+b).
template<int CIN, int EPI>
__global__ __launch_bounds__(256, 4)
void conv3x3_kernel(const float* __restrict__ in, const float* __restrict__ wT,
                    const float* __restrict__ p0, const float* __restrict__ p1,
                    float* __restrict__ out, int cobTot) {
  __shared__ float lds_in[8][4][36];
  const int x0 = blockIdx.x * 32;
  const int y0 = blockIdx.y * 2;
  const int halves = cobTot >> 6;
  const int b   = blockIdx.z / halves;
  const int co0 = (blockIdx.z % halves) * 64;
  const int tid  = threadIdx.x;
  const int co_g = tid & 15;
  const int pg   = tid >> 4;
  const int colg = pg & 7;
  const int rowg = pg >> 3;
  const int pxb  = colg * 4;

  float acc[4][4];
#pragma unroll
  for (int a = 0; a < 4; ++a)
#pragma unroll
    for (int xx = 0; xx < 4; ++xx) acc[a][xx] = 0.f;

  for (int c0 = 0; c0 < CIN; c0 += 8) {
    __syncthreads();
    for (int i = tid; i < 8 * 4 * 36; i += 256) {
      int ch = i / (4 * 36); int rem = i - ch * (4 * 36);
      int r = rem / 36; int xx = rem - r * 36;
      int y = y0 + r - 1; int x = x0 + xx - 1;
      float v = 0.f;
      if ((unsigned)y < (unsigned)HW && (unsigned)x < (unsigned)HW)
        v = in[(((size_t)b * CIN + (c0 + ch)) * HW + y) * HW + x];
      lds_in[ch][r][xx] = v;
    }
    __syncthreads();
    for (int ch = 0; ch < 8; ++ch) {
      float rin[3][6];
#pragma unroll
      for (int rr = 0; rr < 3; ++rr) {
        const float* base = &lds_in[ch][rowg + rr][pxb];
        float4 v4 = *reinterpret_cast<const float4*>(base);
        float2 v2 = *reinterpret_cast<const float2*>(base + 4);
        rin[rr][0] = v4.x; rin[rr][1] = v4.y; rin[rr][2] = v4.z;
        rin[rr][3] = v4.w; rin[rr][4] = v2.x; rin[rr][5] = v2.y;
      }
      const float* wrow = wT + (size_t)(c0 + ch) * 9 * cobTot + co0 + co_g * 4;
#pragma unroll
      for (int t = 0; t < 9; ++t) {
        const float4 w4 = *reinterpret_cast<const float4*>(wrow + (size_t)t * cobTot);
        const int ky = t / 3, kx = t % 3;
#pragma unroll
        for (int xx = 0; xx < 4; ++xx) {
          const float iv = rin[ky][xx + kx];
          acc[0][xx] = fmaf(iv, w4.x, acc[0][xx]);
          acc[1][xx] = fmaf(iv, w4.y, acc[1][xx]);
          acc[2][xx] = fmaf(iv, w4.z, acc[2][xx]);
          acc[3][xx] = fmaf(iv, w4.w, acc[3][xx]);
        }
      }
    }
  }
  const int xbase = x0 + pxb;
  if (xbase >= HW) return;
  const int yout = y0 + rowg;
#pragma unroll
  for (int co = 0; co < 4; ++co) {
    const int c = co0 + co_g * 4 + co;
    const float g0 = p0[c];
    const float g1 = (EPI == 1) ? p1[c] : 0.f;
    float4 vv;
    float* pv = &vv.x;
#pragma unroll
    for (int xx = 0; xx < 4; ++xx) {
      float v = acc[co][xx];
      if (EPI == 0) v = v + g0;
      else { v = fmaf(v, g0, g1); v = fmaxf(v, 0.f); }
      pv[xx] = v;
    }
    *reinterpret_cast<float4*>(out + (((size_t)b * cobTot + c) * HW + yout) * HW + xbase) = vv;
  }
}

// conv3 (128->60 padded 64) fused with threshold-sigmoid, per-pixel L2 norm,
// anchor cosine sim, logit sigmoid. Reduce across the 16 co_g lanes (shfl width 16).
__global__ __launch_bounds__(256, 4)
void conv3_head_kernel(const float* __restrict__ in, const float* __restrict__ wT,
                       const float* __restrict__ b_hm, const float* __restrict__ anchor_vecs,
                       const float* __restrict__ thr_scale, const float* __restrict__ logit_scale,
                       const float* __restrict__ logit_bias, float* __restrict__ heatmap) {
  const int CIN = 128, cobTot = 64;
  __shared__ float lds_in[8][4][36];
  const int x0 = blockIdx.x * 32;
  const int y0 = blockIdx.y * 2;
  const int b  = blockIdx.z;
  const int tid  = threadIdx.x;
  const int co_g = tid & 15;
  const int pg   = tid >> 4;
  const int colg = pg & 7;
  const int rowg = pg >> 3;
  const int pxb  = colg * 4;

  float acc[4][4];
#pragma unroll
  for (int a = 0; a < 4; ++a)
#pragma unroll
    for (int xx = 0; xx < 4; ++xx) acc[a][xx] = 0.f;

  for (int c0 = 0; c0 < CIN; c0 += 8) {
    __syncthreads();
    for (int i = tid; i < 8 * 4 * 36; i += 256) {
      int ch = i / (4 * 36); int rem = i - ch * (4 * 36);
      int r = rem / 36; int xx = rem - r * 36;
      int y = y0 + r - 1; int x = x0 + xx - 1;
      float v = 0.f;
      if ((unsigned)y < (unsigned)HW && (unsigned)x < (unsigned)HW)
        v = in[(((size_t)b * CIN + (c0 + ch)) * HW + y) * HW + x];
      lds_in[ch][r][xx] = v;
    }
    __syncthreads();
    for (int ch = 0; ch < 8; ++ch) {
      float rin[3][6];
#pragma unroll
      for (int rr = 0; rr < 3; ++rr) {
        const float* base = &lds_in[ch][rowg + rr][pxb];
        float4 v4 = *reinterpret_cast<const float4*>(base);
        float2 v2 = *reinterpret_cast<const float2*>(base + 4);
        rin[rr][0] = v4.x; rin[rr][1] = v4.y; rin[rr][2] = v4.z;
        rin[rr][3] = v4.w; rin[rr][4] = v2.x; rin[rr][5] = v2.y;
      }
      const float* wrow = wT + (size_t)(c0 + ch) * 9 * cobTot + co_g * 4;
#pragma unroll
      for (int t = 0; t < 9; ++t) {
        const float4 w4 = *reinterpret_cast<const float4*>(wrow + (size_t)t * cobTot);
        const int ky = t / 3, kx = t % 3;
#pragma unroll
        for (int xx = 0; xx < 4; ++xx) {
          const float iv = rin[ky][xx + kx];
          acc[0][xx] = fmaf(iv, w4.x, acc[0][xx]);
          acc[1][xx] = fmaf(iv, w4.y, acc[1][xx]);
          acc[2][xx] = fmaf(iv, w4.z, acc[2][xx]);
          acc[3][xx] = fmaf(iv, w4.w, acc[3][xx]);
        }
      }
    }
  }

  const int xbase = x0 + pxb;
  if (xbase >= HW) return;   // uniform across each 16-lane shfl group (same pg)
  const int yout = y0 + rowg;

  const int c = co_g * 4;
  float4 a4[10];
#pragma unroll
  for (int k = 0; k < 10; ++k) {
    if (c + 3 < TDIM) a4[k] = *reinterpret_cast<const float4*>(anchor_vecs + k * TDIM + c);
    else a4[k] = make_float4(0.f, 0.f, 0.f, 0.f);
  }
  float bh[4], th[4];
#pragma unroll
  for (int co = 0; co < 4; ++co) {
    int cc = c + co;
    bh[co] = (cc < TDIM) ? b_hm[cc] : 0.f;
    th[co] = (float)(TH_LO + (double)(cc % 20) * TH_STEP);
  }
  const float s  = thr_scale[0];
  const float ls = logit_scale[0];
  const float lb = logit_bias[0];

  float hm4[4];
#pragma unroll
  for (int xx = 0; xx < 4; ++xx) {
    float v[4];
#pragma unroll
    for (int co = 0; co < 4; ++co) {
      if (c + co < TDIM) {
        float z = acc[co][xx] + bh[co];
        float t = (z - th[co]) * s;
        v[co] = 1.f / (1.f + expf(-t));
      } else v[co] = 0.f;
    }
    float s2 = v[0]*v[0] + v[1]*v[1] + v[2]*v[2] + v[3]*v[3];
    float dp[10];
#pragma unroll
    for (int k = 0; k < 10; ++k)
      dp[k] = v[0]*a4[k].x + v[1]*a4[k].y + v[2]*a4[k].z + v[3]*a4[k].w;
#pragma unroll
    for (int off = 1; off < 16; off <<= 1) {
      s2 += __shfl_xor(s2, off, 16);
#pragma unroll
      for (int k = 0; k < 10; ++k) dp[k] += __shfl_xor(dp[k], off, 16);
    }
    float dk = dp[0];
#pragma unroll
    for (int k = 1; k < 10; ++k) if (co_g == k) dk = dp[k];
    float sim = dk / (1e-8f + sqrtf(s2));
    hm4[xx] = 1.f / (1.f + expf(-fmaf(ls, sim, lb)));
  }
  if (co_g < NCLS) {
    float4 vv = make_float4(hm4[0], hm4[1], hm4[2], hm4[3]);
    *reinterpret_cast<float4*>(heatmap + (((size_t)b * NCLS + co_g) * HW + yout) * HW + xbase) = vv;
  }
}

__global__ void sims_kernel(float* __restrict__ out_sims) {
  int t = threadIdx.x;
  if (t < 100) {
    int i = t / 10, j = t % 10;
    float r = 1.f;
#pragma unroll
    for (int d = 0; d < 3; ++d) {
      float ai = c_anchors[i][d], aj = c_anchors[j][d];
      r *= fminf(ai, aj) / fmaxf(ai, aj);
    }
    out_sims[t] = r;
  }
}

// NMS + compaction: survivors (v == 3x3 local max; all heatmap values > 0) are
// appended per-batch via atomicAdd. List order is nondeterministic but the
// downstream radix-select + (key desc, idx asc) sorts are set-deterministic.
__global__ void nms_kernel(const float* __restrict__ hm, float* __restrict__ ckey,
                           int* __restrict__ cidx, int* __restrict__ cnt) {
  int i = blockIdx.x * 256 + threadIdx.x;
  if (i >= 2 * NBIG) return;
  int x = i % HW; int y = (i / HW) % HW; int plane = i / NPIX;
  float v = hm[i];
  float m = v;
#pragma unroll
  for (int dy = -1; dy <= 1; ++dy)
#pragma unroll
    for (int dx = -1; dx <= 1; ++dx) {
      int yy = y + dy, xx = x + dx;
      if ((unsigned)yy < (unsigned)HW && (unsigned)xx < (unsigned)HW)
        m = fmaxf(m, hm[((size_t)plane * NPIX) + yy * HW + xx]);
    }
  if (v == m) {
    int bk = i / NBIG;
    int p = atomicAdd(&cnt[bk], 1);
    ckey[(size_t)bk * NBIG + p] = v;
    cidx[(size_t)bk * NBIG + p] = i - bk * NBIG;
  }
}

// Per-batch exact top-200 over the compacted candidate list (radix select on
// float bits, then bitonic sorts matching jax.lax.top_k order: value desc, idx asc).
__global__ __launch_bounds__(1024)
void topk_kernel(const float* __restrict__ ckey, const int* __restrict__ cidx,
                 const int* __restrict__ cnt, const float* __restrict__ heatmap,
                 const float* __restrict__ bev_pos, float* __restrict__ out,
                 int* __restrict__ iws) {
  const int b = blockIdx.x;
  const int tid = threadIdx.x;
  const float* keys = ckey + (size_t)b * NBIG;
  const int* idxs = cidx + (size_t)b * NBIG;

  __shared__ unsigned hist[256];
  __shared__ unsigned sh_prefix;
  __shared__ int sh_want, sh_n;
  __shared__ int cntGT, cntTie;
  __shared__ unsigned gt_key[256], gt_idx[256];
  __shared__ unsigned tie_idx[2048];

  if (tid == 0) sh_n = cnt[b];
  __syncthreads();
  const int n = sh_n;

  unsigned prefix = 0; int want = NPROP;
  for (int shift = 24; shift >= 0; shift -= 8) {
    if (tid < 256) hist[tid] = 0u;
    __syncthreads();
    for (int i = tid; i < n; i += 1024) {
      unsigned k = __float_as_uint(keys[i]);  // values > 0 -> monotonic bits
      bool match = (shift == 24) || ((k >> (shift + 8)) == (prefix >> (shift + 8)));
      if (match) atomicAdd(&hist[(k >> shift) & 255], 1u);
    }
    __syncthreads();
    if (tid == 0) {
      int cum = 0; int bsel = 0; sh_want = want;
      for (int bin = 255; bin >= 0; --bin) {
        cum += (int)hist[bin];
        if (cum >= want) { bsel = bin; sh_want = want - (cum - (int)hist[bin]); break; }
      }
      sh_prefix = prefix | ((unsigned)bsel << shift);
      cntGT = 0; cntTie = 0;
    }
    __syncthreads();
    prefix = sh_prefix; want = sh_want;
    __syncthreads();
  }
  const unsigned T = prefix;  // key of the 200th largest

  for (int i = tid; i < n; i += 1024) {
    unsigned k = __float_as_uint(keys[i]);
    if (k > T) {
      int p = atomicAdd(&cntGT, 1);
      if (p < 256) { gt_key[p] = k; gt_idx[p] = (unsigned)idxs[i]; }
    } else if (k == T) {
      int p = atomicAdd(&cntTie, 1);
      if (p < 2048) tie_idx[p] = (unsigned)idxs[i];
    }
  }
  __syncthreads();
  const int nGT = min(cntGT, 256);    // radix select guarantees <= 199
  const int nTie = min(cntTie, 2048);

  for (int i = tid; i < 256; i += 1024)
    if (i >= nGT) { gt_key[i] = 0u; gt_idx[i] = 0xFFFFFFFFu; }
  for (int i = tid; i < 2048; i += 1024)
    if (i >= nTie) tie_idx[i] = 0xFFFFFFFFu;
  __syncthreads();

  for (int k2 = 2; k2 <= 256; k2 <<= 1) {
    for (int j = k2 >> 1; j > 0; j >>= 1) {
      for (int i = tid; i < 256; i += 1024) {
        int ixj = i ^ j;
        if (ixj > i) {
          unsigned ka = gt_key[i], kb = gt_key[ixj];
          unsigned ia = gt_idx[i], ib = gt_idx[ixj];
          bool firstA = (ka > kb) || (ka == kb && ia < ib);
          bool up = ((i & k2) == 0);
          if (up ? !firstA : firstA) {
            gt_key[i] = kb; gt_key[ixj] = ka;
            gt_idx[i] = ib; gt_idx[ixj] = ia;
          }
        }
      }
      __syncthreads();
    }
  }
  for (int k2 = 2; k2 <= 2048; k2 <<= 1) {
    for (int j = k2 >> 1; j > 0; j >>= 1) {
      for (int i = tid; i < 2048; i += 1024) {
        int ixj = i ^ j;
        if (ixj > i) {
          unsigned ia = tie_idx[i], ib = tie_idx[ixj];
          bool firstA = ia < ib;
          bool up = ((i & k2) == 0);
          if (up ? !firstA : firstA) { tie_idx[i] = ib; tie_idx[ixj] = ia; }
        }
      }
      __syncthreads();
    }
  }

  for (int r = tid; r < NPROP; r += 1024) {
    unsigned idx; float score;
    if (r < nGT) { idx = gt_idx[r]; score = __uint_as_float(gt_key[r]); }
    else         { idx = tie_idx[r - nGT]; score = __uint_as_float(T); }
    int label = (int)(idx / NPIX);
    int pos = (int)(idx - (unsigned)label * NPIX);
    out[648000 + b * NPROP + r] = score;
    out[648400 + b * NPROP + r] = (float)label;
    out[700000 + (b * NPROP + r) * 2 + 0] = bev_pos[pos * 2 + 0];
    out[700000 + (b * NPROP + r) * 2 + 1] = bev_pos[pos * 2 + 1];
#pragma unroll
    for (int k = 0; k < NCLS; ++k)
      out[700800 + (b * NCLS + k) * NPROP + r] = heatmap[(size_t)(b * NCLS + k) * NPIX + pos];
    iws[b * NPROP + r] = pos;
    iws[2 * NPROP + b * NPROP + r] = label;
  }
}

__global__ void gather_qf_kernel(const float* __restrict__ lidar, const float* __restrict__ w_enc,
                                 const int* __restrict__ iws, float* __restrict__ out_qf) {
  int p = blockIdx.x % NPROP;
  int b = blockIdx.x / NPROP;
  int c = threadIdx.x;
  int pos = iws[b * NPROP + p];
  int label = iws[2 * NPROP + b * NPROP + p];
  float la0 = logf(c_anchors[label][0]);
  float la1 = logf(c_anchors[label][1]);
  float la2 = logf(c_anchors[label][2]);
  float dot = w_enc[c * 3 + 0] * la0 + w_enc[c * 3 + 1] * la1 + w_enc[c * 3 + 2] * la2;
  float g = lidar[((size_t)b * HID + c) * NPIX + pos];
  out_qf[((size_t)b * HID + c) * NPROP + p] = g + dot;
}

extern "C" void kernel_launch(void* const* d_in, const int* in_sizes, int n_in,
                              void* d_out, int out_size, void* d_ws, size_t ws_size,
                              hipStream_t stream) {
  (void)in_sizes; (void)n_in; (void)out_size; (void)ws_size;
  const float* feats       = (const float*)d_in[0];
  const float* w_shared    = (const float*)d_in[1];
  const float* b_shared    = (const float*)d_in[2];
  const float* w_bb        = (const float*)d_in[3];
  const float* gamma_bb    = (const float*)d_in[4];
  const float* beta_bb     = (const float*)d_in[5];
  const float* w_hm        = (const float*)d_in[6];
  const float* b_hm        = (const float*)d_in[7];
  const float* thr_scale   = (const float*)d_in[8];
  const float* logit_scale = (const float*)d_in[9];
  const float* logit_bias  = (const float*)d_in[10];
  const float* w_enc       = (const float*)d_in[11];
  const float* anchor_vecs = (const float*)d_in[12];
  const float* bev_pos     = (const float*)d_in[13];
  float* out = (float*)d_out;

  float* ws = (float*)d_ws;
  size_t off = 0;
  float* lidar = ws + off; off += (size_t)2 * HID * NPIX;   // 8,294,400
  float* xbb   = ws + off; off += (size_t)2 * HID * NPIX;   // 8,294,400
  float* ckey  = ws + off; off += (size_t)2 * NBIG;         //   648,000
  int*   cidx  = (int*)(ws + off); off += (size_t)2 * NBIG; //   648,000
  float* wT1   = ws + off; off += (size_t)512 * 9 * 128;    //   589,824
  float* wT2   = ws + off; off += (size_t)128 * 9 * 128;    //   147,456
  float* wT3   = ws + off; off += (size_t)128 * 9 * 64;     //    73,728
  int*   iws   = (int*)(ws + off); off += 800;              //       800 ints
  int*   cnt   = (int*)(ws + off);                          //         2 ints

  transpose_w_kernel<<<(512*9*128 + 255)/256, 256, 0, stream>>>(w_shared, wT1, 512, 128, 128);
  transpose_w_kernel<<<(128*9*128 + 255)/256, 256, 0, stream>>>(w_bb,     wT2, 128, 128, 128);
  transpose_w_kernel<<<(128*9*64  + 255)/256, 256, 0, stream>>>(w_hm,     wT3, 128,  60,  64);

  dim3 cgrid(6, 90, 4);   // x-tiles(32), y-tiles(2), b*cout-halves
  conv3x3_kernel<512,0><<<cgrid, 256, 0, stream>>>(feats, wT1, b_shared, nullptr, lidar, 128);
  conv3x3_kernel<128,1><<<cgrid, 256, 0, stream>>>(lidar, wT2, gamma_bb, beta_bb, xbb, 128);

  dim3 hgrid(6, 90, 2);
  conv3_head_kernel<<<hgrid, 256, 0, stream>>>(xbb, wT3, b_hm, anchor_vecs,
                                               thr_scale, logit_scale, logit_bias, out);

  sims_kernel<<<1, 128, 0, stream>>>(out + 704800);
  hipMemsetAsync(cnt, 0, 2 * sizeof(int), stream);
  nms_kernel<<<(2*NBIG + 255)/256, 256, 0, stream>>>(out, ckey, cidx, cnt);
  topk_kernel<<<2, 1024, 0, stream>>>(ckey, cidx, cnt, out, bev_pos, out, iws);
  gather_qf_kernel<<<2*NPROP, 128, 0, stream>>>(lidar, w_enc, iws, out + 648800);
}

// Round 3
// 3092.853 us; speedup vs baseline: 1.0726x; 1.0726x over previous
//
#include <hip/hip_runtime.h>
#include <math.h>

// TransFusionHead anchor matching — fp32 pipeline, round 3.
// conv tiles 32x4 px x 64 couts (1080 blocks), per-thread 4co x 8px (32 FMA
// per weight float4), register-staged double-buffered LDS input staging with
// precomputed offsets (no div/mod, no exposed load latency), one barrier/chunk.

#define HW 180
#define NPIX 32400          // 180*180
#define NCLS 10
#define NPROP 200
#define HID 128
#define TDIM 60
#define NBIG (NCLS*NPIX)    // 324000 per batch

// linspace(log(ANCHORS).min()-0.1, log(ANCHORS).max()-0.1, 20), tiled x3
#define TH_LO  (-0.9915981193)
#define TH_STEP (0.1789675812)

__constant__ float c_anchors[10][3] = {
  {4.63f,1.97f,1.74f},{6.93f,2.51f,2.84f},{6.37f,2.85f,3.19f},{10.5f,2.94f,3.47f},
  {12.29f,2.9f,3.87f},{0.5f,2.53f,0.98f},{2.11f,0.77f,1.47f},{1.7f,0.6f,1.28f},
  {0.73f,0.67f,1.77f},{0.41f,0.41f,1.07f}};

// dst[c][t][co] = src[co][c][t]  (zero-pad co >= cout)
__global__ void transpose_w_kernel(const float* __restrict__ src, float* __restrict__ dst,
                                   int cin, int cout, int cobt) {
  int i = blockIdx.x * 256 + threadIdx.x;
  int n = cin * 9 * cobt;
  if (i >= n) return;
  int co = i % cobt;
  int t  = (i / cobt) % 9;
  int c  = i / (cobt * 9);
  dst[i] = (co < cout) ? src[((size_t)co * cin + c) * 9 + t] : 0.f;
}

// Staged LDS tile: 8 ch x 6 rows x 36 cols (34 used), double buffered.
// 1728 floats/chunk -> 7 slots per thread (256 thr).
// Thread map: co_g = tid&15 (4 couts each), pg = tid>>4: colg = pg&3 (8 px),
// rowg = pg>>2 (1 row). acc[4co][8px].

template<int CIN, int EPI>
__global__ __launch_bounds__(256, 4)
void conv3x3_kernel(const float* __restrict__ in, const float* __restrict__ wT,
                    const float* __restrict__ p0, const float* __restrict__ p1,
                    float* __restrict__ out, int cobTot) {
  __shared__ float lds[2][8][6][36];
  const int x0 = blockIdx.x * 32;
  const int y0 = blockIdx.y * 4;
  const int halves = cobTot >> 6;
  const int b   = blockIdx.z / halves;
  const int co0 = (blockIdx.z % halves) * 64;
  const int tid  = threadIdx.x;
  const int co_g = tid & 15;
  const int pg   = tid >> 4;
  const int colg = pg & 3;
  const int rowg = pg >> 2;

  // --- staging setup (invariant across chunks) ---
  unsigned off[7]; bool okf[7];
#pragma unroll
  for (int k = 0; k < 7; ++k) {
    int L = tid + k * 256;
    int ch = L / 216; int rem = L - ch * 216;
    int r = rem / 36; int x = rem - r * 36;
    int y = y0 + r - 1; int gx = x0 + x - 1;
    bool ok = (L < 1728) && ((unsigned)y < (unsigned)HW) && ((unsigned)gx < (unsigned)HW);
    okf[k] = ok;
    off[k] = ok ? (unsigned)(((b * CIN + ch) * HW + y) * HW + gx) : 0u;
  }
  float stg[7];
  // prologue: chunk 0
#pragma unroll
  for (int k = 0; k < 7; ++k) stg[k] = in[off[k]];
  {
    float* pb = &lds[0][0][0][0];
#pragma unroll
    for (int k = 0; k < 7; ++k) {
      int L = tid + k * 256;
      if (L < 1728) pb[L] = okf[k] ? stg[k] : 0.f;
    }
  }
  __syncthreads();

  float acc[4][8];
#pragma unroll
  for (int a = 0; a < 4; ++a)
#pragma unroll
    for (int px = 0; px < 8; ++px) acc[a][px] = 0.f;

  const int CHUNKS = CIN / 8;
  unsigned chunkOff = 0;
  for (int c = 0; c < CHUNKS; ++c) {
    // issue next chunk's global loads (latency hides under compute below)
    if (c + 1 < CHUNKS) {
      chunkOff += 8u * NPIX;
#pragma unroll
      for (int k = 0; k < 7; ++k) stg[k] = in[off[k] + chunkOff];
    }
    // compute current chunk from lds[c&1]
    const float* wbase = wT + (size_t)(c * 8) * 9 * cobTot + co0 + co_g * 4;
    const float* lbase = &lds[c & 1][0][rowg][colg * 8];
    for (int ch = 0; ch < 8; ++ch) {
      float rin[3][10];
#pragma unroll
      for (int rr = 0; rr < 3; ++rr) {
        const float* rp = lbase + ch * (6 * 36) + rr * 36;
        float4 q0 = *reinterpret_cast<const float4*>(rp);
        float4 q1 = *reinterpret_cast<const float4*>(rp + 4);
        float2 q2 = *reinterpret_cast<const float2*>(rp + 8);
        rin[rr][0] = q0.x; rin[rr][1] = q0.y; rin[rr][2] = q0.z; rin[rr][3] = q0.w;
        rin[rr][4] = q1.x; rin[rr][5] = q1.y; rin[rr][6] = q1.z; rin[rr][7] = q1.w;
        rin[rr][8] = q2.x; rin[rr][9] = q2.y;
      }
      const float* wrow = wbase + (size_t)ch * 9 * cobTot;
#pragma unroll
      for (int t = 0; t < 9; ++t) {
        const float4 w4 = *reinterpret_cast<const float4*>(wrow + (size_t)t * cobTot);
        const int ky = t / 3, kx = t % 3;
#pragma unroll
        for (int px = 0; px < 8; ++px) {
          const float iv = rin[ky][px + kx];
          acc[0][px] = fmaf(iv, w4.x, acc[0][px]);
          acc[1][px] = fmaf(iv, w4.y, acc[1][px]);
          acc[2][px] = fmaf(iv, w4.z, acc[2][px]);
          acc[3][px] = fmaf(iv, w4.w, acc[3][px]);
        }
      }
    }
    // write next chunk into the other buffer, one barrier per chunk
    if (c + 1 < CHUNKS) {
      float* pb = &lds[(c + 1) & 1][0][0][0];
#pragma unroll
      for (int k = 0; k < 7; ++k) {
        int L = tid + k * 256;
        if (L < 1728) pb[L] = okf[k] ? stg[k] : 0.f;
      }
      __syncthreads();
    }
  }

  // --- epilogue ---
  const int xb = x0 + colg * 8;
  if (xb >= HW) return;
  const bool full = (xb + 8 <= HW);     // 180 % 8 == 4: partial tile keeps lo half
  const int yo = y0 + rowg;
#pragma unroll
  for (int co = 0; co < 4; ++co) {
    const int cc = co0 + co_g * 4 + co;
    const float g0 = p0[cc];
    const float g1 = (EPI == 1) ? p1[cc] : 0.f;
    float v[8];
#pragma unroll
    for (int px = 0; px < 8; ++px) {
      float z = acc[co][px];
      if (EPI == 0) z = z + g0;
      else { z = fmaf(z, g0, g1); z = fmaxf(z, 0.f); }
      v[px] = z;
    }
    float* op = out + (((size_t)b * cobTot + cc) * HW + yo) * HW + xb;
    *reinterpret_cast<float4*>(op) = make_float4(v[0], v[1], v[2], v[3]);
    if (full) *reinterpret_cast<float4*>(op + 4) = make_float4(v[4], v[5], v[6], v[7]);
  }
}

// conv3 (128->60 padded 64) + threshold-sigmoid + L2-norm + anchor sim + sigmoid.
__global__ __launch_bounds__(256, 4)
void conv3_head_kernel(const float* __restrict__ in, const float* __restrict__ wT,
                       const float* __restrict__ b_hm, const float* __restrict__ anchor_vecs,
                       const float* __restrict__ thr_scale, const float* __restrict__ logit_scale,
                       const float* __restrict__ logit_bias, float* __restrict__ heatmap) {
  const int CIN = 128, cobTot = 64;
  __shared__ float lds[2][8][6][36];
  const int x0 = blockIdx.x * 32;
  const int y0 = blockIdx.y * 4;
  const int b  = blockIdx.z;
  const int tid  = threadIdx.x;
  const int co_g = tid & 15;
  const int pg   = tid >> 4;
  const int colg = pg & 3;
  const int rowg = pg >> 2;

  unsigned off[7]; bool okf[7];
#pragma unroll
  for (int k = 0; k < 7; ++k) {
    int L = tid + k * 256;
    int ch = L / 216; int rem = L - ch * 216;
    int r = rem / 36; int x = rem - r * 36;
    int y = y0 + r - 1; int gx = x0 + x - 1;
    bool ok = (L < 1728) && ((unsigned)y < (unsigned)HW) && ((unsigned)gx < (unsigned)HW);
    okf[k] = ok;
    off[k] = ok ? (unsigned)(((b * CIN + ch) * HW + y) * HW + gx) : 0u;
  }
  float stg[7];
#pragma unroll
  for (int k = 0; k < 7; ++k) stg[k] = in[off[k]];
  {
    float* pb = &lds[0][0][0][0];
#pragma unroll
    for (int k = 0; k < 7; ++k) {
      int L = tid + k * 256;
      if (L < 1728) pb[L] = okf[k] ? stg[k] : 0.f;
    }
  }
  __syncthreads();

  float acc[4][8];
#pragma unroll
  for (int a = 0; a < 4; ++a)
#pragma unroll
    for (int px = 0; px < 8; ++px) acc[a][px] = 0.f;

  const int CHUNKS = CIN / 8;
  unsigned chunkOff = 0;
  for (int c = 0; c < CHUNKS; ++c) {
    if (c + 1 < CHUNKS) {
      chunkOff += 8u * NPIX;
#pragma unroll
      for (int k = 0; k < 7; ++k) stg[k] = in[off[k] + chunkOff];
    }
    const float* wbase = wT + (size_t)(c * 8) * 9 * cobTot + co_g * 4;
    const float* lbase = &lds[c & 1][0][rowg][colg * 8];
    for (int ch = 0; ch < 8; ++ch) {
      float rin[3][10];
#pragma unroll
      for (int rr = 0; rr < 3; ++rr) {
        const float* rp = lbase + ch * (6 * 36) + rr * 36;
        float4 q0 = *reinterpret_cast<const float4*>(rp);
        float4 q1 = *reinterpret_cast<const float4*>(rp + 4);
        float2 q2 = *reinterpret_cast<const float2*>(rp + 8);
        rin[rr][0] = q0.x; rin[rr][1] = q0.y; rin[rr][2] = q0.z; rin[rr][3] = q0.w;
        rin[rr][4] = q1.x; rin[rr][5] = q1.y; rin[rr][6] = q1.z; rin[rr][7] = q1.w;
        rin[rr][8] = q2.x; rin[rr][9] = q2.y;
      }
      const float* wrow = wbase + (size_t)ch * 9 * cobTot;
#pragma unroll
      for (int t = 0; t < 9; ++t) {
        const float4 w4 = *reinterpret_cast<const float4*>(wrow + (size_t)t * cobTot);
        const int ky = t / 3, kx = t % 3;
#pragma unroll
        for (int px = 0; px < 8; ++px) {
          const float iv = rin[ky][px + kx];
          acc[0][px] = fmaf(iv, w4.x, acc[0][px]);
          acc[1][px] = fmaf(iv, w4.y, acc[1][px]);
          acc[2][px] = fmaf(iv, w4.z, acc[2][px]);
          acc[3][px] = fmaf(iv, w4.w, acc[3][px]);
        }
      }
    }
    if (c + 1 < CHUNKS) {
      float* pb = &lds[(c + 1) & 1][0][0][0];
#pragma unroll
      for (int k = 0; k < 7; ++k) {
        int L = tid + k * 256;
        if (L < 1728) pb[L] = okf[k] ? stg[k] : 0.f;
      }
      __syncthreads();
    }
  }

  // ---- fused head epilogue ----
  const int cbase = co_g * 4;
  float4 a4[10];
#pragma unroll
  for (int k = 0; k < 10; ++k) {
    if (cbase + 3 < TDIM) a4[k] = *reinterpret_cast<const float4*>(anchor_vecs + k * TDIM + cbase);
    else a4[k] = make_float4(0.f, 0.f, 0.f, 0.f);
  }
  float bh[4], th[4];
#pragma unroll
  for (int co = 0; co < 4; ++co) {
    int cc = cbase + co;
    bh[co] = (cc < TDIM) ? b_hm[cc] : 0.f;
    th[co] = (float)(TH_LO + (double)(cc % 20) * TH_STEP);
  }
  const float s  = thr_scale[0];
  const float ls = logit_scale[0];
  const float lb = logit_bias[0];

  float hmv[8];
#pragma unroll
  for (int px = 0; px < 8; ++px) {
    float v[4];
#pragma unroll
    for (int co = 0; co < 4; ++co) {
      if (cbase + co < TDIM) {
        float z = acc[co][px] + bh[co];
        float t = (z - th[co]) * s;
        v[co] = 1.f / (1.f + expf(-t));
      } else v[co] = 0.f;
    }
    float s2 = v[0]*v[0] + v[1]*v[1] + v[2]*v[2] + v[3]*v[3];
    float dp[10];
#pragma unroll
    for (int k = 0; k < 10; ++k)
      dp[k] = v[0]*a4[k].x + v[1]*a4[k].y + v[2]*a4[k].z + v[3]*a4[k].w;
#pragma unroll
    for (int o = 1; o < 16; o <<= 1) {
      s2 += __shfl_xor(s2, o, 16);
#pragma unroll
      for (int k = 0; k < 10; ++k) dp[k] += __shfl_xor(dp[k], o, 16);
    }
    float dk = dp[0];
#pragma unroll
    for (int k = 1; k < 10; ++k) if (co_g == k) dk = dp[k];
    float sim = dk / (1e-8f + sqrtf(s2));
    hmv[px] = 1.f / (1.f + expf(-fmaf(ls, sim, lb)));
  }

  const int xb = x0 + colg * 8;
  if (xb >= HW || co_g >= NCLS) return;
  const bool full = (xb + 8 <= HW);
  const int yo = y0 + rowg;
  float* op = heatmap + (((size_t)b * NCLS + co_g) * HW + yo) * HW + xb;
  *reinterpret_cast<float4*>(op) = make_float4(hmv[0], hmv[1], hmv[2], hmv[3]);
  if (full) *reinterpret_cast<float4*>(op + 4) = make_float4(hmv[4], hmv[5], hmv[6], hmv[7]);
}

__global__ void sims_kernel(float* __restrict__ out_sims) {
  int t = threadIdx.x;
  if (t < 100) {
    int i = t / 10, j = t % 10;
    float r = 1.f;
#pragma unroll
    for (int d = 0; d < 3; ++d) {
      float ai = c_anchors[i][d], aj = c_anchors[j][d];
      r *= fminf(ai, aj) / fmaxf(ai, aj);
    }
    out_sims[t] = r;
  }
}

// NMS + compaction: survivors (v == 3x3 local max; heatmap values > 0) appended
// per-batch via atomicAdd. Order nondeterministic; downstream select/sort is
// set-deterministic.
__global__ void nms_kernel(const float* __restrict__ hm, float* __restrict__ ckey,
                           int* __restrict__ cidx, int* __restrict__ cnt) {
  int i = blockIdx.x * 256 + threadIdx.x;
  if (i >= 2 * NBIG) return;
  int x = i % HW; int y = (i / HW) % HW; int plane = i / NPIX;
  float v = hm[i];
  float m = v;
#pragma unroll
  for (int dy = -1; dy <= 1; ++dy)
#pragma unroll
    for (int dx = -1; dx <= 1; ++dx) {
      int yy = y + dy, xx = x + dx;
      if ((unsigned)yy < (unsigned)HW && (unsigned)xx < (unsigned)HW)
        m = fmaxf(m, hm[((size_t)plane * NPIX) + yy * HW + xx]);
    }
  if (v == m) {
    int bk = i / NBIG;
    int p = atomicAdd(&cnt[bk], 1);
    ckey[(size_t)bk * NBIG + p] = v;
    cidx[(size_t)bk * NBIG + p] = i - bk * NBIG;
  }
}

// Per-batch exact top-200 over compacted candidates (radix select on float
// bits, then bitonic sorts matching jax.lax.top_k order: value desc, idx asc).
__global__ __launch_bounds__(1024)
void topk_kernel(const float* __restrict__ ckey, const int* __restrict__ cidx,
                 const int* __restrict__ cnt, const float* __restrict__ heatmap,
                 const float* __restrict__ bev_pos, float* __restrict__ out,
                 int* __restrict__ iws) {
  const int b = blockIdx.x;
  const int tid = threadIdx.x;
  const float* keys = ckey + (size_t)b * NBIG;
  const int* idxs = cidx + (size_t)b * NBIG;

  __shared__ unsigned hist[256];
  __shared__ unsigned sh_prefix;
  __shared__ int sh_want, sh_n;
  __shared__ int cntGT, cntTie;
  __shared__ unsigned gt_key[256], gt_idx[256];
  __shared__ unsigned tie_idx[2048];

  if (tid == 0) sh_n = cnt[b];
  __syncthreads();
  const int n = sh_n;

  unsigned prefix = 0; int want = NPROP;
  for (int shift = 24; shift >= 0; shift -= 8) {
    if (tid < 256) hist[tid] = 0u;
    __syncthreads();
    for (int i = tid; i < n; i += 1024) {
      unsigned k = __float_as_uint(keys[i]);
      bool match = (shift == 24) || ((k >> (shift + 8)) == (prefix >> (shift + 8)));
      if (match) atomicAdd(&hist[(k >> shift) & 255], 1u);
    }
    __syncthreads();
    if (tid == 0) {
      int cum = 0; int bsel = 0; sh_want = want;
      for (int bin = 255; bin >= 0; --bin) {
        cum += (int)hist[bin];
        if (cum >= want) { bsel = bin; sh_want = want - (cum - (int)hist[bin]); break; }
      }
      sh_prefix = prefix | ((unsigned)bsel << shift);
      cntGT = 0; cntTie = 0;
    }
    __syncthreads();
    prefix = sh_prefix; want = sh_want;
    __syncthreads();
  }
  const unsigned T = prefix;

  for (int i = tid; i < n; i += 1024) {
    unsigned k = __float_as_uint(keys[i]);
    if (k > T) {
      int p = atomicAdd(&cntGT, 1);
      if (p < 256) { gt_key[p] = k; gt_idx[p] = (unsigned)idxs[i]; }
    } else if (k == T) {
      int p = atomicAdd(&cntTie, 1);
      if (p < 2048) tie_idx[p] = (unsigned)idxs[i];
    }
  }
  __syncthreads();
  const int nGT = min(cntGT, 256);
  const int nTie = min(cntTie, 2048);

  for (int i = tid; i < 256; i += 1024)
    if (i >= nGT) { gt_key[i] = 0u; gt_idx[i] = 0xFFFFFFFFu; }
  for (int i = tid; i < 2048; i += 1024)
    if (i >= nTie) tie_idx[i] = 0xFFFFFFFFu;
  __syncthreads();

  for (int k2 = 2; k2 <= 256; k2 <<= 1) {
    for (int j = k2 >> 1; j > 0; j >>= 1) {
      for (int i = tid; i < 256; i += 1024) {
        int ixj = i ^ j;
        if (ixj > i) {
          unsigned ka = gt_key[i], kb = gt_key[ixj];
          unsigned ia = gt_idx[i], ib = gt_idx[ixj];
          bool firstA = (ka > kb) || (ka == kb && ia < ib);
          bool up = ((i & k2) == 0);
          if (up ? !firstA : firstA) {
            gt_key[i] = kb; gt_key[ixj] = ka;
            gt_idx[i] = ib; gt_idx[ixj] = ia;
          }
        }
      }
      __syncthreads();
    }
  }
  for (int k2 = 2; k2 <= 2048; k2 <<= 1) {
    for (int j = k2 >> 1; j > 0; j >>= 1) {
      for (int i = tid; i < 2048; i += 1024) {
        int ixj = i ^ j;
        if (ixj > i) {
          unsigned ia = tie_idx[i], ib = tie_idx[ixj];
          bool firstA = ia < ib;
          bool up = ((i & k2) == 0);
          if (up ? !firstA : firstA) { tie_idx[i] = ib; tie_idx[ixj] = ia; }
        }
      }
      __syncthreads();
    }
  }

  for (int r = tid; r < NPROP; r += 1024) {
    unsigned idx; float score;
    if (r < nGT) { idx = gt_idx[r]; score = __uint_as_float(gt_key[r]); }
    else         { idx = tie_idx[r - nGT]; score = __uint_as_float(T); }
    int label = (int)(idx / NPIX);
    int pos = (int)(idx - (unsigned)label * NPIX);
    out[648000 + b * NPROP + r] = score;
    out[648400 + b * NPROP + r] = (float)label;
    out[700000 + (b * NPROP + r) * 2 + 0] = bev_pos[pos * 2 + 0];
    out[700000 + (b * NPROP + r) * 2 + 1] = bev_pos[pos * 2 + 1];
#pragma unroll
    for (int k = 0; k < NCLS; ++k)
      out[700800 + (b * NCLS + k) * NPROP + r] = heatmap[(size_t)(b * NCLS + k) * NPIX + pos];
    iws[b * NPROP + r] = pos;
    iws[2 * NPROP + b * NPROP + r] = label;
  }
}

__global__ void gather_qf_kernel(const float* __restrict__ lidar, const float* __restrict__ w_enc,
                                 const int* __restrict__ iws, float* __restrict__ out_qf) {
  int p = blockIdx.x % NPROP;
  int b = blockIdx.x / NPROP;
  int c = threadIdx.x;
  int pos = iws[b * NPROP + p];
  int label = iws[2 * NPROP + b * NPROP + p];
  float la0 = logf(c_anchors[label][0]);
  float la1 = logf(c_anchors[label][1]);
  float la2 = logf(c_anchors[label][2]);
  float dot = w_enc[c * 3 + 0] * la0 + w_enc[c * 3 + 1] * la1 + w_enc[c * 3 + 2] * la2;
  float g = lidar[((size_t)b * HID + c) * NPIX + pos];
  out_qf[((size_t)b * HID + c) * NPROP + p] = g + dot;
}

extern "C" void kernel_launch(void* const* d_in, const int* in_sizes, int n_in,
                              void* d_out, int out_size, void* d_ws, size_t ws_size,
                              hipStream_t stream) {
  (void)in_sizes; (void)n_in; (void)out_size; (void)ws_size;
  const float* feats       = (const float*)d_in[0];
  const float* w_shared    = (const float*)d_in[1];
  const float* b_shared    = (const float*)d_in[2];
  const float* w_bb        = (const float*)d_in[3];
  const float* gamma_bb    = (const float*)d_in[4];
  const float* beta_bb     = (const float*)d_in[5];
  const float* w_hm        = (const float*)d_in[6];
  const float* b_hm        = (const float*)d_in[7];
  const float* thr_scale   = (const float*)d_in[8];
  const float* logit_scale = (const float*)d_in[9];
  const float* logit_bias  = (const float*)d_in[10];
  const float* w_enc       = (const float*)d_in[11];
  const float* anchor_vecs = (const float*)d_in[12];
  const float* bev_pos     = (const float*)d_in[13];
  float* out = (float*)d_out;

  float* ws = (float*)d_ws;
  size_t off = 0;
  float* lidar = ws + off; off += (size_t)2 * HID * NPIX;   // 8,294,400
  float* xbb   = ws + off; off += (size_t)2 * HID * NPIX;   // 8,294,400
  float* ckey  = ws + off; off += (size_t)2 * NBIG;         //   648,000
  int*   cidx  = (int*)(ws + off); off += (size_t)2 * NBIG; //   648,000
  float* wT1   = ws + off; off += (size_t)512 * 9 * 128;    //   589,824
  float* wT2   = ws + off; off += (size_t)128 * 9 * 128;    //   147,456
  float* wT3   = ws + off; off += (size_t)128 * 9 * 64;     //    73,728
  int*   iws   = (int*)(ws + off); off += 800;              //       800 ints
  int*   cnt   = (int*)(ws + off);                          //         2 ints

  transpose_w_kernel<<<(512*9*128 + 255)/256, 256, 0, stream>>>(w_shared, wT1, 512, 128, 128);
  transpose_w_kernel<<<(128*9*128 + 255)/256, 256, 0, stream>>>(w_bb,     wT2, 128, 128, 128);
  transpose_w_kernel<<<(128*9*64  + 255)/256, 256, 0, stream>>>(w_hm,     wT3, 128,  60,  64);

  dim3 cgrid(6, 45, 4);   // x-tiles(32), y-tiles(4), b*cout-halves
  conv3x3_kernel<512,0><<<cgrid, 256, 0, stream>>>(feats, wT1, b_shared, nullptr, lidar, 128);
  conv3x3_kernel<128,1><<<cgrid, 256, 0, stream>>>(lidar, wT2, gamma_bb, beta_bb, xbb, 128);

  dim3 hgrid(6, 45, 2);
  conv3_head_kernel<<<hgrid, 256, 0, stream>>>(xbb, wT3, b_hm, anchor_vecs,
                                               thr_scale, logit_scale, logit_bias, out);

  sims_kernel<<<1, 128, 0, stream>>>(out + 704800);
  hipMemsetAsync(cnt, 0, 2 * sizeof(int), stream);
  nms_kernel<<<(2*NBIG + 255)/256, 256, 0, stream>>>(out, ckey, cidx, cnt);
  topk_kernel<<<2, 1024, 0, stream>>>(ckey, cidx, cnt, out, bev_pos, out, iws);
  gather_qf_kernel<<<2*NPROP, 128, 0, stream>>>(lidar, w_enc, iws, out + 648800);
}

// Round 4
// 2809.931 us; speedup vs baseline: 1.1806x; 1.1007x over previous
//
#include <hip/hip_runtime.h>
#include <math.h>

// TransFusionHead anchor matching — fp32 pipeline, round 4.
// Key change vs r3: conv weights staged in LDS (double-buffered, 18KB/chunk)
// so waves stop re-pulling 72 KB/chunk of weights through L1 (measured 1:1
// co-limiter with FMA issue -> VALUBusy pinned at 50%). Input tile staging
// unchanged (reg-staged dbuf, one barrier/chunk).

#define HW 180
#define NPIX 32400          // 180*180
#define NCLS 10
#define NPROP 200
#define HID 128
#define TDIM 60
#define NBIG (NCLS*NPIX)    // 324000 per batch

// linspace(log(ANCHORS).min()-0.1, log(ANCHORS).max()-0.1, 20), tiled x3
#define TH_LO  (-0.9915981193)
#define TH_STEP (0.1789675812)

__constant__ float c_anchors[10][3] = {
  {4.63f,1.97f,1.74f},{6.93f,2.51f,2.84f},{6.37f,2.85f,3.19f},{10.5f,2.94f,3.47f},
  {12.29f,2.9f,3.87f},{0.5f,2.53f,0.98f},{2.11f,0.77f,1.47f},{1.7f,0.6f,1.28f},
  {0.73f,0.67f,1.77f},{0.41f,0.41f,1.07f}};

// dst[c][t][co] = src[co][c][t]  (zero-pad co >= cout)
__global__ void transpose_w_kernel(const float* __restrict__ src, float* __restrict__ dst,
                                   int cin, int cout, int cobt) {
  int i = blockIdx.x * 256 + threadIdx.x;
  int n = cin * 9 * cobt;
  if (i >= n) return;
  int co = i % cobt;
  int t  = (i / cobt) % 9;
  int c  = i / (cobt * 9);
  dst[i] = (co < cout) ? src[((size_t)co * cin + c) * 9 + t] : 0.f;
}

// Tile 32x4 px x 64 couts. 256 thr: co_g=tid&15 (4 couts), pg=tid>>4:
// colg=pg&3 (8 px), rowg=pg>>2. acc[4co][8px].
// LDS per buffer: input 8ch x 6r x 36c = 1728 f; weights 8ch x 9t x 64co = 4608 f.
template<int CIN, int EPI>
__global__ __launch_bounds__(256, 3)
void conv3x3_kernel(const float* __restrict__ in, const float* __restrict__ wT,
                    const float* __restrict__ p0, const float* __restrict__ p1,
                    float* __restrict__ out, int cobTot) {
  __shared__ float lds_in[2][1728];
  __shared__ float lds_w[2][4608];
  const int x0 = blockIdx.x * 32;
  const int y0 = blockIdx.y * 4;
  const int halves = cobTot >> 6;
  const int b   = blockIdx.z / halves;
  const int co0 = (blockIdx.z % halves) * 64;
  const int tid  = threadIdx.x;
  const int co_g = tid & 15;
  const int pg   = tid >> 4;
  const int colg = pg & 3;
  const int rowg = pg >> 2;

  // --- input staging map (7 scalar slots/thread) ---
  unsigned off[7]; bool okf[7];
#pragma unroll
  for (int k = 0; k < 7; ++k) {
    int L = tid + k * 256;
    int ch = L / 216; int rem = L - ch * 216;
    int r = rem / 36; int x = rem - r * 36;
    int y = y0 + r - 1; int gx = x0 + x - 1;
    bool ok = (L < 1728) && ((unsigned)y < (unsigned)HW) && ((unsigned)gx < (unsigned)HW);
    okf[k] = ok;
    off[k] = ok ? (unsigned)(((b * CIN + ch) * HW + y) * HW + gx) : 0u;
  }
  // --- weight staging map (5 float4 slots/thread; 1152 f4 per chunk-half) ---
  const float4* w4src = reinterpret_cast<const float4*>(wT);
  unsigned woff[5];
#pragma unroll
  for (int k = 0; k < 5; ++k) {
    int lin = tid + k * 256;
    int ch = lin / 144; int rem = lin - ch * 144;
    int t = rem >> 4; int fc = rem & 15;
    woff[k] = (lin < 1152) ? (unsigned)((ch * 9 + t) * (cobTot >> 2) + (co0 >> 2) + fc) : 0u;
  }
  const unsigned wstride = 18u * (unsigned)cobTot;   // f4 per 8-ch chunk

  // --- prologue: chunk 0 ---
  float stg[7]; float4 wstg[5];
#pragma unroll
  for (int k = 0; k < 7; ++k) stg[k] = in[off[k]];
#pragma unroll
  for (int k = 0; k < 5; ++k) wstg[k] = w4src[woff[k]];
  {
    float* pb = lds_in[0];
#pragma unroll
    for (int k = 0; k < 7; ++k) {
      int L = tid + k * 256;
      if (L < 1728) pb[L] = okf[k] ? stg[k] : 0.f;
    }
    float4* pw = reinterpret_cast<float4*>(lds_w[0]);
#pragma unroll
    for (int k = 0; k < 5; ++k) {
      int lin = tid + k * 256;
      if (lin < 1152) pw[lin] = wstg[k];
    }
  }
  __syncthreads();

  float acc[4][8];
#pragma unroll
  for (int a = 0; a < 4; ++a)
#pragma unroll
    for (int px = 0; px < 8; ++px) acc[a][px] = 0.f;

  const int CHUNKS = CIN / 8;
  unsigned chunkOff = 0;
  for (int c = 0; c < CHUNKS; ++c) {
    // issue next chunk's global loads (hide under compute below)
    if (c + 1 < CHUNKS) {
      chunkOff += 8u * NPIX;
#pragma unroll
      for (int k = 0; k < 7; ++k) stg[k] = in[off[k] + chunkOff];
      const unsigned wbase = (unsigned)(c + 1) * wstride;
#pragma unroll
      for (int k = 0; k < 5; ++k) wstg[k] = w4src[woff[k] + wbase];
    }
    // compute current chunk entirely from LDS
    const float* wch = lds_w[c & 1];
    const float* lbase = lds_in[c & 1] + rowg * 36 + colg * 8;
    for (int ch = 0; ch < 8; ++ch) {
      float rin[3][10];
#pragma unroll
      for (int rr = 0; rr < 3; ++rr) {
        const float* rp = lbase + ch * 216 + rr * 36;
        float4 q0 = *reinterpret_cast<const float4*>(rp);
        float4 q1 = *reinterpret_cast<const float4*>(rp + 4);
        float2 q2 = *reinterpret_cast<const float2*>(rp + 8);
        rin[rr][0] = q0.x; rin[rr][1] = q0.y; rin[rr][2] = q0.z; rin[rr][3] = q0.w;
        rin[rr][4] = q1.x; rin[rr][5] = q1.y; rin[rr][6] = q1.z; rin[rr][7] = q1.w;
        rin[rr][8] = q2.x; rin[rr][9] = q2.y;
      }
      const float* wrow = wch + ch * 576 + co_g * 4;
#pragma unroll
      for (int t = 0; t < 9; ++t) {
        const float4 w4 = *reinterpret_cast<const float4*>(wrow + t * 64);
        const int ky = t / 3, kx = t % 3;
#pragma unroll
        for (int px = 0; px < 8; ++px) {
          const float iv = rin[ky][px + kx];
          acc[0][px] = fmaf(iv, w4.x, acc[0][px]);
          acc[1][px] = fmaf(iv, w4.y, acc[1][px]);
          acc[2][px] = fmaf(iv, w4.z, acc[2][px]);
          acc[3][px] = fmaf(iv, w4.w, acc[3][px]);
        }
      }
    }
    // write next chunk into the other buffers, one barrier per chunk
    if (c + 1 < CHUNKS) {
      float* pb = lds_in[(c + 1) & 1];
#pragma unroll
      for (int k = 0; k < 7; ++k) {
        int L = tid + k * 256;
        if (L < 1728) pb[L] = okf[k] ? stg[k] : 0.f;
      }
      float4* pw = reinterpret_cast<float4*>(lds_w[(c + 1) & 1]);
#pragma unroll
      for (int k = 0; k < 5; ++k) {
        int lin = tid + k * 256;
        if (lin < 1152) pw[lin] = wstg[k];
      }
      __syncthreads();
    }
  }

  // --- epilogue ---
  const int xb = x0 + colg * 8;
  if (xb >= HW) return;
  const bool full = (xb + 8 <= HW);     // 180 % 8 == 4
  const int yo = y0 + rowg;
#pragma unroll
  for (int co = 0; co < 4; ++co) {
    const int cc = co0 + co_g * 4 + co;
    const float g0 = p0[cc];
    const float g1 = (EPI == 1) ? p1[cc] : 0.f;
    float v[8];
#pragma unroll
    for (int px = 0; px < 8; ++px) {
      float z = acc[co][px];
      if (EPI == 0) z = z + g0;
      else { z = fmaf(z, g0, g1); z = fmaxf(z, 0.f); }
      v[px] = z;
    }
    float* op = out + (((size_t)b * cobTot + cc) * HW + yo) * HW + xb;
    *reinterpret_cast<float4*>(op) = make_float4(v[0], v[1], v[2], v[3]);
    if (full) *reinterpret_cast<float4*>(op + 4) = make_float4(v[4], v[5], v[6], v[7]);
  }
}

// conv3 (128->60 padded 64) + threshold-sigmoid + L2-norm + anchor sim + sigmoid.
__global__ __launch_bounds__(256, 3)
void conv3_head_kernel(const float* __restrict__ in, const float* __restrict__ wT,
                       const float* __restrict__ b_hm, const float* __restrict__ anchor_vecs,
                       const float* __restrict__ thr_scale, const float* __restrict__ logit_scale,
                       const float* __restrict__ logit_bias, float* __restrict__ heatmap) {
  const int CIN = 128, cobTot = 64;
  __shared__ float lds_in[2][1728];
  __shared__ float lds_w[2][4608];
  const int x0 = blockIdx.x * 32;
  const int y0 = blockIdx.y * 4;
  const int b  = blockIdx.z;
  const int tid  = threadIdx.x;
  const int co_g = tid & 15;
  const int pg   = tid >> 4;
  const int colg = pg & 3;
  const int rowg = pg >> 2;

  unsigned off[7]; bool okf[7];
#pragma unroll
  for (int k = 0; k < 7; ++k) {
    int L = tid + k * 256;
    int ch = L / 216; int rem = L - ch * 216;
    int r = rem / 36; int x = rem - r * 36;
    int y = y0 + r - 1; int gx = x0 + x - 1;
    bool ok = (L < 1728) && ((unsigned)y < (unsigned)HW) && ((unsigned)gx < (unsigned)HW);
    okf[k] = ok;
    off[k] = ok ? (unsigned)(((b * CIN + ch) * HW + y) * HW + gx) : 0u;
  }
  const float4* w4src = reinterpret_cast<const float4*>(wT);
  unsigned woff[5];
#pragma unroll
  for (int k = 0; k < 5; ++k) {
    int lin = tid + k * 256;
    int ch = lin / 144; int rem = lin - ch * 144;
    int t = rem >> 4; int fc = rem & 15;
    woff[k] = (lin < 1152) ? (unsigned)((ch * 9 + t) * 16 + fc) : 0u;
  }
  const unsigned wstride = 1152u;

  float stg[7]; float4 wstg[5];
#pragma unroll
  for (int k = 0; k < 7; ++k) stg[k] = in[off[k]];
#pragma unroll
  for (int k = 0; k < 5; ++k) wstg[k] = w4src[woff[k]];
  {
    float* pb = lds_in[0];
#pragma unroll
    for (int k = 0; k < 7; ++k) {
      int L = tid + k * 256;
      if (L < 1728) pb[L] = okf[k] ? stg[k] : 0.f;
    }
    float4* pw = reinterpret_cast<float4*>(lds_w[0]);
#pragma unroll
    for (int k = 0; k < 5; ++k) {
      int lin = tid + k * 256;
      if (lin < 1152) pw[lin] = wstg[k];
    }
  }
  __syncthreads();

  float acc[4][8];
#pragma unroll
  for (int a = 0; a < 4; ++a)
#pragma unroll
    for (int px = 0; px < 8; ++px) acc[a][px] = 0.f;

  const int CHUNKS = CIN / 8;
  unsigned chunkOff = 0;
  for (int c = 0; c < CHUNKS; ++c) {
    if (c + 1 < CHUNKS) {
      chunkOff += 8u * NPIX;
#pragma unroll
      for (int k = 0; k < 7; ++k) stg[k] = in[off[k] + chunkOff];
      const unsigned wbase = (unsigned)(c + 1) * wstride;
#pragma unroll
      for (int k = 0; k < 5; ++k) wstg[k] = w4src[woff[k] + wbase];
    }
    const float* wch = lds_w[c & 1];
    const float* lbase = lds_in[c & 1] + rowg * 36 + colg * 8;
    for (int ch = 0; ch < 8; ++ch) {
      float rin[3][10];
#pragma unroll
      for (int rr = 0; rr < 3; ++rr) {
        const float* rp = lbase + ch * 216 + rr * 36;
        float4 q0 = *reinterpret_cast<const float4*>(rp);
        float4 q1 = *reinterpret_cast<const float4*>(rp + 4);
        float2 q2 = *reinterpret_cast<const float2*>(rp + 8);
        rin[rr][0] = q0.x; rin[rr][1] = q0.y; rin[rr][2] = q0.z; rin[rr][3] = q0.w;
        rin[rr][4] = q1.x; rin[rr][5] = q1.y; rin[rr][6] = q1.z; rin[rr][7] = q1.w;
        rin[rr][8] = q2.x; rin[rr][9] = q2.y;
      }
      const float* wrow = wch + ch * 576 + co_g * 4;
#pragma unroll
      for (int t = 0; t < 9; ++t) {
        const float4 w4 = *reinterpret_cast<const float4*>(wrow + t * 64);
        const int ky = t / 3, kx = t % 3;
#pragma unroll
        for (int px = 0; px < 8; ++px) {
          const float iv = rin[ky][px + kx];
          acc[0][px] = fmaf(iv, w4.x, acc[0][px]);
          acc[1][px] = fmaf(iv, w4.y, acc[1][px]);
          acc[2][px] = fmaf(iv, w4.z, acc[2][px]);
          acc[3][px] = fmaf(iv, w4.w, acc[3][px]);
        }
      }
    }
    if (c + 1 < CHUNKS) {
      float* pb = lds_in[(c + 1) & 1];
#pragma unroll
      for (int k = 0; k < 7; ++k) {
        int L = tid + k * 256;
        if (L < 1728) pb[L] = okf[k] ? stg[k] : 0.f;
      }
      float4* pw = reinterpret_cast<float4*>(lds_w[(c + 1) & 1]);
#pragma unroll
      for (int k = 0; k < 5; ++k) {
        int lin = tid + k * 256;
        if (lin < 1152) pw[lin] = wstg[k];
      }
      __syncthreads();
    }
  }

  // ---- fused head epilogue ----
  const int cbase = co_g * 4;
  float4 a4[10];
#pragma unroll
  for (int k = 0; k < 10; ++k) {
    if (cbase + 3 < TDIM) a4[k] = *reinterpret_cast<const float4*>(anchor_vecs + k * TDIM + cbase);
    else a4[k] = make_float4(0.f, 0.f, 0.f, 0.f);
  }
  float bh[4], th[4];
#pragma unroll
  for (int co = 0; co < 4; ++co) {
    int cc = cbase + co;
    bh[co] = (cc < TDIM) ? b_hm[cc] : 0.f;
    th[co] = (float)(TH_LO + (double)(cc % 20) * TH_STEP);
  }
  const float s  = thr_scale[0];
  const float ls = logit_scale[0];
  const float lb = logit_bias[0];

  float hmv[8];
#pragma unroll
  for (int px = 0; px < 8; ++px) {
    float v[4];
#pragma unroll
    for (int co = 0; co < 4; ++co) {
      if (cbase + co < TDIM) {
        float z = acc[co][px] + bh[co];
        float t = (z - th[co]) * s;
        v[co] = 1.f / (1.f + expf(-t));
      } else v[co] = 0.f;
    }
    float s2 = v[0]*v[0] + v[1]*v[1] + v[2]*v[2] + v[3]*v[3];
    float dp[10];
#pragma unroll
    for (int k = 0; k < 10; ++k)
      dp[k] = v[0]*a4[k].x + v[1]*a4[k].y + v[2]*a4[k].z + v[3]*a4[k].w;
#pragma unroll
    for (int o = 1; o < 16; o <<= 1) {
      s2 += __shfl_xor(s2, o, 16);
#pragma unroll
      for (int k = 0; k < 10; ++k) dp[k] += __shfl_xor(dp[k], o, 16);
    }
    float dk = dp[0];
#pragma unroll
    for (int k = 1; k < 10; ++k) if (co_g == k) dk = dp[k];
    float sim = dk / (1e-8f + sqrtf(s2));
    hmv[px] = 1.f / (1.f + expf(-fmaf(ls, sim, lb)));
  }

  const int xb = x0 + colg * 8;
  if (xb >= HW || co_g >= NCLS) return;
  const bool full = (xb + 8 <= HW);
  const int yo = y0 + rowg;
  float* op = heatmap + (((size_t)b * NCLS + co_g) * HW + yo) * HW + xb;
  *reinterpret_cast<float4*>(op) = make_float4(hmv[0], hmv[1], hmv[2], hmv[3]);
  if (full) *reinterpret_cast<float4*>(op + 4) = make_float4(hmv[4], hmv[5], hmv[6], hmv[7]);
}

__global__ void sims_kernel(float* __restrict__ out_sims) {
  int t = threadIdx.x;
  if (t < 100) {
    int i = t / 10, j = t % 10;
    float r = 1.f;
#pragma unroll
    for (int d = 0; d < 3; ++d) {
      float ai = c_anchors[i][d], aj = c_anchors[j][d];
      r *= fminf(ai, aj) / fmaxf(ai, aj);
    }
    out_sims[t] = r;
  }
}

// NMS + compaction: survivors (v == 3x3 local max; heatmap values > 0) appended
// per-batch via atomicAdd. Order nondeterministic; downstream select/sort is
// set-deterministic.
__global__ void nms_kernel(const float* __restrict__ hm, float* __restrict__ ckey,
                           int* __restrict__ cidx, int* __restrict__ cnt) {
  int i = blockIdx.x * 256 + threadIdx.x;
  if (i >= 2 * NBIG) return;
  int x = i % HW; int y = (i / HW) % HW; int plane = i / NPIX;
  float v = hm[i];
  float m = v;
#pragma unroll
  for (int dy = -1; dy <= 1; ++dy)
#pragma unroll
    for (int dx = -1; dx <= 1; ++dx) {
      int yy = y + dy, xx = x + dx;
      if ((unsigned)yy < (unsigned)HW && (unsigned)xx < (unsigned)HW)
        m = fmaxf(m, hm[((size_t)plane * NPIX) + yy * HW + xx]);
    }
  if (v == m) {
    int bk = i / NBIG;
    int p = atomicAdd(&cnt[bk], 1);
    ckey[(size_t)bk * NBIG + p] = v;
    cidx[(size_t)bk * NBIG + p] = i - bk * NBIG;
  }
}

// Per-batch exact top-200 over compacted candidates (radix select on float
// bits, then bitonic sorts matching jax.lax.top_k order: value desc, idx asc).
__global__ __launch_bounds__(1024)
void topk_kernel(const float* __restrict__ ckey, const int* __restrict__ cidx,
                 const int* __restrict__ cnt, const float* __restrict__ heatmap,
                 const float* __restrict__ bev_pos, float* __restrict__ out,
                 int* __restrict__ iws) {
  const int b = blockIdx.x;
  const int tid = threadIdx.x;
  const float* keys = ckey + (size_t)b * NBIG;
  const int* idxs = cidx + (size_t)b * NBIG;

  __shared__ unsigned hist[256];
  __shared__ unsigned sh_prefix;
  __shared__ int sh_want, sh_n;
  __shared__ int cntGT, cntTie;
  __shared__ unsigned gt_key[256], gt_idx[256];
  __shared__ unsigned tie_idx[2048];

  if (tid == 0) sh_n = cnt[b];
  __syncthreads();
  const int n = sh_n;

  unsigned prefix = 0; int want = NPROP;
  for (int shift = 24; shift >= 0; shift -= 8) {
    if (tid < 256) hist[tid] = 0u;
    __syncthreads();
    for (int i = tid; i < n; i += 1024) {
      unsigned k = __float_as_uint(keys[i]);
      bool match = (shift == 24) || ((k >> (shift + 8)) == (prefix >> (shift + 8)));
      if (match) atomicAdd(&hist[(k >> shift) & 255], 1u);
    }
    __syncthreads();
    if (tid == 0) {
      int cum = 0; int bsel = 0; sh_want = want;
      for (int bin = 255; bin >= 0; --bin) {
        cum += (int)hist[bin];
        if (cum >= want) { bsel = bin; sh_want = want - (cum - (int)hist[bin]); break; }
      }
      sh_prefix = prefix | ((unsigned)bsel << shift);
      cntGT = 0; cntTie = 0;
    }
    __syncthreads();
    prefix = sh_prefix; want = sh_want;
    __syncthreads();
  }
  const unsigned T = prefix;

  for (int i = tid; i < n; i += 1024) {
    unsigned k = __float_as_uint(keys[i]);
    if (k > T) {
      int p = atomicAdd(&cntGT, 1);
      if (p < 256) { gt_key[p] = k; gt_idx[p] = (unsigned)idxs[i]; }
    } else if (k == T) {
      int p = atomicAdd(&cntTie, 1);
      if (p < 2048) tie_idx[p] = (unsigned)idxs[i];
    }
  }
  __syncthreads();
  const int nGT = min(cntGT, 256);
  const int nTie = min(cntTie, 2048);

  for (int i = tid; i < 256; i += 1024)
    if (i >= nGT) { gt_key[i] = 0u; gt_idx[i] = 0xFFFFFFFFu; }
  for (int i = tid; i < 2048; i += 1024)
    if (i >= nTie) tie_idx[i] = 0xFFFFFFFFu;
  __syncthreads();

  for (int k2 = 2; k2 <= 256; k2 <<= 1) {
    for (int j = k2 >> 1; j > 0; j >>= 1) {
      for (int i = tid; i < 256; i += 1024) {
        int ixj = i ^ j;
        if (ixj > i) {
          unsigned ka = gt_key[i], kb = gt_key[ixj];
          unsigned ia = gt_idx[i], ib = gt_idx[ixj];
          bool firstA = (ka > kb) || (ka == kb && ia < ib);
          bool up = ((i & k2) == 0);
          if (up ? !firstA : firstA) {
            gt_key[i] = kb; gt_key[ixj] = ka;
            gt_idx[i] = ib; gt_idx[ixj] = ia;
          }
        }
      }
      __syncthreads();
    }
  }
  for (int k2 = 2; k2 <= 2048; k2 <<= 1) {
    for (int j = k2 >> 1; j > 0; j >>= 1) {
      for (int i = tid; i < 2048; i += 1024) {
        int ixj = i ^ j;
        if (ixj > i) {
          unsigned ia = tie_idx[i], ib = tie_idx[ixj];
          bool firstA = ia < ib;
          bool up = ((i & k2) == 0);
          if (up ? !firstA : firstA) { tie_idx[i] = ib; tie_idx[ixj] = ia; }
        }
      }
      __syncthreads();
    }
  }

  for (int r = tid; r < NPROP; r += 1024) {
    unsigned idx; float score;
    if (r < nGT) { idx = gt_idx[r]; score = __uint_as_float(gt_key[r]); }
    else         { idx = tie_idx[r - nGT]; score = __uint_as_float(T); }
    int label = (int)(idx / NPIX);
    int pos = (int)(idx - (unsigned)label * NPIX);
    out[648000 + b * NPROP + r] = score;
    out[648400 + b * NPROP + r] = (float)label;
    out[700000 + (b * NPROP + r) * 2 + 0] = bev_pos[pos * 2 + 0];
    out[700000 + (b * NPROP + r) * 2 + 1] = bev_pos[pos * 2 + 1];
#pragma unroll
    for (int k = 0; k < NCLS; ++k)
      out[700800 + (b * NCLS + k) * NPROP + r] = heatmap[(size_t)(b * NCLS + k) * NPIX + pos];
    iws[b * NPROP + r] = pos;
    iws[2 * NPROP + b * NPROP + r] = label;
  }
}

__global__ void gather_qf_kernel(const float* __restrict__ lidar, const float* __restrict__ w_enc,
                                 const int* __restrict__ iws, float* __restrict__ out_qf) {
  int p = blockIdx.x % NPROP;
  int b = blockIdx.x / NPROP;
  int c = threadIdx.x;
  int pos = iws[b * NPROP + p];
  int label = iws[2 * NPROP + b * NPROP + p];
  float la0 = logf(c_anchors[label][0]);
  float la1 = logf(c_anchors[label][1]);
  float la2 = logf(c_anchors[label][2]);
  float dot = w_enc[c * 3 + 0] * la0 + w_enc[c * 3 + 1] * la1 + w_enc[c * 3 + 2] * la2;
  float g = lidar[((size_t)b * HID + c) * NPIX + pos];
  out_qf[((size_t)b * HID + c) * NPROP + p] = g + dot;
}

extern "C" void kernel_launch(void* const* d_in, const int* in_sizes, int n_in,
                              void* d_out, int out_size, void* d_ws, size_t ws_size,
                              hipStream_t stream) {
  (void)in_sizes; (void)n_in; (void)out_size; (void)ws_size;
  const float* feats       = (const float*)d_in[0];
  const float* w_shared    = (const float*)d_in[1];
  const float* b_shared    = (const float*)d_in[2];
  const float* w_bb        = (const float*)d_in[3];
  const float* gamma_bb    = (const float*)d_in[4];
  const float* beta_bb     = (const float*)d_in[5];
  const float* w_hm        = (const float*)d_in[6];
  const float* b_hm        = (const float*)d_in[7];
  const float* thr_scale   = (const float*)d_in[8];
  const float* logit_scale = (const float*)d_in[9];
  const float* logit_bias  = (const float*)d_in[10];
  const float* w_enc       = (const float*)d_in[11];
  const float* anchor_vecs = (const float*)d_in[12];
  const float* bev_pos     = (const float*)d_in[13];
  float* out = (float*)d_out;

  float* ws = (float*)d_ws;
  size_t off = 0;
  float* lidar = ws + off; off += (size_t)2 * HID * NPIX;   // 8,294,400
  float* xbb   = ws + off; off += (size_t)2 * HID * NPIX;   // 8,294,400
  float* ckey  = ws + off; off += (size_t)2 * NBIG;         //   648,000
  int*   cidx  = (int*)(ws + off); off += (size_t)2 * NBIG; //   648,000
  float* wT1   = ws + off; off += (size_t)512 * 9 * 128;    //   589,824
  float* wT2   = ws + off; off += (size_t)128 * 9 * 128;    //   147,456
  float* wT3   = ws + off; off += (size_t)128 * 9 * 64;     //    73,728
  int*   iws   = (int*)(ws + off); off += 800;              //       800 ints
  int*   cnt   = (int*)(ws + off);                          //         2 ints

  transpose_w_kernel<<<(512*9*128 + 255)/256, 256, 0, stream>>>(w_shared, wT1, 512, 128, 128);
  transpose_w_kernel<<<(128*9*128 + 255)/256, 256, 0, stream>>>(w_bb,     wT2, 128, 128, 128);
  transpose_w_kernel<<<(128*9*64  + 255)/256, 256, 0, stream>>>(w_hm,     wT3, 128,  60,  64);

  dim3 cgrid(6, 45, 4);   // x-tiles(32), y-tiles(4), b*cout-halves
  conv3x3_kernel<512,0><<<cgrid, 256, 0, stream>>>(feats, wT1, b_shared, nullptr, lidar, 128);
  conv3x3_kernel<128,1><<<cgrid, 256, 0, stream>>>(lidar, wT2, gamma_bb, beta_bb, xbb, 128);

  dim3 hgrid(6, 45, 2);
  conv3_head_kernel<<<hgrid, 256, 0, stream>>>(xbb, wT3, b_hm, anchor_vecs,
                                               thr_scale, logit_scale, logit_bias, out);

  sims_kernel<<<1, 128, 0, stream>>>(out + 704800);
  hipMemsetAsync(cnt, 0, 2 * sizeof(int), stream);
  nms_kernel<<<(2*NBIG + 255)/256, 256, 0, stream>>>(out, ckey, cidx, cnt);
  topk_kernel<<<2, 1024, 0, stream>>>(ckey, cidx, cnt, out, bev_pos, out, iws);
  gather_qf_kernel<<<2*NPROP, 128, 0, stream>>>(lidar, w_enc, iws, out + 648800);
}

// Round 5
// 2618.584 us; speedup vs baseline: 1.2669x; 1.0731x over previous
//
#include <hip/hip_runtime.h>
#include <math.h>

// TransFusionHead anchor matching — fp32 pipeline, round 5.
// r4 lesson: register-staged weight dbuf spilled to scratch (WRITE_SIZE 970MB).
// r5: weights staged via __builtin_amdgcn_global_load_lds (direct DMA, no
// VGPRs); weight layout [half][cin][9][64] so each 8-ch chunk slice is a
// contiguous 18KB block. Input tile staging stays reg-based (7 scalars).

#define HW 180
#define NPIX 32400          // 180*180
#define NCLS 10
#define NPROP 200
#define HID 128
#define TDIM 60
#define NBIG (NCLS*NPIX)    // 324000 per batch

// linspace(log(ANCHORS).min()-0.1, log(ANCHORS).max()-0.1, 20), tiled x3
#define TH_LO  (-0.9915981193)
#define TH_STEP (0.1789675812)

__constant__ float c_anchors[10][3] = {
  {4.63f,1.97f,1.74f},{6.93f,2.51f,2.84f},{6.37f,2.85f,3.19f},{10.5f,2.94f,3.47f},
  {12.29f,2.9f,3.87f},{0.5f,2.53f,0.98f},{2.11f,0.77f,1.47f},{1.7f,0.6f,1.28f},
  {0.73f,0.67f,1.77f},{0.41f,0.41f,1.07f}};

// async global->LDS, 16B per lane (wave-uniform LDS base + lane*16)
#define GLD_LDS16(g, l) __builtin_amdgcn_global_load_lds( \
    (__attribute__((address_space(1))) void*)(g), \
    (__attribute__((address_space(3))) void*)(l), 16, 0, 0)

// dst[((h*cin + c)*9 + t)*64 + cq] = src[(h*64+cq)*cin*9 + c*9 + t], 0-padded
__global__ void transpose_w_kernel(const float* __restrict__ src, float* __restrict__ dst,
                                   int cin, int cout, int halves) {
  int i = blockIdx.x * 256 + threadIdx.x;
  int n = halves * cin * 9 * 64;
  if (i >= n) return;
  int cq = i & 63;
  int t  = (i >> 6) % 9;
  int rest = i / (64 * 9);
  int c = rest % cin;
  int h = rest / cin;
  int co = h * 64 + cq;
  dst[i] = (co < cout) ? src[((size_t)co * cin + c) * 9 + t] : 0.f;
}

// Tile 32x4 px x 64 couts. 256 thr: co_g=tid&15 (4 couts), pg=tid>>4:
// colg=pg&3 (8 px), rowg=pg>>2. acc[4co][8px].
// LDS/buf: input 8ch x 6r x 36c = 1728 f; weights 8ch x 9t x 64co = 4608 f (DMA).
template<int CIN, int EPI>
__global__ __launch_bounds__(256, 3)
void conv3x3_kernel(const float* __restrict__ in, const float* __restrict__ wT,
                    const float* __restrict__ p0, const float* __restrict__ p1,
                    float* __restrict__ out, int halves) {
  __shared__ float lds_in[2][1728];
  __shared__ float lds_w[2][4608];
  const int x0 = blockIdx.x * 32;
  const int y0 = blockIdx.y * 4;
  const int b   = blockIdx.z / halves;
  const int half = blockIdx.z % halves;
  const int cobTot = halves * 64;
  const int tid  = threadIdx.x;
  const int co_g = tid & 15;
  const int pg   = tid >> 4;
  const int colg = pg & 3;
  const int rowg = pg >> 2;
  const int wave = tid >> 6;
  const int lane = tid & 63;

  // weight source: contiguous 4608-float slice per chunk for this half
  const float* wTbase = wT + (size_t)half * CIN * 576;   // 576 = 9*64

  // --- input staging map (7 scalar slots/thread) ---
  unsigned off[7]; bool okf[7];
#pragma unroll
  for (int k = 0; k < 7; ++k) {
    int L = tid + k * 256;
    int ch = L / 216; int rem = L - ch * 216;
    int r = rem / 36; int x = rem - r * 36;
    int y = y0 + r - 1; int gx = x0 + x - 1;
    bool ok = (L < 1728) && ((unsigned)y < (unsigned)HW) && ((unsigned)gx < (unsigned)HW);
    okf[k] = ok;
    off[k] = ok ? (unsigned)(((b * CIN + ch) * HW + y) * HW + gx) : 0u;
  }

  // --- prologue: chunk 0 ---
  float stg[7];
#pragma unroll
  for (int k = 0; k < 7; ++k) stg[k] = in[off[k]];
  // weight DMA chunk 0: 18 segs x 1024B; wave w does segs w, w+4, ...
#pragma unroll
  for (int i = 0; i < 5; ++i) {
    int s = wave + (i << 2);
    if (s < 18) GLD_LDS16(wTbase + s * 256 + lane * 4, &lds_w[0][s * 256]);
  }
  {
    float* pb = lds_in[0];
#pragma unroll
    for (int k = 0; k < 7; ++k) {
      int L = tid + k * 256;
      if (L < 1728) pb[L] = okf[k] ? stg[k] : 0.f;
    }
  }
  __syncthreads();   // drains vmcnt (DMA) + lgkm

  float acc[4][8];
#pragma unroll
  for (int a = 0; a < 4; ++a)
#pragma unroll
    for (int px = 0; px < 8; ++px) acc[a][px] = 0.f;

  const int CHUNKS = CIN / 8;
  unsigned chunkOff = 0;
  for (int c = 0; c < CHUNKS; ++c) {
    // issue next chunk's loads (hide under compute below)
    if (c + 1 < CHUNKS) {
      chunkOff += 8u * NPIX;
#pragma unroll
      for (int k = 0; k < 7; ++k) stg[k] = in[off[k] + chunkOff];
      const float* gw = wTbase + (size_t)(c + 1) * 4608;
      float* lw = lds_w[(c + 1) & 1];
#pragma unroll
      for (int i = 0; i < 5; ++i) {
        int s = wave + (i << 2);
        if (s < 18) GLD_LDS16(gw + s * 256 + lane * 4, lw + s * 256);
      }
    }
    // compute current chunk entirely from LDS
    const float* wch = lds_w[c & 1];
    const float* lbase = lds_in[c & 1] + rowg * 36 + colg * 8;
    for (int ch = 0; ch < 8; ++ch) {
      float rin[3][10];
#pragma unroll
      for (int rr = 0; rr < 3; ++rr) {
        const float* rp = lbase + ch * 216 + rr * 36;
        float4 q0 = *reinterpret_cast<const float4*>(rp);
        float4 q1 = *reinterpret_cast<const float4*>(rp + 4);
        float2 q2 = *reinterpret_cast<const float2*>(rp + 8);
        rin[rr][0] = q0.x; rin[rr][1] = q0.y; rin[rr][2] = q0.z; rin[rr][3] = q0.w;
        rin[rr][4] = q1.x; rin[rr][5] = q1.y; rin[rr][6] = q1.z; rin[rr][7] = q1.w;
        rin[rr][8] = q2.x; rin[rr][9] = q2.y;
      }
      const float* wrow = wch + ch * 576 + co_g * 4;
#pragma unroll
      for (int t = 0; t < 9; ++t) {
        const float4 w4 = *reinterpret_cast<const float4*>(wrow + t * 64);
        const int ky = t / 3, kx = t % 3;
#pragma unroll
        for (int px = 0; px < 8; ++px) {
          const float iv = rin[ky][px + kx];
          acc[0][px] = fmaf(iv, w4.x, acc[0][px]);
          acc[1][px] = fmaf(iv, w4.y, acc[1][px]);
          acc[2][px] = fmaf(iv, w4.z, acc[2][px]);
          acc[3][px] = fmaf(iv, w4.w, acc[3][px]);
        }
      }
    }
    // write next input chunk into the other buffer, one barrier per chunk
    if (c + 1 < CHUNKS) {
      float* pb = lds_in[(c + 1) & 1];
#pragma unroll
      for (int k = 0; k < 7; ++k) {
        int L = tid + k * 256;
        if (L < 1728) pb[L] = okf[k] ? stg[k] : 0.f;
      }
      __syncthreads();   // waits DMA (vmcnt 0) + ds_writes, then barrier
    }
  }

  // --- epilogue ---
  const int xb = x0 + colg * 8;
  if (xb >= HW) return;
  const bool full = (xb + 8 <= HW);     // 180 % 8 == 4
  const int yo = y0 + rowg;
#pragma unroll
  for (int co = 0; co < 4; ++co) {
    const int cc = half * 64 + co_g * 4 + co;
    const float g0 = p0[cc];
    const float g1 = (EPI == 1) ? p1[cc] : 0.f;
    float v[8];
#pragma unroll
    for (int px = 0; px < 8; ++px) {
      float z = acc[co][px];
      if (EPI == 0) z = z + g0;
      else { z = fmaf(z, g0, g1); z = fmaxf(z, 0.f); }
      v[px] = z;
    }
    float* op = out + (((size_t)b * cobTot + cc) * HW + yo) * HW + xb;
    *reinterpret_cast<float4*>(op) = make_float4(v[0], v[1], v[2], v[3]);
    if (full) *reinterpret_cast<float4*>(op + 4) = make_float4(v[4], v[5], v[6], v[7]);
  }
}

// conv3 (128->60 padded 64) + threshold-sigmoid + L2-norm + anchor sim + sigmoid.
__global__ __launch_bounds__(256, 3)
void conv3_head_kernel(const float* __restrict__ in, const float* __restrict__ wT,
                       const float* __restrict__ b_hm, const float* __restrict__ anchor_vecs,
                       const float* __restrict__ thr_scale, const float* __restrict__ logit_scale,
                       const float* __restrict__ logit_bias, float* __restrict__ heatmap) {
  const int CIN = 128;
  __shared__ float lds_in[2][1728];
  __shared__ float lds_w[2][4608];
  const int x0 = blockIdx.x * 32;
  const int y0 = blockIdx.y * 4;
  const int b  = blockIdx.z;
  const int tid  = threadIdx.x;
  const int co_g = tid & 15;
  const int pg   = tid >> 4;
  const int colg = pg & 3;
  const int rowg = pg >> 2;
  const int wave = tid >> 6;
  const int lane = tid & 63;

  unsigned off[7]; bool okf[7];
#pragma unroll
  for (int k = 0; k < 7; ++k) {
    int L = tid + k * 256;
    int ch = L / 216; int rem = L - ch * 216;
    int r = rem / 36; int x = rem - r * 36;
    int y = y0 + r - 1; int gx = x0 + x - 1;
    bool ok = (L < 1728) && ((unsigned)y < (unsigned)HW) && ((unsigned)gx < (unsigned)HW);
    okf[k] = ok;
    off[k] = ok ? (unsigned)(((b * CIN + ch) * HW + y) * HW + gx) : 0u;
  }

  float stg[7];
#pragma unroll
  for (int k = 0; k < 7; ++k) stg[k] = in[off[k]];
#pragma unroll
  for (int i = 0; i < 5; ++i) {
    int s = wave + (i << 2);
    if (s < 18) GLD_LDS16(wT + s * 256 + lane * 4, &lds_w[0][s * 256]);
  }
  {
    float* pb = lds_in[0];
#pragma unroll
    for (int k = 0; k < 7; ++k) {
      int L = tid + k * 256;
      if (L < 1728) pb[L] = okf[k] ? stg[k] : 0.f;
    }
  }
  __syncthreads();

  float acc[4][8];
#pragma unroll
  for (int a = 0; a < 4; ++a)
#pragma unroll
    for (int px = 0; px < 8; ++px) acc[a][px] = 0.f;

  const int CHUNKS = CIN / 8;
  unsigned chunkOff = 0;
  for (int c = 0; c < CHUNKS; ++c) {
    if (c + 1 < CHUNKS) {
      chunkOff += 8u * NPIX;
#pragma unroll
      for (int k = 0; k < 7; ++k) stg[k] = in[off[k] + chunkOff];
      const float* gw = wT + (size_t)(c + 1) * 4608;
      float* lw = lds_w[(c + 1) & 1];
#pragma unroll
      for (int i = 0; i < 5; ++i) {
        int s = wave + (i << 2);
        if (s < 18) GLD_LDS16(gw + s * 256 + lane * 4, lw + s * 256);
      }
    }
    const float* wch = lds_w[c & 1];
    const float* lbase = lds_in[c & 1] + rowg * 36 + colg * 8;
    for (int ch = 0; ch < 8; ++ch) {
      float rin[3][10];
#pragma unroll
      for (int rr = 0; rr < 3; ++rr) {
        const float* rp = lbase + ch * 216 + rr * 36;
        float4 q0 = *reinterpret_cast<const float4*>(rp);
        float4 q1 = *reinterpret_cast<const float4*>(rp + 4);
        float2 q2 = *reinterpret_cast<const float2*>(rp + 8);
        rin[rr][0] = q0.x; rin[rr][1] = q0.y; rin[rr][2] = q0.z; rin[rr][3] = q0.w;
        rin[rr][4] = q1.x; rin[rr][5] = q1.y; rin[rr][6] = q1.z; rin[rr][7] = q1.w;
        rin[rr][8] = q2.x; rin[rr][9] = q2.y;
      }
      const float* wrow = wch + ch * 576 + co_g * 4;
#pragma unroll
      for (int t = 0; t < 9; ++t) {
        const float4 w4 = *reinterpret_cast<const float4*>(wrow + t * 64);
        const int ky = t / 3, kx = t % 3;
#pragma unroll
        for (int px = 0; px < 8; ++px) {
          const float iv = rin[ky][px + kx];
          acc[0][px] = fmaf(iv, w4.x, acc[0][px]);
          acc[1][px] = fmaf(iv, w4.y, acc[1][px]);
          acc[2][px] = fmaf(iv, w4.z, acc[2][px]);
          acc[3][px] = fmaf(iv, w4.w, acc[3][px]);
        }
      }
    }
    if (c + 1 < CHUNKS) {
      float* pb = lds_in[(c + 1) & 1];
#pragma unroll
      for (int k = 0; k < 7; ++k) {
        int L = tid + k * 256;
        if (L < 1728) pb[L] = okf[k] ? stg[k] : 0.f;
      }
      __syncthreads();
    }
  }

  // ---- fused head epilogue ----
  const int cbase = co_g * 4;
  float4 a4[10];
#pragma unroll
  for (int k = 0; k < 10; ++k) {
    if (cbase + 3 < TDIM) a4[k] = *reinterpret_cast<const float4*>(anchor_vecs + k * TDIM + cbase);
    else a4[k] = make_float4(0.f, 0.f, 0.f, 0.f);
  }
  float bh[4], th[4];
#pragma unroll
  for (int co = 0; co < 4; ++co) {
    int cc = cbase + co;
    bh[co] = (cc < TDIM) ? b_hm[cc] : 0.f;
    th[co] = (float)(TH_LO + (double)(cc % 20) * TH_STEP);
  }
  const float s  = thr_scale[0];
  const float ls = logit_scale[0];
  const float lb = logit_bias[0];

  float hmv[8];
#pragma unroll
  for (int px = 0; px < 8; ++px) {
    float v[4];
#pragma unroll
    for (int co = 0; co < 4; ++co) {
      if (cbase + co < TDIM) {
        float z = acc[co][px] + bh[co];
        float t = (z - th[co]) * s;
        v[co] = 1.f / (1.f + expf(-t));
      } else v[co] = 0.f;
    }
    float s2 = v[0]*v[0] + v[1]*v[1] + v[2]*v[2] + v[3]*v[3];
    float dp[10];
#pragma unroll
    for (int k = 0; k < 10; ++k)
      dp[k] = v[0]*a4[k].x + v[1]*a4[k].y + v[2]*a4[k].z + v[3]*a4[k].w;
#pragma unroll
    for (int o = 1; o < 16; o <<= 1) {
      s2 += __shfl_xor(s2, o, 16);
#pragma unroll
      for (int k = 0; k < 10; ++k) dp[k] += __shfl_xor(dp[k], o, 16);
    }
    float dk = dp[0];
#pragma unroll
    for (int k = 1; k < 10; ++k) if (co_g == k) dk = dp[k];
    float sim = dk / (1e-8f + sqrtf(s2));
    hmv[px] = 1.f / (1.f + expf(-fmaf(ls, sim, lb)));
  }

  const int xb = x0 + colg * 8;
  if (xb >= HW || co_g >= NCLS) return;
  const bool full = (xb + 8 <= HW);
  const int yo = y0 + rowg;
  float* op = heatmap + (((size_t)b * NCLS + co_g) * HW + yo) * HW + xb;
  *reinterpret_cast<float4*>(op) = make_float4(hmv[0], hmv[1], hmv[2], hmv[3]);
  if (full) *reinterpret_cast<float4*>(op + 4) = make_float4(hmv[4], hmv[5], hmv[6], hmv[7]);
}

__global__ void sims_kernel(float* __restrict__ out_sims) {
  int t = threadIdx.x;
  if (t < 100) {
    int i = t / 10, j = t % 10;
    float r = 1.f;
#pragma unroll
    for (int d = 0; d < 3; ++d) {
      float ai = c_anchors[i][d], aj = c_anchors[j][d];
      r *= fminf(ai, aj) / fmaxf(ai, aj);
    }
    out_sims[t] = r;
  }
}

// NMS + compaction: survivors (v == 3x3 local max; heatmap values > 0) appended
// per-batch via atomicAdd. Order nondeterministic; downstream select/sort is
// set-deterministic.
__global__ void nms_kernel(const float* __restrict__ hm, float* __restrict__ ckey,
                           int* __restrict__ cidx, int* __restrict__ cnt) {
  int i = blockIdx.x * 256 + threadIdx.x;
  if (i >= 2 * NBIG) return;
  int x = i % HW; int y = (i / HW) % HW; int plane = i / NPIX;
  float v = hm[i];
  float m = v;
#pragma unroll
  for (int dy = -1; dy <= 1; ++dy)
#pragma unroll
    for (int dx = -1; dx <= 1; ++dx) {
      int yy = y + dy, xx = x + dx;
      if ((unsigned)yy < (unsigned)HW && (unsigned)xx < (unsigned)HW)
        m = fmaxf(m, hm[((size_t)plane * NPIX) + yy * HW + xx]);
    }
  if (v == m) {
    int bk = i / NBIG;
    int p = atomicAdd(&cnt[bk], 1);
    ckey[(size_t)bk * NBIG + p] = v;
    cidx[(size_t)bk * NBIG + p] = i - bk * NBIG;
  }
}

// Per-batch exact top-200 over compacted candidates (radix select on float
// bits, then bitonic sorts matching jax.lax.top_k order: value desc, idx asc).
__global__ __launch_bounds__(1024)
void topk_kernel(const float* __restrict__ ckey, const int* __restrict__ cidx,
                 const int* __restrict__ cnt, const float* __restrict__ heatmap,
                 const float* __restrict__ bev_pos, float* __restrict__ out,
                 int* __restrict__ iws) {
  const int b = blockIdx.x;
  const int tid = threadIdx.x;
  const float* keys = ckey + (size_t)b * NBIG;
  const int* idxs = cidx + (size_t)b * NBIG;

  __shared__ unsigned hist[256];
  __shared__ unsigned sh_prefix;
  __shared__ int sh_want, sh_n;
  __shared__ int cntGT, cntTie;
  __shared__ unsigned gt_key[256], gt_idx[256];
  __shared__ unsigned tie_idx[2048];

  if (tid == 0) sh_n = cnt[b];
  __syncthreads();
  const int n = sh_n;

  unsigned prefix = 0; int want = NPROP;
  for (int shift = 24; shift >= 0; shift -= 8) {
    if (tid < 256) hist[tid] = 0u;
    __syncthreads();
    for (int i = tid; i < n; i += 1024) {
      unsigned k = __float_as_uint(keys[i]);
      bool match = (shift == 24) || ((k >> (shift + 8)) == (prefix >> (shift + 8)));
      if (match) atomicAdd(&hist[(k >> shift) & 255], 1u);
    }
    __syncthreads();
    if (tid == 0) {
      int cum = 0; int bsel = 0; sh_want = want;
      for (int bin = 255; bin >= 0; --bin) {
        cum += (int)hist[bin];
        if (cum >= want) { bsel = bin; sh_want = want - (cum - (int)hist[bin]); break; }
      }
      sh_prefix = prefix | ((unsigned)bsel << shift);
      cntGT = 0; cntTie = 0;
    }
    __syncthreads();
    prefix = sh_prefix; want = sh_want;
    __syncthreads();
  }
  const unsigned T = prefix;

  for (int i = tid; i < n; i += 1024) {
    unsigned k = __float_as_uint(keys[i]);
    if (k > T) {
      int p = atomicAdd(&cntGT, 1);
      if (p < 256) { gt_key[p] = k; gt_idx[p] = (unsigned)idxs[i]; }
    } else if (k == T) {
      int p = atomicAdd(&cntTie, 1);
      if (p < 2048) tie_idx[p] = (unsigned)idxs[i];
    }
  }
  __syncthreads();
  const int nGT = min(cntGT, 256);
  const int nTie = min(cntTie, 2048);

  for (int i = tid; i < 256; i += 1024)
    if (i >= nGT) { gt_key[i] = 0u; gt_idx[i] = 0xFFFFFFFFu; }
  for (int i = tid; i < 2048; i += 1024)
    if (i >= nTie) tie_idx[i] = 0xFFFFFFFFu;
  __syncthreads();

  for (int k2 = 2; k2 <= 256; k2 <<= 1) {
    for (int j = k2 >> 1; j > 0; j >>= 1) {
      for (int i = tid; i < 256; i += 1024) {
        int ixj = i ^ j;
        if (ixj > i) {
          unsigned ka = gt_key[i], kb = gt_key[ixj];
          unsigned ia = gt_idx[i], ib = gt_idx[ixj];
          bool firstA = (ka > kb) || (ka == kb && ia < ib);
          bool up = ((i & k2) == 0);
          if (up ? !firstA : firstA) {
            gt_key[i] = kb; gt_key[ixj] = ka;
            gt_idx[i] = ib; gt_idx[ixj] = ia;
          }
        }
      }
      __syncthreads();
    }
  }
  for (int k2 = 2; k2 <= 2048; k2 <<= 1) {
    for (int j = k2 >> 1; j > 0; j >>= 1) {
      for (int i = tid; i < 2048; i += 1024) {
        int ixj = i ^ j;
        if (ixj > i) {
          unsigned ia = tie_idx[i], ib = tie_idx[ixj];
          bool firstA = ia < ib;
          bool up = ((i & k2) == 0);
          if (up ? !firstA : firstA) { tie_idx[i] = ib; tie_idx[ixj] = ia; }
        }
      }
      __syncthreads();
    }
  }

  for (int r = tid; r < NPROP; r += 1024) {
    unsigned idx; float score;
    if (r < nGT) { idx = gt_idx[r]; score = __uint_as_float(gt_key[r]); }
    else         { idx = tie_idx[r - nGT]; score = __uint_as_float(T); }
    int label = (int)(idx / NPIX);
    int pos = (int)(idx - (unsigned)label * NPIX);
    out[648000 + b * NPROP + r] = score;
    out[648400 + b * NPROP + r] = (float)label;
    out[700000 + (b * NPROP + r) * 2 + 0] = bev_pos[pos * 2 + 0];
    out[700000 + (b * NPROP + r) * 2 + 1] = bev_pos[pos * 2 + 1];
#pragma unroll
    for (int k = 0; k < NCLS; ++k)
      out[700800 + (b * NCLS + k) * NPROP + r] = heatmap[(size_t)(b * NCLS + k) * NPIX + pos];
    iws[b * NPROP + r] = pos;
    iws[2 * NPROP + b * NPROP + r] = label;
  }
}

__global__ void gather_qf_kernel(const float* __restrict__ lidar, const float* __restrict__ w_enc,
                                 const int* __restrict__ iws, float* __restrict__ out_qf) {
  int p = blockIdx.x % NPROP;
  int b = blockIdx.x / NPROP;
  int c = threadIdx.x;
  int pos = iws[b * NPROP + p];
  int label = iws[2 * NPROP + b * NPROP + p];
  float la0 = logf(c_anchors[label][0]);
  float la1 = logf(c_anchors[label][1]);
  float la2 = logf(c_anchors[label][2]);
  float dot = w_enc[c * 3 + 0] * la0 + w_enc[c * 3 + 1] * la1 + w_enc[c * 3 + 2] * la2;
  float g = lidar[((size_t)b * HID + c) * NPIX + pos];
  out_qf[((size_t)b * HID + c) * NPROP + p] = g + dot;
}

extern "C" void kernel_launch(void* const* d_in, const int* in_sizes, int n_in,
                              void* d_out, int out_size, void* d_ws, size_t ws_size,
                              hipStream_t stream) {
  (void)in_sizes; (void)n_in; (void)out_size; (void)ws_size;
  const float* feats       = (const float*)d_in[0];
  const float* w_shared    = (const float*)d_in[1];
  const float* b_shared    = (const float*)d_in[2];
  const float* w_bb        = (const float*)d_in[3];
  const float* gamma_bb    = (const float*)d_in[4];
  const float* beta_bb     = (const float*)d_in[5];
  const float* w_hm        = (const float*)d_in[6];
  const float* b_hm        = (const float*)d_in[7];
  const float* thr_scale   = (const float*)d_in[8];
  const float* logit_scale = (const float*)d_in[9];
  const float* logit_bias  = (const float*)d_in[10];
  const float* w_enc       = (const float*)d_in[11];
  const float* anchor_vecs = (const float*)d_in[12];
  const float* bev_pos     = (const float*)d_in[13];
  float* out = (float*)d_out;

  float* ws = (float*)d_ws;
  size_t off = 0;
  float* lidar = ws + off; off += (size_t)2 * HID * NPIX;   // 8,294,400
  float* xbb   = ws + off; off += (size_t)2 * HID * NPIX;   // 8,294,400
  float* ckey  = ws + off; off += (size_t)2 * NBIG;         //   648,000
  int*   cidx  = (int*)(ws + off); off += (size_t)2 * NBIG; //   648,000
  float* wT1   = ws + off; off += (size_t)512 * 9 * 128;    //   589,824
  float* wT2   = ws + off; off += (size_t)128 * 9 * 128;    //   147,456
  float* wT3   = ws + off; off += (size_t)128 * 9 * 64;     //    73,728
  int*   iws   = (int*)(ws + off); off += 800;              //       800 ints
  int*   cnt   = (int*)(ws + off);                          //         2 ints

  transpose_w_kernel<<<(512*9*128 + 255)/256, 256, 0, stream>>>(w_shared, wT1, 512, 128, 2);
  transpose_w_kernel<<<(128*9*128 + 255)/256, 256, 0, stream>>>(w_bb,     wT2, 128, 128, 2);
  transpose_w_kernel<<<(128*9*64  + 255)/256, 256, 0, stream>>>(w_hm,     wT3, 128,  60, 1);

  dim3 cgrid(6, 45, 4);   // x-tiles(32), y-tiles(4), b*half
  conv3x3_kernel<512,0><<<cgrid, 256, 0, stream>>>(feats, wT1, b_shared, nullptr, lidar, 2);
  conv3x3_kernel<128,1><<<cgrid, 256, 0, stream>>>(lidar, wT2, gamma_bb, beta_bb, xbb, 2);

  dim3 hgrid(6, 45, 2);
  conv3_head_kernel<<<hgrid, 256, 0, stream>>>(xbb, wT3, b_hm, anchor_vecs,
                                               thr_scale, logit_scale, logit_bias, out);

  sims_kernel<<<1, 128, 0, stream>>>(out + 704800);
  hipMemsetAsync(cnt, 0, 2 * sizeof(int), stream);
  nms_kernel<<<(2*NBIG + 255)/256, 256, 0, stream>>>(out, ckey, cidx, cnt);
  topk_kernel<<<2, 1024, 0, stream>>>(ckey, cidx, cnt, out, bev_pos, out, iws);
  gather_qf_kernel<<<2*NPROP, 128, 0, stream>>>(lidar, w_enc, iws, out + 648800);
}

// Round 6
// 1755.746 us; speedup vs baseline: 1.8894x; 1.4914x over previous
//
#include <hip/hip_runtime.h>
#include <math.h>

// TransFusionHead anchor matching — round 6: split-fp16 MFMA convs.
// conv1/conv2 via mfma_f32_16x16x32_f16 with 2-way fp16 split (3 MFMA per
// logical fp32 MFMA, rep err 2^-22). Activations in NHWC-32chunk hi/lo f16
// planes (linear global_load_lds DMA); weights prepacked in A-frag order.
// conv3+head / NMS / topk / gathers unchanged from r5.

#define HW 180
#define NPIX 32400
#define NCLS 10
#define NPROP 200
#define HID 128
#define TDIM 60
#define NBIG (NCLS*NPIX)

#define TH_LO  (-0.9915981193)
#define TH_STEP (0.1789675812)

__constant__ float c_anchors[10][3] = {
  {4.63f,1.97f,1.74f},{6.93f,2.51f,2.84f},{6.37f,2.85f,3.19f},{10.5f,2.94f,3.47f},
  {12.29f,2.9f,3.87f},{0.5f,2.53f,0.98f},{2.11f,0.77f,1.47f},{1.7f,0.6f,1.28f},
  {0.73f,0.67f,1.77f},{0.41f,0.41f,1.07f}};

using f16x8 = _Float16 __attribute__((ext_vector_type(8)));
using f16x4 = _Float16 __attribute__((ext_vector_type(4)));
using f32x4 = float    __attribute__((ext_vector_type(4)));

#define GLD_LDS16(g, l) __builtin_amdgcn_global_load_lds( \
    (__attribute__((address_space(1))) void*)(g), \
    (__attribute__((address_space(3))) void*)(l), 16, 0, 0)

// ---------- conv3 weight transpose (unchanged r5 layout, halves=1) ----------
__global__ void transpose_w_kernel(const float* __restrict__ src, float* __restrict__ dst,
                                   int cin, int cout, int halves) {
  int i = blockIdx.x * 256 + threadIdx.x;
  int n = halves * cin * 9 * 64;
  if (i >= n) return;
  int cq = i & 63;
  int t  = (i >> 6) % 9;
  int rest = i / (64 * 9);
  int c = rest % cin;
  int h = rest / cin;
  int co = h * 64 + cq;
  dst[i] = (co < cout) ? src[((size_t)co * cin + c) * 9 + t] : 0.f;
}

// ---------- MFMA weight prepack: [h][ks][t][mf][lane][8] hi plane + lo plane ----------
template<int CIN, int KS>
__global__ void transpose_w_mfma(const float* __restrict__ w, _Float16* __restrict__ Whi) {
  const int N = 2 * KS * 9 * 4 * 512;
  int i = blockIdx.x * 256 + threadIdx.x;
  if (i >= N) return;
  int j = i & 7, lane = (i >> 3) & 63, mf = (i >> 9) & 3;
  int r = i >> 11;
  int t = r % 9; r /= 9;
  int ks = r % KS; int h = r / KS;
  int co = h * 64 + mf * 16 + (lane & 15);
  int ch = ks * 32 + (lane >> 4) * 8 + j;
  float v = w[((size_t)co * CIN + ch) * 9 + t];
  _Float16 hi = (_Float16)v;
  Whi[i] = hi;
  Whi[N + i] = (_Float16)(v - (float)hi);
}

// ---------- feats fp32 NCHW -> X1 hi/lo f16 [b][16ks][px][32] ----------
__global__ __launch_bounds__(256)
void convert_feats(const float* __restrict__ feats, _Float16* __restrict__ X1) {
  int px = blockIdx.x * 256 + threadIdx.x;
  int b = blockIdx.y >> 4, ks = blockIdx.y & 15;
  if (px >= NPIX) return;
  const float* src = feats + ((size_t)(b * 512 + ks * 32)) * NPIX + px;
  float v[32];
#pragma unroll
  for (int c = 0; c < 32; ++c) v[c] = src[(size_t)c * NPIX];
  f16x8 hv[4], lv[4];
#pragma unroll
  for (int c = 0; c < 32; ++c) {
    _Float16 h = (_Float16)v[c];
    hv[c >> 3][c & 7] = h;
    lv[c >> 3][c & 7] = (_Float16)(v[c] - (float)h);
  }
  size_t ob = ((size_t)(b * 16 + ks) * NPIX + px) * 32;
#pragma unroll
  for (int i = 0; i < 4; ++i) {
    *(f16x8*)(X1 + ob + i * 8) = hv[i];
    *(f16x8*)(X1 + 33177600u + ob + i * 8) = lv[i];
  }
}

// ---------- split-fp16 MFMA conv3x3 ----------
// Block: 16x16 px tile, 64 couts (half h). 4 waves; wave w: rows 4w..4w+3,
// 4 m-frags x 4 n-frags. LDS: 18x18 px x 32ch hi+lo (41.5 KB), single buffer.
// EPI0: +bias -> lidar NHWC f32 + X2 hi/lo.  EPI1: relu(x*g+b) -> xbb NCHW f32.
template<int KS, int EPI>
__global__ __launch_bounds__(256, 2)
void conv_mfma(const _Float16* __restrict__ X, const _Float16* __restrict__ W,
               const float* __restrict__ p0, const float* __restrict__ p1,
               float* __restrict__ out0, _Float16* __restrict__ outX) {
  constexpr unsigned XPS = 2u * KS * NPIX * 32;   // f16 per plane
  constexpr unsigned WPS = 2u * KS * 9 * 4 * 512;
  __shared__ _Float16 lds_x[20736];               // hi [0,10368), lo [10368,20736)

  const int x0 = blockIdx.x * 16;
  const int y0 = blockIdx.y * 16;
  const int b  = blockIdx.z >> 1;
  const int h  = blockIdx.z & 1;
  const int tid = threadIdx.x;
  const int wave = tid >> 6;
  const int lane = tid & 63;
  const int xl = lane & 15, kg = lane >> 4;

  // zero LDS once (OOB halo slots stay zero; DMA masks never write them)
  {
    unsigned* p = (unsigned*)lds_x;
    for (int i = tid; i < 10368; i += 256) p[i] = 0u;
  }

  // staging map: 2592 16B-chunks (hi 1296 + lo 1296), 41 wave-insts, wave w
  // handles insts w,w+4,... ; lane of inst i covers chunk 64i+lane.
  unsigned offs[11]; unsigned okbits = 0;
#pragma unroll
  for (int s = 0; s < 11; ++s) {
    int inst = wave + 4 * s;
    int c = inst * 64 + lane;
    bool valid = (inst < 41) && (c < 2592);
    int plane = (c >= 1296) ? 1 : 0;
    int cc = c - plane * 1296;
    int px = cc >> 2, q = cc & 3;
    int r = px / 18, xx = px - r * 18;
    int gy = y0 - 1 + r, gx = x0 - 1 + xx;
    bool ok = valid && ((unsigned)gy < 180u) && ((unsigned)gx < 180u);
    offs[s] = ok ? ((unsigned)((b * KS) * NPIX + gy * 180 + gx) * 32u + (unsigned)q * 8u
                    + (unsigned)plane * XPS) : 0u;
    okbits |= (ok ? 1u : 0u) << s;
  }

  f32x4 acc[4][4];
#pragma unroll
  for (int mf = 0; mf < 4; ++mf)
#pragma unroll
    for (int f = 0; f < 4; ++f) acc[mf][f] = (f32x4){0.f, 0.f, 0.f, 0.f};

  for (int ks = 0; ks < KS; ++ks) {
    __syncthreads();                       // prior compute done before overwrite
    const unsigned kof = (unsigned)ks * (NPIX * 32u);
#pragma unroll
    for (int s = 0; s < 11; ++s) {
      if (okbits & (1u << s))
        GLD_LDS16(X + (size_t)(offs[s] + kof), lds_x + (wave + 4 * s) * 512);
    }
    __syncthreads();                       // drains vmcnt(0): tile ready

    const _Float16* wks = W + (size_t)((h * KS + ks) * 9) * 2048 + lane * 8;
#pragma unroll
    for (int t = 0; t < 9; ++t) {
      const int ky = t / 3, kx = t % 3;
      f16x8 bh[4], bl[4];
#pragma unroll
      for (int f = 0; f < 4; ++f) {
        int R = 4 * wave + f;
        int lo = ((R + ky) * 18 + xl + kx) * 32 + kg * 8;
        bh[f] = *(const f16x8*)(lds_x + lo);
        bl[f] = *(const f16x8*)(lds_x + 10368 + lo);
      }
      const _Float16* wt = wks + (size_t)t * 2048;
      f16x8 ah[4], al[4];
#pragma unroll
      for (int mf = 0; mf < 4; ++mf) {
        ah[mf] = *(const f16x8*)(wt + mf * 512);
        al[mf] = *(const f16x8*)(wt + WPS + mf * 512);
      }
#pragma unroll
      for (int mf = 0; mf < 4; ++mf)
#pragma unroll
        for (int f = 0; f < 4; ++f) {
          acc[mf][f] = __builtin_amdgcn_mfma_f32_16x16x32_f16(ah[mf], bh[f], acc[mf][f], 0, 0, 0);
          acc[mf][f] = __builtin_amdgcn_mfma_f32_16x16x32_f16(ah[mf], bl[f], acc[mf][f], 0, 0, 0);
          acc[mf][f] = __builtin_amdgcn_mfma_f32_16x16x32_f16(al[mf], bh[f], acc[mf][f], 0, 0, 0);
        }
    }
  }

  // ---- epilogue: C frag col=lane&15 (pixel x), row=kg*4+r (cout) ----
  const int x = x0 + xl;
  if (x >= HW) return;
#pragma unroll
  for (int mf = 0; mf < 4; ++mf) {
    const int cobase = h * 64 + mf * 16 + kg * 4;
    f32x4 q0 = *(const f32x4*)(p0 + cobase);
    f32x4 q1 = (EPI == 1) ? *(const f32x4*)(p1 + cobase) : (f32x4){0.f,0.f,0.f,0.f};
#pragma unroll
    for (int f = 0; f < 4; ++f) {
      const int y = y0 + 4 * wave + f;
      if (y >= HW) continue;
      if (EPI == 0) {
        f32x4 v;
        f16x4 h4, l4;
#pragma unroll
        for (int r = 0; r < 4; ++r) {
          float z = acc[mf][f][r] + q0[r];
          v[r] = z;
          _Float16 hh = (_Float16)z;
          h4[r] = hh;
          l4[r] = (_Float16)(z - (float)hh);
        }
        const int kso = cobase >> 5, c32 = cobase & 31;
        size_t nidx = ((size_t)(b * 4 + kso) * NPIX + (size_t)y * 180 + x) * 32 + c32;
        *(f32x4*)(out0 + nidx) = v;
        *(f16x4*)(outX + nidx) = h4;
        *(f16x4*)(outX + 8294400u + nidx) = l4;
      } else {
#pragma unroll
        for (int r = 0; r < 4; ++r) {
          float z = fmaf(acc[mf][f][r], q0[r], q1[r]);
          z = fmaxf(z, 0.f);
          out0[((size_t)(b * 128 + cobase + r)) * NPIX + (size_t)y * 180 + x] = z;
        }
      }
    }
  }
}

// ---------- conv3 (128->60 pad 64) + head, fp32 (unchanged from r5) ----------
__global__ __launch_bounds__(256, 3)
void conv3_head_kernel(const float* __restrict__ in, const float* __restrict__ wT,
                       const float* __restrict__ b_hm, const float* __restrict__ anchor_vecs,
                       const float* __restrict__ thr_scale, const float* __restrict__ logit_scale,
                       const float* __restrict__ logit_bias, float* __restrict__ heatmap) {
  const int CIN = 128;
  __shared__ float lds_in[2][1728];
  __shared__ float lds_w[2][4608];
  const int x0 = blockIdx.x * 32;
  const int y0 = blockIdx.y * 4;
  const int b  = blockIdx.z;
  const int tid  = threadIdx.x;
  const int co_g = tid & 15;
  const int pg   = tid >> 4;
  const int colg = pg & 3;
  const int rowg = pg >> 2;
  const int wave = tid >> 6;
  const int lane = tid & 63;

  unsigned off[7]; bool okf[7];
#pragma unroll
  for (int k = 0; k < 7; ++k) {
    int L = tid + k * 256;
    int ch = L / 216; int rem = L - ch * 216;
    int r = rem / 36; int x = rem - r * 36;
    int y = y0 + r - 1; int gx = x0 + x - 1;
    bool ok = (L < 1728) && ((unsigned)y < (unsigned)HW) && ((unsigned)gx < (unsigned)HW);
    okf[k] = ok;
    off[k] = ok ? (unsigned)(((b * CIN + ch) * HW + y) * HW + gx) : 0u;
  }

  float stg[7];
#pragma unroll
  for (int k = 0; k < 7; ++k) stg[k] = in[off[k]];
#pragma unroll
  for (int i = 0; i < 5; ++i) {
    int s = wave + (i << 2);
    if (s < 18) GLD_LDS16(wT + s * 256 + lane * 4, &lds_w[0][s * 256]);
  }
  {
    float* pb = lds_in[0];
#pragma unroll
    for (int k = 0; k < 7; ++k) {
      int L = tid + k * 256;
      if (L < 1728) pb[L] = okf[k] ? stg[k] : 0.f;
    }
  }
  __syncthreads();

  float acc[4][8];
#pragma unroll
  for (int a = 0; a < 4; ++a)
#pragma unroll
    for (int px = 0; px < 8; ++px) acc[a][px] = 0.f;

  const int CHUNKS = CIN / 8;
  unsigned chunkOff = 0;
  for (int c = 0; c < CHUNKS; ++c) {
    if (c + 1 < CHUNKS) {
      chunkOff += 8u * NPIX;
#pragma unroll
      for (int k = 0; k < 7; ++k) stg[k] = in[off[k] + chunkOff];
      const float* gw = wT + (size_t)(c + 1) * 4608;
      float* lw = lds_w[(c + 1) & 1];
#pragma unroll
      for (int i = 0; i < 5; ++i) {
        int s = wave + (i << 2);
        if (s < 18) GLD_LDS16(gw + s * 256 + lane * 4, lw + s * 256);
      }
    }
    const float* wch = lds_w[c & 1];
    const float* lbase = lds_in[c & 1] + rowg * 36 + colg * 8;
    for (int ch = 0; ch < 8; ++ch) {
      float rin[3][10];
#pragma unroll
      for (int rr = 0; rr < 3; ++rr) {
        const float* rp = lbase + ch * 216 + rr * 36;
        float4 q0 = *reinterpret_cast<const float4*>(rp);
        float4 q1 = *reinterpret_cast<const float4*>(rp + 4);
        float2 q2 = *reinterpret_cast<const float2*>(rp + 8);
        rin[rr][0] = q0.x; rin[rr][1] = q0.y; rin[rr][2] = q0.z; rin[rr][3] = q0.w;
        rin[rr][4] = q1.x; rin[rr][5] = q1.y; rin[rr][6] = q1.z; rin[rr][7] = q1.w;
        rin[rr][8] = q2.x; rin[rr][9] = q2.y;
      }
      const float* wrow = wch + ch * 576 + co_g * 4;
#pragma unroll
      for (int t = 0; t < 9; ++t) {
        const float4 w4 = *reinterpret_cast<const float4*>(wrow + t * 64);
        const int ky = t / 3, kx = t % 3;
#pragma unroll
        for (int px = 0; px < 8; ++px) {
          const float iv = rin[ky][px + kx];
          acc[0][px] = fmaf(iv, w4.x, acc[0][px]);
          acc[1][px] = fmaf(iv, w4.y, acc[1][px]);
          acc[2][px] = fmaf(iv, w4.z, acc[2][px]);
          acc[3][px] = fmaf(iv, w4.w, acc[3][px]);
        }
      }
    }
    if (c + 1 < CHUNKS) {
      float* pb = lds_in[(c + 1) & 1];
#pragma unroll
      for (int k = 0; k < 7; ++k) {
        int L = tid + k * 256;
        if (L < 1728) pb[L] = okf[k] ? stg[k] : 0.f;
      }
      __syncthreads();
    }
  }

  const int cbase = co_g * 4;
  float4 a4[10];
#pragma unroll
  for (int k = 0; k < 10; ++k) {
    if (cbase + 3 < TDIM) a4[k] = *reinterpret_cast<const float4*>(anchor_vecs + k * TDIM + cbase);
    else a4[k] = make_float4(0.f, 0.f, 0.f, 0.f);
  }
  float bh[4], th[4];
#pragma unroll
  for (int co = 0; co < 4; ++co) {
    int cc = cbase + co;
    bh[co] = (cc < TDIM) ? b_hm[cc] : 0.f;
    th[co] = (float)(TH_LO + (double)(cc % 20) * TH_STEP);
  }
  const float s  = thr_scale[0];
  const float ls = logit_scale[0];
  const float lb = logit_bias[0];

  float hmv[8];
#pragma unroll
  for (int px = 0; px < 8; ++px) {
    float v[4];
#pragma unroll
    for (int co = 0; co < 4; ++co) {
      if (cbase + co < TDIM) {
        float z = acc[co][px] + bh[co];
        float t = (z - th[co]) * s;
        v[co] = 1.f / (1.f + expf(-t));
      } else v[co] = 0.f;
    }
    float s2 = v[0]*v[0] + v[1]*v[1] + v[2]*v[2] + v[3]*v[3];
    float dp[10];
#pragma unroll
    for (int k = 0; k < 10; ++k)
      dp[k] = v[0]*a4[k].x + v[1]*a4[k].y + v[2]*a4[k].z + v[3]*a4[k].w;
#pragma unroll
    for (int o = 1; o < 16; o <<= 1) {
      s2 += __shfl_xor(s2, o, 16);
#pragma unroll
      for (int k = 0; k < 10; ++k) dp[k] += __shfl_xor(dp[k], o, 16);
    }
    float dk = dp[0];
#pragma unroll
    for (int k = 1; k < 10; ++k) if (co_g == k) dk = dp[k];
    float sim = dk / (1e-8f + sqrtf(s2));
    hmv[px] = 1.f / (1.f + expf(-fmaf(ls, sim, lb)));
  }

  const int xb = x0 + colg * 8;
  if (xb >= HW || co_g >= NCLS) return;
  const bool full = (xb + 8 <= HW);
  const int yo = y0 + rowg;
  float* op = heatmap + (((size_t)b * NCLS + co_g) * HW + yo) * HW + xb;
  *reinterpret_cast<float4*>(op) = make_float4(hmv[0], hmv[1], hmv[2], hmv[3]);
  if (full) *reinterpret_cast<float4*>(op + 4) = make_float4(hmv[4], hmv[5], hmv[6], hmv[7]);
}

__global__ void sims_kernel(float* __restrict__ out_sims) {
  int t = threadIdx.x;
  if (t < 100) {
    int i = t / 10, j = t % 10;
    float r = 1.f;
#pragma unroll
    for (int d = 0; d < 3; ++d) {
      float ai = c_anchors[i][d], aj = c_anchors[j][d];
      r *= fminf(ai, aj) / fmaxf(ai, aj);
    }
    out_sims[t] = r;
  }
}

__global__ void nms_kernel(const float* __restrict__ hm, float* __restrict__ ckey,
                           int* __restrict__ cidx, int* __restrict__ cnt) {
  int i = blockIdx.x * 256 + threadIdx.x;
  if (i >= 2 * NBIG) return;
  int x = i % HW; int y = (i / HW) % HW; int plane = i / NPIX;
  float v = hm[i];
  float m = v;
#pragma unroll
  for (int dy = -1; dy <= 1; ++dy)
#pragma unroll
    for (int dx = -1; dx <= 1; ++dx) {
      int yy = y + dy, xx = x + dx;
      if ((unsigned)yy < (unsigned)HW && (unsigned)xx < (unsigned)HW)
        m = fmaxf(m, hm[((size_t)plane * NPIX) + yy * HW + xx]);
    }
  if (v == m) {
    int bk = i / NBIG;
    int p = atomicAdd(&cnt[bk], 1);
    ckey[(size_t)bk * NBIG + p] = v;
    cidx[(size_t)bk * NBIG + p] = i - bk * NBIG;
  }
}

__global__ __launch_bounds__(1024)
void topk_kernel(const float* __restrict__ ckey, const int* __restrict__ cidx,
                 const int* __restrict__ cnt, const float* __restrict__ heatmap,
                 const float* __restrict__ bev_pos, float* __restrict__ out,
                 int* __restrict__ iws) {
  const int b = blockIdx.x;
  const int tid = threadIdx.x;
  const float* keys = ckey + (size_t)b * NBIG;
  const int* idxs = cidx + (size_t)b * NBIG;

  __shared__ unsigned hist[256];
  __shared__ unsigned sh_prefix;
  __shared__ int sh_want, sh_n;
  __shared__ int cntGT, cntTie;
  __shared__ unsigned gt_key[256], gt_idx[256];
  __shared__ unsigned tie_idx[2048];

  if (tid == 0) sh_n = cnt[b];
  __syncthreads();
  const int n = sh_n;

  unsigned prefix = 0; int want = NPROP;
  for (int shift = 24; shift >= 0; shift -= 8) {
    if (tid < 256) hist[tid] = 0u;
    __syncthreads();
    for (int i = tid; i < n; i += 1024) {
      unsigned k = __float_as_uint(keys[i]);
      bool match = (shift == 24) || ((k >> (shift + 8)) == (prefix >> (shift + 8)));
      if (match) atomicAdd(&hist[(k >> shift) & 255], 1u);
    }
    __syncthreads();
    if (tid == 0) {
      int cum = 0; int bsel = 0; sh_want = want;
      for (int bin = 255; bin >= 0; --bin) {
        cum += (int)hist[bin];
        if (cum >= want) { bsel = bin; sh_want = want - (cum - (int)hist[bin]); break; }
      }
      sh_prefix = prefix | ((unsigned)bsel << shift);
      cntGT = 0; cntTie = 0;
    }
    __syncthreads();
    prefix = sh_prefix; want = sh_want;
    __syncthreads();
  }
  const unsigned T = prefix;

  for (int i = tid; i < n; i += 1024) {
    unsigned k = __float_as_uint(keys[i]);
    if (k > T) {
      int p = atomicAdd(&cntGT, 1);
      if (p < 256) { gt_key[p] = k; gt_idx[p] = (unsigned)idxs[i]; }
    } else if (k == T) {
      int p = atomicAdd(&cntTie, 1);
      if (p < 2048) tie_idx[p] = (unsigned)idxs[i];
    }
  }
  __syncthreads();
  const int nGT = min(cntGT, 256);
  const int nTie = min(cntTie, 2048);

  for (int i = tid; i < 256; i += 1024)
    if (i >= nGT) { gt_key[i] = 0u; gt_idx[i] = 0xFFFFFFFFu; }
  for (int i = tid; i < 2048; i += 1024)
    if (i >= nTie) tie_idx[i] = 0xFFFFFFFFu;
  __syncthreads();

  for (int k2 = 2; k2 <= 256; k2 <<= 1) {
    for (int j = k2 >> 1; j > 0; j >>= 1) {
      for (int i = tid; i < 256; i += 1024) {
        int ixj = i ^ j;
        if (ixj > i) {
          unsigned ka = gt_key[i], kb = gt_key[ixj];
          unsigned ia = gt_idx[i], ib = gt_idx[ixj];
          bool firstA = (ka > kb) || (ka == kb && ia < ib);
          bool up = ((i & k2) == 0);
          if (up ? !firstA : firstA) {
            gt_key[i] = kb; gt_key[ixj] = ka;
            gt_idx[i] = ib; gt_idx[ixj] = ia;
          }
        }
      }
      __syncthreads();
    }
  }
  for (int k2 = 2; k2 <= 2048; k2 <<= 1) {
    for (int j = k2 >> 1; j > 0; j >>= 1) {
      for (int i = tid; i < 2048; i += 1024) {
        int ixj = i ^ j;
        if (ixj > i) {
          unsigned ia = tie_idx[i], ib = tie_idx[ixj];
          bool firstA = ia < ib;
          bool up = ((i & k2) == 0);
          if (up ? !firstA : firstA) { tie_idx[i] = ib; tie_idx[ixj] = ia; }
        }
      }
      __syncthreads();
    }
  }

  for (int r = tid; r < NPROP; r += 1024) {
    unsigned idx; float score;
    if (r < nGT) { idx = gt_idx[r]; score = __uint_as_float(gt_key[r]); }
    else         { idx = tie_idx[r - nGT]; score = __uint_as_float(T); }
    int label = (int)(idx / NPIX);
    int pos = (int)(idx - (unsigned)label * NPIX);
    out[648000 + b * NPROP + r] = score;
    out[648400 + b * NPROP + r] = (float)label;
    out[700000 + (b * NPROP + r) * 2 + 0] = bev_pos[pos * 2 + 0];
    out[700000 + (b * NPROP + r) * 2 + 1] = bev_pos[pos * 2 + 1];
#pragma unroll
    for (int k = 0; k < NCLS; ++k)
      out[700800 + (b * NCLS + k) * NPROP + r] = heatmap[(size_t)(b * NCLS + k) * NPIX + pos];
    iws[b * NPROP + r] = pos;
    iws[2 * NPROP + b * NPROP + r] = label;
  }
}

// lidar is NHWC-chunked fp32: [b][4][px][32]
__global__ void gather_qf_kernel(const float* __restrict__ lidar, const float* __restrict__ w_enc,
                                 const int* __restrict__ iws, float* __restrict__ out_qf) {
  int p = blockIdx.x % NPROP;
  int b = blockIdx.x / NPROP;
  int c = threadIdx.x;
  int pos = iws[b * NPROP + p];
  int label = iws[2 * NPROP + b * NPROP + p];
  float la0 = logf(c_anchors[label][0]);
  float la1 = logf(c_anchors[label][1]);
  float la2 = logf(c_anchors[label][2]);
  float dot = w_enc[c * 3 + 0] * la0 + w_enc[c * 3 + 1] * la1 + w_enc[c * 3 + 2] * la2;
  float g = lidar[((size_t)(b * 4 + (c >> 5)) * NPIX + pos) * 32 + (c & 31)];
  out_qf[((size_t)b * HID + c) * NPROP + p] = g + dot;
}

extern "C" void kernel_launch(void* const* d_in, const int* in_sizes, int n_in,
                              void* d_out, int out_size, void* d_ws, size_t ws_size,
                              hipStream_t stream) {
  (void)in_sizes; (void)n_in; (void)out_size; (void)ws_size;
  const float* feats       = (const float*)d_in[0];
  const float* w_shared    = (const float*)d_in[1];
  const float* b_shared    = (const float*)d_in[2];
  const float* w_bb        = (const float*)d_in[3];
  const float* gamma_bb    = (const float*)d_in[4];
  const float* beta_bb     = (const float*)d_in[5];
  const float* w_hm        = (const float*)d_in[6];
  const float* b_hm        = (const float*)d_in[7];
  const float* thr_scale   = (const float*)d_in[8];
  const float* logit_scale = (const float*)d_in[9];
  const float* logit_bias  = (const float*)d_in[10];
  const float* w_enc       = (const float*)d_in[11];
  const float* anchor_vecs = (const float*)d_in[12];
  const float* bev_pos     = (const float*)d_in[13];
  float* out = (float*)d_out;

  float* ws = (float*)d_ws;
  size_t off = 0;
  _Float16* X1 = (_Float16*)(ws + off); off += 33177600;   // 2 planes x 33.18M f16
  _Float16* X2 = (_Float16*)(ws + off); off += 8294400;    // 2 planes x 8.29M f16
  float* lidarN = ws + off; off += 8294400;                // NHWC fp32
  float* xbb    = ws + off; off += 8294400;                // NCHW fp32
  _Float16* W1 = (_Float16*)(ws + off); off += 589824;     // 2 planes x 589824 f16
  _Float16* W2 = (_Float16*)(ws + off); off += 147456;     // 2 planes x 147456 f16
  float* wT3   = ws + off; off += 73728;
  float* ckey  = ws + off; off += (size_t)2 * NBIG;
  int*   cidx  = (int*)(ws + off); off += (size_t)2 * NBIG;
  int*   iws   = (int*)(ws + off); off += 800;
  int*   cnt   = (int*)(ws + off);

  transpose_w_kernel<<<(128*9*64 + 255)/256, 256, 0, stream>>>(w_hm, wT3, 128, 60, 1);
  transpose_w_mfma<512,16><<<(2*16*9*4*512 + 255)/256, 256, 0, stream>>>(w_shared, W1);
  transpose_w_mfma<128, 4><<<(2*4*9*4*512  + 255)/256, 256, 0, stream>>>(w_bb, W2);
  convert_feats<<<dim3(127, 32), 256, 0, stream>>>(feats, X1);

  dim3 cgrid(12, 12, 4);
  conv_mfma<16,0><<<cgrid, 256, 0, stream>>>(X1, W1, b_shared, nullptr, lidarN, X2);
  conv_mfma<4, 1><<<cgrid, 256, 0, stream>>>(X2, W2, gamma_bb, beta_bb, xbb, nullptr);

  dim3 hgrid(6, 45, 2);
  conv3_head_kernel<<<hgrid, 256, 0, stream>>>(xbb, wT3, b_hm, anchor_vecs,
                                               thr_scale, logit_scale, logit_bias, out);

  sims_kernel<<<1, 128, 0, stream>>>(out + 704800);
  hipMemsetAsync(cnt, 0, 2 * sizeof(int), stream);
  nms_kernel<<<(2*NBIG + 255)/256, 256, 0, stream>>>(out, ckey, cidx, cnt);
  topk_kernel<<<2, 1024, 0, stream>>>(ckey, cidx, cnt, out, bev_pos, out, iws);
  gather_qf_kernel<<<2*NPROP, 128, 0, stream>>>(lidarN, w_enc, iws, out + 648800);
}

// Round 7
// 944.864 us; speedup vs baseline: 3.5110x; 1.8582x over previous
//
#include <hip/hip_runtime.h>
#include <math.h>

// TransFusionHead anchor matching — round 7: NMS atomic-contention fix.
// r6 exposed nms_kernel at 834us, VALUBusy 0.2% = serialized global atomics
// (every survivor hit one of 2 counters). Now: per-block LDS compaction +
// one global atomicAdd per (block, batch). Rest unchanged from r6.

#define HW 180
#define NPIX 32400
#define NCLS 10
#define NPROP 200
#define HID 128
#define TDIM 60
#define NBIG (NCLS*NPIX)

#define TH_LO  (-0.9915981193)
#define TH_STEP (0.1789675812)

__constant__ float c_anchors[10][3] = {
  {4.63f,1.97f,1.74f},{6.93f,2.51f,2.84f},{6.37f,2.85f,3.19f},{10.5f,2.94f,3.47f},
  {12.29f,2.9f,3.87f},{0.5f,2.53f,0.98f},{2.11f,0.77f,1.47f},{1.7f,0.6f,1.28f},
  {0.73f,0.67f,1.77f},{0.41f,0.41f,1.07f}};

using f16x8 = _Float16 __attribute__((ext_vector_type(8)));
using f16x4 = _Float16 __attribute__((ext_vector_type(4)));
using f32x4 = float    __attribute__((ext_vector_type(4)));

#define GLD_LDS16(g, l) __builtin_amdgcn_global_load_lds( \
    (__attribute__((address_space(1))) void*)(g), \
    (__attribute__((address_space(3))) void*)(l), 16, 0, 0)

// ---------- conv3 weight transpose ----------
__global__ void transpose_w_kernel(const float* __restrict__ src, float* __restrict__ dst,
                                   int cin, int cout, int halves) {
  int i = blockIdx.x * 256 + threadIdx.x;
  int n = halves * cin * 9 * 64;
  if (i >= n) return;
  int cq = i & 63;
  int t  = (i >> 6) % 9;
  int rest = i / (64 * 9);
  int c = rest % cin;
  int h = rest / cin;
  int co = h * 64 + cq;
  dst[i] = (co < cout) ? src[((size_t)co * cin + c) * 9 + t] : 0.f;
}

// ---------- MFMA weight prepack: [h][ks][t][mf][lane][8] hi plane + lo plane ----------
template<int CIN, int KS>
__global__ void transpose_w_mfma(const float* __restrict__ w, _Float16* __restrict__ Whi) {
  const int N = 2 * KS * 9 * 4 * 512;
  int i = blockIdx.x * 256 + threadIdx.x;
  if (i >= N) return;
  int j = i & 7, lane = (i >> 3) & 63, mf = (i >> 9) & 3;
  int r = i >> 11;
  int t = r % 9; r /= 9;
  int ks = r % KS; int h = r / KS;
  int co = h * 64 + mf * 16 + (lane & 15);
  int ch = ks * 32 + (lane >> 4) * 8 + j;
  float v = w[((size_t)co * CIN + ch) * 9 + t];
  _Float16 hi = (_Float16)v;
  Whi[i] = hi;
  Whi[N + i] = (_Float16)(v - (float)hi);
}

// ---------- feats fp32 NCHW -> X1 hi/lo f16 [b][16ks][px][32] ----------
__global__ __launch_bounds__(256)
void convert_feats(const float* __restrict__ feats, _Float16* __restrict__ X1) {
  int px = blockIdx.x * 256 + threadIdx.x;
  int b = blockIdx.y >> 4, ks = blockIdx.y & 15;
  if (px >= NPIX) return;
  const float* src = feats + ((size_t)(b * 512 + ks * 32)) * NPIX + px;
  float v[32];
#pragma unroll
  for (int c = 0; c < 32; ++c) v[c] = src[(size_t)c * NPIX];
  f16x8 hv[4], lv[4];
#pragma unroll
  for (int c = 0; c < 32; ++c) {
    _Float16 h = (_Float16)v[c];
    hv[c >> 3][c & 7] = h;
    lv[c >> 3][c & 7] = (_Float16)(v[c] - (float)h);
  }
  size_t ob = ((size_t)(b * 16 + ks) * NPIX + px) * 32;
#pragma unroll
  for (int i = 0; i < 4; ++i) {
    *(f16x8*)(X1 + ob + i * 8) = hv[i];
    *(f16x8*)(X1 + 33177600u + ob + i * 8) = lv[i];
  }
}

// ---------- split-fp16 MFMA conv3x3 (unchanged from r6) ----------
template<int KS, int EPI>
__global__ __launch_bounds__(256, 2)
void conv_mfma(const _Float16* __restrict__ X, const _Float16* __restrict__ W,
               const float* __restrict__ p0, const float* __restrict__ p1,
               float* __restrict__ out0, _Float16* __restrict__ outX) {
  constexpr unsigned XPS = 2u * KS * NPIX * 32;   // f16 per plane
  constexpr unsigned WPS = 2u * KS * 9 * 4 * 512;
  __shared__ _Float16 lds_x[20736];               // hi [0,10368), lo [10368,20736)

  const int x0 = blockIdx.x * 16;
  const int y0 = blockIdx.y * 16;
  const int b  = blockIdx.z >> 1;
  const int h  = blockIdx.z & 1;
  const int tid = threadIdx.x;
  const int wave = tid >> 6;
  const int lane = tid & 63;
  const int xl = lane & 15, kg = lane >> 4;

  {
    unsigned* p = (unsigned*)lds_x;
    for (int i = tid; i < 10368; i += 256) p[i] = 0u;
  }

  unsigned offs[11]; unsigned okbits = 0;
#pragma unroll
  for (int s = 0; s < 11; ++s) {
    int inst = wave + 4 * s;
    int c = inst * 64 + lane;
    bool valid = (inst < 41) && (c < 2592);
    int plane = (c >= 1296) ? 1 : 0;
    int cc = c - plane * 1296;
    int px = cc >> 2, q = cc & 3;
    int r = px / 18, xx = px - r * 18;
    int gy = y0 - 1 + r, gx = x0 - 1 + xx;
    bool ok = valid && ((unsigned)gy < 180u) && ((unsigned)gx < 180u);
    offs[s] = ok ? ((unsigned)((b * KS) * NPIX + gy * 180 + gx) * 32u + (unsigned)q * 8u
                    + (unsigned)plane * XPS) : 0u;
    okbits |= (ok ? 1u : 0u) << s;
  }

  f32x4 acc[4][4];
#pragma unroll
  for (int mf = 0; mf < 4; ++mf)
#pragma unroll
    for (int f = 0; f < 4; ++f) acc[mf][f] = (f32x4){0.f, 0.f, 0.f, 0.f};

  for (int ks = 0; ks < KS; ++ks) {
    __syncthreads();
    const unsigned kof = (unsigned)ks * (NPIX * 32u);
#pragma unroll
    for (int s = 0; s < 11; ++s) {
      if (okbits & (1u << s))
        GLD_LDS16(X + (size_t)(offs[s] + kof), lds_x + (wave + 4 * s) * 512);
    }
    __syncthreads();

    const _Float16* wks = W + (size_t)((h * KS + ks) * 9) * 2048 + lane * 8;
#pragma unroll
    for (int t = 0; t < 9; ++t) {
      const int ky = t / 3, kx = t % 3;
      f16x8 bh[4], bl[4];
#pragma unroll
      for (int f = 0; f < 4; ++f) {
        int R = 4 * wave + f;
        int lo = ((R + ky) * 18 + xl + kx) * 32 + kg * 8;
        bh[f] = *(const f16x8*)(lds_x + lo);
        bl[f] = *(const f16x8*)(lds_x + 10368 + lo);
      }
      const _Float16* wt = wks + (size_t)t * 2048;
      f16x8 ah[4], al[4];
#pragma unroll
      for (int mf = 0; mf < 4; ++mf) {
        ah[mf] = *(const f16x8*)(wt + mf * 512);
        al[mf] = *(const f16x8*)(wt + WPS + mf * 512);
      }
#pragma unroll
      for (int mf = 0; mf < 4; ++mf)
#pragma unroll
        for (int f = 0; f < 4; ++f) {
          acc[mf][f] = __builtin_amdgcn_mfma_f32_16x16x32_f16(ah[mf], bh[f], acc[mf][f], 0, 0, 0);
          acc[mf][f] = __builtin_amdgcn_mfma_f32_16x16x32_f16(ah[mf], bl[f], acc[mf][f], 0, 0, 0);
          acc[mf][f] = __builtin_amdgcn_mfma_f32_16x16x32_f16(al[mf], bh[f], acc[mf][f], 0, 0, 0);
        }
    }
  }

  const int x = x0 + xl;
  if (x >= HW) return;
#pragma unroll
  for (int mf = 0; mf < 4; ++mf) {
    const int cobase = h * 64 + mf * 16 + kg * 4;
    f32x4 q0 = *(const f32x4*)(p0 + cobase);
    f32x4 q1 = (EPI == 1) ? *(const f32x4*)(p1 + cobase) : (f32x4){0.f,0.f,0.f,0.f};
#pragma unroll
    for (int f = 0; f < 4; ++f) {
      const int y = y0 + 4 * wave + f;
      if (y >= HW) continue;
      if (EPI == 0) {
        f32x4 v;
        f16x4 h4, l4;
#pragma unroll
        for (int r = 0; r < 4; ++r) {
          float z = acc[mf][f][r] + q0[r];
          v[r] = z;
          _Float16 hh = (_Float16)z;
          h4[r] = hh;
          l4[r] = (_Float16)(z - (float)hh);
        }
        const int kso = cobase >> 5, c32 = cobase & 31;
        size_t nidx = ((size_t)(b * 4 + kso) * NPIX + (size_t)y * 180 + x) * 32 + c32;
        *(f32x4*)(out0 + nidx) = v;
        *(f16x4*)(outX + nidx) = h4;
        *(f16x4*)(outX + 8294400u + nidx) = l4;
      } else {
#pragma unroll
        for (int r = 0; r < 4; ++r) {
          float z = fmaf(acc[mf][f][r], q0[r], q1[r]);
          z = fmaxf(z, 0.f);
          out0[((size_t)(b * 128 + cobase + r)) * NPIX + (size_t)y * 180 + x] = z;
        }
      }
    }
  }
}

// ---------- conv3 (128->60 pad 64) + head, fp32 (unchanged) ----------
__global__ __launch_bounds__(256, 3)
void conv3_head_kernel(const float* __restrict__ in, const float* __restrict__ wT,
                       const float* __restrict__ b_hm, const float* __restrict__ anchor_vecs,
                       const float* __restrict__ thr_scale, const float* __restrict__ logit_scale,
                       const float* __restrict__ logit_bias, float* __restrict__ heatmap) {
  const int CIN = 128;
  __shared__ float lds_in[2][1728];
  __shared__ float lds_w[2][4608];
  const int x0 = blockIdx.x * 32;
  const int y0 = blockIdx.y * 4;
  const int b  = blockIdx.z;
  const int tid  = threadIdx.x;
  const int co_g = tid & 15;
  const int pg   = tid >> 4;
  const int colg = pg & 3;
  const int rowg = pg >> 2;
  const int wave = tid >> 6;
  const int lane = tid & 63;

  unsigned off[7]; bool okf[7];
#pragma unroll
  for (int k = 0; k < 7; ++k) {
    int L = tid + k * 256;
    int ch = L / 216; int rem = L - ch * 216;
    int r = rem / 36; int x = rem - r * 36;
    int y = y0 + r - 1; int gx = x0 + x - 1;
    bool ok = (L < 1728) && ((unsigned)y < (unsigned)HW) && ((unsigned)gx < (unsigned)HW);
    okf[k] = ok;
    off[k] = ok ? (unsigned)(((b * CIN + ch) * HW + y) * HW + gx) : 0u;
  }

  float stg[7];
#pragma unroll
  for (int k = 0; k < 7; ++k) stg[k] = in[off[k]];
#pragma unroll
  for (int i = 0; i < 5; ++i) {
    int s = wave + (i << 2);
    if (s < 18) GLD_LDS16(wT + s * 256 + lane * 4, &lds_w[0][s * 256]);
  }
  {
    float* pb = lds_in[0];
#pragma unroll
    for (int k = 0; k < 7; ++k) {
      int L = tid + k * 256;
      if (L < 1728) pb[L] = okf[k] ? stg[k] : 0.f;
    }
  }
  __syncthreads();

  float acc[4][8];
#pragma unroll
  for (int a = 0; a < 4; ++a)
#pragma unroll
    for (int px = 0; px < 8; ++px) acc[a][px] = 0.f;

  const int CHUNKS = CIN / 8;
  unsigned chunkOff = 0;
  for (int c = 0; c < CHUNKS; ++c) {
    if (c + 1 < CHUNKS) {
      chunkOff += 8u * NPIX;
#pragma unroll
      for (int k = 0; k < 7; ++k) stg[k] = in[off[k] + chunkOff];
      const float* gw = wT + (size_t)(c + 1) * 4608;
      float* lw = lds_w[(c + 1) & 1];
#pragma unroll
      for (int i = 0; i < 5; ++i) {
        int s = wave + (i << 2);
        if (s < 18) GLD_LDS16(gw + s * 256 + lane * 4, lw + s * 256);
      }
    }
    const float* wch = lds_w[c & 1];
    const float* lbase = lds_in[c & 1] + rowg * 36 + colg * 8;
    for (int ch = 0; ch < 8; ++ch) {
      float rin[3][10];
#pragma unroll
      for (int rr = 0; rr < 3; ++rr) {
        const float* rp = lbase + ch * 216 + rr * 36;
        float4 q0 = *reinterpret_cast<const float4*>(rp);
        float4 q1 = *reinterpret_cast<const float4*>(rp + 4);
        float2 q2 = *reinterpret_cast<const float2*>(rp + 8);
        rin[rr][0] = q0.x; rin[rr][1] = q0.y; rin[rr][2] = q0.z; rin[rr][3] = q0.w;
        rin[rr][4] = q1.x; rin[rr][5] = q1.y; rin[rr][6] = q1.z; rin[rr][7] = q1.w;
        rin[rr][8] = q2.x; rin[rr][9] = q2.y;
      }
      const float* wrow = wch + ch * 576 + co_g * 4;
#pragma unroll
      for (int t = 0; t < 9; ++t) {
        const float4 w4 = *reinterpret_cast<const float4*>(wrow + t * 64);
        const int ky = t / 3, kx = t % 3;
#pragma unroll
        for (int px = 0; px < 8; ++px) {
          const float iv = rin[ky][px + kx];
          acc[0][px] = fmaf(iv, w4.x, acc[0][px]);
          acc[1][px] = fmaf(iv, w4.y, acc[1][px]);
          acc[2][px] = fmaf(iv, w4.z, acc[2][px]);
          acc[3][px] = fmaf(iv, w4.w, acc[3][px]);
        }
      }
    }
    if (c + 1 < CHUNKS) {
      float* pb = lds_in[(c + 1) & 1];
#pragma unroll
      for (int k = 0; k < 7; ++k) {
        int L = tid + k * 256;
        if (L < 1728) pb[L] = okf[k] ? stg[k] : 0.f;
      }
      __syncthreads();
    }
  }

  const int cbase = co_g * 4;
  float4 a4[10];
#pragma unroll
  for (int k = 0; k < 10; ++k) {
    if (cbase + 3 < TDIM) a4[k] = *reinterpret_cast<const float4*>(anchor_vecs + k * TDIM + cbase);
    else a4[k] = make_float4(0.f, 0.f, 0.f, 0.f);
  }
  float bh[4], th[4];
#pragma unroll
  for (int co = 0; co < 4; ++co) {
    int cc = cbase + co;
    bh[co] = (cc < TDIM) ? b_hm[cc] : 0.f;
    th[co] = (float)(TH_LO + (double)(cc % 20) * TH_STEP);
  }
  const float s  = thr_scale[0];
  const float ls = logit_scale[0];
  const float lb = logit_bias[0];

  float hmv[8];
#pragma unroll
  for (int px = 0; px < 8; ++px) {
    float v[4];
#pragma unroll
    for (int co = 0; co < 4; ++co) {
      if (cbase + co < TDIM) {
        float z = acc[co][px] + bh[co];
        float t = (z - th[co]) * s;
        v[co] = 1.f / (1.f + expf(-t));
      } else v[co] = 0.f;
    }
    float s2 = v[0]*v[0] + v[1]*v[1] + v[2]*v[2] + v[3]*v[3];
    float dp[10];
#pragma unroll
    for (int k = 0; k < 10; ++k)
      dp[k] = v[0]*a4[k].x + v[1]*a4[k].y + v[2]*a4[k].z + v[3]*a4[k].w;
#pragma unroll
    for (int o = 1; o < 16; o <<= 1) {
      s2 += __shfl_xor(s2, o, 16);
#pragma unroll
      for (int k = 0; k < 10; ++k) dp[k] += __shfl_xor(dp[k], o, 16);
    }
    float dk = dp[0];
#pragma unroll
    for (int k = 1; k < 10; ++k) if (co_g == k) dk = dp[k];
    float sim = dk / (1e-8f + sqrtf(s2));
    hmv[px] = 1.f / (1.f + expf(-fmaf(ls, sim, lb)));
  }

  const int xb = x0 + colg * 8;
  if (xb >= HW || co_g >= NCLS) return;
  const bool full = (xb + 8 <= HW);
  const int yo = y0 + rowg;
  float* op = heatmap + (((size_t)b * NCLS + co_g) * HW + yo) * HW + xb;
  *reinterpret_cast<float4*>(op) = make_float4(hmv[0], hmv[1], hmv[2], hmv[3]);
  if (full) *reinterpret_cast<float4*>(op + 4) = make_float4(hmv[4], hmv[5], hmv[6], hmv[7]);
}

__global__ void sims_kernel(float* __restrict__ out_sims) {
  int t = threadIdx.x;
  if (t < 100) {
    int i = t / 10, j = t % 10;
    float r = 1.f;
#pragma unroll
    for (int d = 0; d < 3; ++d) {
      float ai = c_anchors[i][d], aj = c_anchors[j][d];
      r *= fminf(ai, aj) / fmaxf(ai, aj);
    }
    out_sims[t] = r;
  }
}

// NMS + two-level compaction: LDS per-block counters (one per batch since a
// block can straddle the b0/b1 boundary), one global atomicAdd per (block,
// batch), survivors write into their reserved slots. Order nondeterministic;
// downstream radix-select + sorts are set-deterministic.
__global__ __launch_bounds__(256)
void nms_kernel(const float* __restrict__ hm, float* __restrict__ ckey,
                int* __restrict__ cidx, int* __restrict__ cnt) {
  __shared__ int lcnt[2];
  __shared__ int lbase[2];
  const int tid = threadIdx.x;
  if (tid < 2) lcnt[tid] = 0;
  __syncthreads();

  int i = blockIdx.x * 256 + tid;
  bool surv = false; float v = 0.f; int bk = 0, p = 0;
  if (i < 2 * NBIG) {
    int x = i % HW; int y = (i / HW) % HW; int plane = i / NPIX;
    v = hm[i];
    float m = v;
#pragma unroll
    for (int dy = -1; dy <= 1; ++dy)
#pragma unroll
      for (int dx = -1; dx <= 1; ++dx) {
        int yy = y + dy, xx = x + dx;
        if ((unsigned)yy < (unsigned)HW && (unsigned)xx < (unsigned)HW)
          m = fmaxf(m, hm[((size_t)plane * NPIX) + yy * HW + xx]);
      }
    if (v == m) {
      surv = true;
      bk = i / NBIG;
      p = atomicAdd(&lcnt[bk], 1);      // LDS atomic: fast
    }
  }
  __syncthreads();
  if (tid < 2 && lcnt[tid] > 0)
    lbase[tid] = atomicAdd(&cnt[tid], lcnt[tid]);   // <=2 global atomics/block
  __syncthreads();
  if (surv) {
    int slot = lbase[bk] + p;
    ckey[(size_t)bk * NBIG + slot] = v;
    cidx[(size_t)bk * NBIG + slot] = i - bk * NBIG;
  }
}

__global__ __launch_bounds__(1024)
void topk_kernel(const float* __restrict__ ckey, const int* __restrict__ cidx,
                 const int* __restrict__ cnt, const float* __restrict__ heatmap,
                 const float* __restrict__ bev_pos, float* __restrict__ out,
                 int* __restrict__ iws) {
  const int b = blockIdx.x;
  const int tid = threadIdx.x;
  const float* keys = ckey + (size_t)b * NBIG;
  const int* idxs = cidx + (size_t)b * NBIG;

  __shared__ unsigned hist[256];
  __shared__ unsigned sh_prefix;
  __shared__ int sh_want, sh_n;
  __shared__ int cntGT, cntTie;
  __shared__ unsigned gt_key[256], gt_idx[256];
  __shared__ unsigned tie_idx[2048];

  if (tid == 0) sh_n = cnt[b];
  __syncthreads();
  const int n = sh_n;

  unsigned prefix = 0; int want = NPROP;
  for (int shift = 24; shift >= 0; shift -= 8) {
    if (tid < 256) hist[tid] = 0u;
    __syncthreads();
    for (int i = tid; i < n; i += 1024) {
      unsigned k = __float_as_uint(keys[i]);
      bool match = (shift == 24) || ((k >> (shift + 8)) == (prefix >> (shift + 8)));
      if (match) atomicAdd(&hist[(k >> shift) & 255], 1u);
    }
    __syncthreads();
    if (tid == 0) {
      int cum = 0; int bsel = 0; sh_want = want;
      for (int bin = 255; bin >= 0; --bin) {
        cum += (int)hist[bin];
        if (cum >= want) { bsel = bin; sh_want = want - (cum - (int)hist[bin]); break; }
      }
      sh_prefix = prefix | ((unsigned)bsel << shift);
      cntGT = 0; cntTie = 0;
    }
    __syncthreads();
    prefix = sh_prefix; want = sh_want;
    __syncthreads();
  }
  const unsigned T = prefix;

  for (int i = tid; i < n; i += 1024) {
    unsigned k = __float_as_uint(keys[i]);
    if (k > T) {
      int p = atomicAdd(&cntGT, 1);
      if (p < 256) { gt_key[p] = k; gt_idx[p] = (unsigned)idxs[i]; }
    } else if (k == T) {
      int p = atomicAdd(&cntTie, 1);
      if (p < 2048) tie_idx[p] = (unsigned)idxs[i];
    }
  }
  __syncthreads();
  const int nGT = min(cntGT, 256);
  const int nTie = min(cntTie, 2048);

  for (int i = tid; i < 256; i += 1024)
    if (i >= nGT) { gt_key[i] = 0u; gt_idx[i] = 0xFFFFFFFFu; }
  for (int i = tid; i < 2048; i += 1024)
    if (i >= nTie) tie_idx[i] = 0xFFFFFFFFu;
  __syncthreads();

  for (int k2 = 2; k2 <= 256; k2 <<= 1) {
    for (int j = k2 >> 1; j > 0; j >>= 1) {
      for (int i = tid; i < 256; i += 1024) {
        int ixj = i ^ j;
        if (ixj > i) {
          unsigned ka = gt_key[i], kb = gt_key[ixj];
          unsigned ia = gt_idx[i], ib = gt_idx[ixj];
          bool firstA = (ka > kb) || (ka == kb && ia < ib);
          bool up = ((i & k2) == 0);
          if (up ? !firstA : firstA) {
            gt_key[i] = kb; gt_key[ixj] = ka;
            gt_idx[i] = ib; gt_idx[ixj] = ia;
          }
        }
      }
      __syncthreads();
    }
  }
  for (int k2 = 2; k2 <= 2048; k2 <<= 1) {
    for (int j = k2 >> 1; j > 0; j >>= 1) {
      for (int i = tid; i < 2048; i += 1024) {
        int ixj = i ^ j;
        if (ixj > i) {
          unsigned ia = tie_idx[i], ib = tie_idx[ixj];
          bool firstA = ia < ib;
          bool up = ((i & k2) == 0);
          if (up ? !firstA : firstA) { tie_idx[i] = ib; tie_idx[ixj] = ia; }
        }
      }
      __syncthreads();
    }
  }

  for (int r = tid; r < NPROP; r += 1024) {
    unsigned idx; float score;
    if (r < nGT) { idx = gt_idx[r]; score = __uint_as_float(gt_key[r]); }
    else         { idx = tie_idx[r - nGT]; score = __uint_as_float(T); }
    int label = (int)(idx / NPIX);
    int pos = (int)(idx - (unsigned)label * NPIX);
    out[648000 + b * NPROP + r] = score;
    out[648400 + b * NPROP + r] = (float)label;
    out[700000 + (b * NPROP + r) * 2 + 0] = bev_pos[pos * 2 + 0];
    out[700000 + (b * NPROP + r) * 2 + 1] = bev_pos[pos * 2 + 1];
#pragma unroll
    for (int k = 0; k < NCLS; ++k)
      out[700800 + (b * NCLS + k) * NPROP + r] = heatmap[(size_t)(b * NCLS + k) * NPIX + pos];
    iws[b * NPROP + r] = pos;
    iws[2 * NPROP + b * NPROP + r] = label;
  }
}

// lidar is NHWC-chunked fp32: [b][4][px][32]
__global__ void gather_qf_kernel(const float* __restrict__ lidar, const float* __restrict__ w_enc,
                                 const int* __restrict__ iws, float* __restrict__ out_qf) {
  int p = blockIdx.x % NPROP;
  int b = blockIdx.x / NPROP;
  int c = threadIdx.x;
  int pos = iws[b * NPROP + p];
  int label = iws[2 * NPROP + b * NPROP + p];
  float la0 = logf(c_anchors[label][0]);
  float la1 = logf(c_anchors[label][1]);
  float la2 = logf(c_anchors[label][2]);
  float dot = w_enc[c * 3 + 0] * la0 + w_enc[c * 3 + 1] * la1 + w_enc[c * 3 + 2] * la2;
  float g = lidar[((size_t)(b * 4 + (c >> 5)) * NPIX + pos) * 32 + (c & 31)];
  out_qf[((size_t)b * HID + c) * NPROP + p] = g + dot;
}

extern "C" void kernel_launch(void* const* d_in, const int* in_sizes, int n_in,
                              void* d_out, int out_size, void* d_ws, size_t ws_size,
                              hipStream_t stream) {
  (void)in_sizes; (void)n_in; (void)out_size; (void)ws_size;
  const float* feats       = (const float*)d_in[0];
  const float* w_shared    = (const float*)d_in[1];
  const float* b_shared    = (const float*)d_in[2];
  const float* w_bb        = (const float*)d_in[3];
  const float* gamma_bb    = (const float*)d_in[4];
  const float* beta_bb     = (const float*)d_in[5];
  const float* w_hm        = (const float*)d_in[6];
  const float* b_hm        = (const float*)d_in[7];
  const float* thr_scale   = (const float*)d_in[8];
  const float* logit_scale = (const float*)d_in[9];
  const float* logit_bias  = (const float*)d_in[10];
  const float* w_enc       = (const float*)d_in[11];
  const float* anchor_vecs = (const float*)d_in[12];
  const float* bev_pos     = (const float*)d_in[13];
  float* out = (float*)d_out;

  float* ws = (float*)d_ws;
  size_t off = 0;
  _Float16* X1 = (_Float16*)(ws + off); off += 33177600;   // 2 planes x 33.18M f16
  _Float16* X2 = (_Float16*)(ws + off); off += 8294400;    // 2 planes x 8.29M f16
  float* lidarN = ws + off; off += 8294400;                // NHWC fp32
  float* xbb    = ws + off; off += 8294400;                // NCHW fp32
  _Float16* W1 = (_Float16*)(ws + off); off += 589824;     // 2 planes x 589824 f16
  _Float16* W2 = (_Float16*)(ws + off); off += 147456;     // 2 planes x 147456 f16
  float* wT3   = ws + off; off += 73728;
  float* ckey  = ws + off; off += (size_t)2 * NBIG;
  int*   cidx  = (int*)(ws + off); off += (size_t)2 * NBIG;
  int*   iws   = (int*)(ws + off); off += 800;
  int*   cnt   = (int*)(ws + off);

  transpose_w_kernel<<<(128*9*64 + 255)/256, 256, 0, stream>>>(w_hm, wT3, 128, 60, 1);
  transpose_w_mfma<512,16><<<(2*16*9*4*512 + 255)/256, 256, 0, stream>>>(w_shared, W1);
  transpose_w_mfma<128, 4><<<(2*4*9*4*512  + 255)/256, 256, 0, stream>>>(w_bb, W2);
  convert_feats<<<dim3(127, 32), 256, 0, stream>>>(feats, X1);

  dim3 cgrid(12, 12, 4);
  conv_mfma<16,0><<<cgrid, 256, 0, stream>>>(X1, W1, b_shared, nullptr, lidarN, X2);
  conv_mfma<4, 1><<<cgrid, 256, 0, stream>>>(X2, W2, gamma_bb, beta_bb, xbb, nullptr);

  dim3 hgrid(6, 45, 2);
  conv3_head_kernel<<<hgrid, 256, 0, stream>>>(xbb, wT3, b_hm, anchor_vecs,
                                               thr_scale, logit_scale, logit_bias, out);

  sims_kernel<<<1, 128, 0, stream>>>(out + 704800);
  hipMemsetAsync(cnt, 0, 2 * sizeof(int), stream);
  nms_kernel<<<(2*NBIG + 255)/256, 256, 0, stream>>>(out, ckey, cidx, cnt);
  topk_kernel<<<2, 1024, 0, stream>>>(ckey, cidx, cnt, out, bev_pos, out, iws);
  gather_qf_kernel<<<2*NPROP, 128, 0, stream>>>(lidarN, w_enc, iws, out + 648800);
}

// Round 9
// 729.599 us; speedup vs baseline: 4.5469x; 1.2950x over previous
//
#include <hip/hip_runtime.h>
#include <math.h>

// TransFusionHead anchor matching — round 9: fix r8's W-layout bugs.
// r8 failed: prepack wrote only half the W tensor, kernel used wrong slice
// stride (18432 vs 36864 f16), and lo-plane LDS reads ran OOB past the shared
// array. r9: per-(h,ks) slice = [plane][t][mf][lane][8] (36864 f16); LDS holds
// X + ONE W plane (59,904 B, 2 blocks/CU); per ks: DMA X+Whi / hi-phase /
// DMA Wlo / lo-phase with a barrier between each.

#define HW 180
#define NPIX 32400
#define NCLS 10
#define NPROP 200
#define HID 128
#define TDIM 60
#define NBIG (NCLS*NPIX)

#define TH_LO  (-0.9915981193)
#define TH_STEP (0.1789675812)

__constant__ float c_anchors[10][3] = {
  {4.63f,1.97f,1.74f},{6.93f,2.51f,2.84f},{6.37f,2.85f,3.19f},{10.5f,2.94f,3.47f},
  {12.29f,2.9f,3.87f},{0.5f,2.53f,0.98f},{2.11f,0.77f,1.47f},{1.7f,0.6f,1.28f},
  {0.73f,0.67f,1.77f},{0.41f,0.41f,1.07f}};

using f16x8 = _Float16 __attribute__((ext_vector_type(8)));
using f16x4 = _Float16 __attribute__((ext_vector_type(4)));
using f32x4 = float    __attribute__((ext_vector_type(4)));

#define GLD_LDS16(g, l) __builtin_amdgcn_global_load_lds( \
    (__attribute__((address_space(1))) void*)(g), \
    (__attribute__((address_space(3))) void*)(l), 16, 0, 0)

// ---------- conv3 weight transpose ----------
__global__ void transpose_w_kernel(const float* __restrict__ src, float* __restrict__ dst,
                                   int cin, int cout, int halves) {
  int i = blockIdx.x * 256 + threadIdx.x;
  int n = halves * cin * 9 * 64;
  if (i >= n) return;
  int cq = i & 63;
  int t  = (i >> 6) % 9;
  int rest = i / (64 * 9);
  int c = rest % cin;
  int h = rest / cin;
  int co = h * 64 + cq;
  dst[i] = (co < cout) ? src[((size_t)co * cin + c) * 9 + t] : 0.f;
}

// ---------- MFMA weight prepack: [h][ks][plane][t][mf][lane][8] ----------
// per-(h,ks) slice = 2*9*4*512 = 36864 f16.  Total = HALVES*KS*36864.
template<int CIN, int KS, int HALVES>
__global__ void transpose_w_mfma(const float* __restrict__ w, _Float16* __restrict__ dst) {
  const int N = HALVES * KS * 36864;
  int i = blockIdx.x * 256 + threadIdx.x;
  if (i >= N) return;
  int j = i & 7;
  int lane = (i >> 3) & 63;
  int mf = (i >> 9) & 3;
  int rest = i >> 11;
  int t = rest % 9; rest /= 9;
  int plane = rest & 1; rest >>= 1;
  int ks = rest % KS; int h = rest / KS;
  int co = h * 64 + mf * 16 + (lane & 15);
  int ch = ks * 32 + (lane >> 4) * 8 + j;
  float v = w[((size_t)co * CIN + ch) * 9 + t];
  _Float16 hi = (_Float16)v;
  dst[i] = plane ? (_Float16)(v - (float)hi) : hi;
}

// ---------- feats fp32 NCHW -> X1 hi/lo f16 [b][16ks][px][32] ----------
__global__ __launch_bounds__(256)
void convert_feats(const float* __restrict__ feats, _Float16* __restrict__ X1) {
  int px = blockIdx.x * 256 + threadIdx.x;
  int b = blockIdx.y >> 4, ks = blockIdx.y & 15;
  if (px >= NPIX) return;
  const float* src = feats + ((size_t)(b * 512 + ks * 32)) * NPIX + px;
  float v[32];
#pragma unroll
  for (int c = 0; c < 32; ++c) v[c] = src[(size_t)c * NPIX];
  f16x8 hv[4], lv[4];
#pragma unroll
  for (int c = 0; c < 32; ++c) {
    _Float16 h = (_Float16)v[c];
    hv[c >> 3][c & 7] = h;
    lv[c >> 3][c & 7] = (_Float16)(v[c] - (float)h);
  }
  size_t ob = ((size_t)(b * 16 + ks) * NPIX + px) * 32;
#pragma unroll
  for (int i = 0; i < 4; ++i) {
    *(f16x8*)(X1 + ob + i * 8) = hv[i];
    *(f16x8*)(X1 + 33177600u + ob + i * 8) = lv[i];
  }
}

// ---------- split-fp16 MFMA conv3x3, tile 16x8 px x 64 co ----------
// LDS: X 10x18x32x2pl (11520 f16) + ONE W plane (18432 f16) = 59904 B.
// Per ks: [bar] DMA X+Whi [bar] hi-phase (ah*bh + ah*bl) [bar] DMA Wlo
// [bar] lo-phase (al*bh).
template<int KS, int EPI>
__global__ __launch_bounds__(256, 2)
void conv_mfma(const _Float16* __restrict__ X, const _Float16* __restrict__ W,
               const float* __restrict__ p0, const float* __restrict__ p1,
               float* __restrict__ out0, _Float16* __restrict__ outX) {
  constexpr unsigned XPS = 2u * KS * NPIX * 32;   // f16 per activation plane
  __shared__ _Float16 lds[11520 + 18432];
  _Float16* lds_x = lds;
  _Float16* lds_w = lds + 11520;

  const int x0 = blockIdx.x * 16;
  const int y0 = blockIdx.y * 8;
  const int b  = blockIdx.z >> 1;
  const int h  = blockIdx.z & 1;
  const int tid = threadIdx.x;
  const int wave = tid >> 6;
  const int lane = tid & 63;
  const int xl = lane & 15, kg = lane >> 4;

  // zero X region once (halo slots stay zero; masked DMA lanes never write)
  {
    unsigned* p = (unsigned*)lds_x;
    for (int i = tid; i < 5760; i += 256) p[i] = 0u;
  }

  // X staging map: 1440 16B-chunks (hi 720 + lo 720), 23 wave-insts.
  unsigned offs[6]; unsigned okb = 0;
#pragma unroll
  for (int s = 0; s < 6; ++s) {
    int inst = wave + 4 * s;
    int c = inst * 64 + lane;
    bool valid = (inst < 23) && (c < 1440);
    int plane = (c >= 720) ? 1 : 0;
    int cc = c - plane * 720;
    int px = cc >> 2, q = cc & 3;
    int r = px / 18, xx = px - r * 18;
    int gy = y0 - 1 + r, gx = x0 - 1 + xx;
    bool ok = valid && ((unsigned)gy < 180u) && ((unsigned)gx < 180u);
    offs[s] = ok ? ((unsigned)((b * KS) * NPIX + gy * 180 + gx) * 32u + (unsigned)q * 8u
                    + (unsigned)plane * XPS) : 0u;
    okb |= (ok ? 1u : 0u) << s;
  }

  f32x4 acc[4][2];
#pragma unroll
  for (int mf = 0; mf < 4; ++mf)
#pragma unroll
    for (int f = 0; f < 2; ++f) acc[mf][f] = (f32x4){0.f, 0.f, 0.f, 0.f};

  const _Float16* gwb = W + (size_t)(h * KS) * 36864;
  for (int ks = 0; ks < KS; ++ks) {
    __syncthreads();                       // A: prev reads of X/W done
    const unsigned kof = (unsigned)ks * (NPIX * 32u);
#pragma unroll
    for (int s = 0; s < 6; ++s) {
      if (okb & (1u << s))
        GLD_LDS16(X + (size_t)(offs[s] + kof), lds_x + (wave + 4 * s) * 512);
    }
    const _Float16* gw = gwb + (size_t)ks * 36864;
#pragma unroll
    for (int s = 0; s < 9; ++s) {          // W-hi plane: 36 chunks exactly
      int c2 = wave + 4 * s;
      GLD_LDS16(gw + c2 * 512 + lane * 8, lds_w + c2 * 512);
    }
    __syncthreads();                       // B: X + W-hi ready

#pragma unroll
    for (int t = 0; t < 9; ++t) {
      const int ky = t / 3, kx = t % 3;
      f16x8 bh[2], bl[2];
#pragma unroll
      for (int f = 0; f < 2; ++f) {
        int R = 2 * wave + f;
        int lo = ((R + ky) * 18 + xl + kx) * 32 + kg * 8;
        bh[f] = *(const f16x8*)(lds_x + lo);
        bl[f] = *(const f16x8*)(lds_x + 5760 + lo);
      }
      const _Float16* wt = lds_w + t * 2048 + lane * 8;
      f16x8 ah[4];
#pragma unroll
      for (int mf = 0; mf < 4; ++mf) ah[mf] = *(const f16x8*)(wt + mf * 512);
#pragma unroll
      for (int mf = 0; mf < 4; ++mf)
#pragma unroll
        for (int f = 0; f < 2; ++f) {
          acc[mf][f] = __builtin_amdgcn_mfma_f32_16x16x32_f16(ah[mf], bh[f], acc[mf][f], 0, 0, 0);
          acc[mf][f] = __builtin_amdgcn_mfma_f32_16x16x32_f16(ah[mf], bl[f], acc[mf][f], 0, 0, 0);
        }
    }
    __syncthreads();                       // C: W-hi reads done
#pragma unroll
    for (int s = 0; s < 9; ++s) {          // W-lo plane into same buffer
      int c2 = wave + 4 * s;
      GLD_LDS16(gw + 18432 + c2 * 512 + lane * 8, lds_w + c2 * 512);
    }
    __syncthreads();                       // D: W-lo ready

#pragma unroll
    for (int t = 0; t < 9; ++t) {
      const int ky = t / 3, kx = t % 3;
      f16x8 bh[2];
#pragma unroll
      for (int f = 0; f < 2; ++f) {
        int R = 2 * wave + f;
        int lo = ((R + ky) * 18 + xl + kx) * 32 + kg * 8;
        bh[f] = *(const f16x8*)(lds_x + lo);
      }
      const _Float16* wt = lds_w + t * 2048 + lane * 8;
      f16x8 al[4];
#pragma unroll
      for (int mf = 0; mf < 4; ++mf) al[mf] = *(const f16x8*)(wt + mf * 512);
#pragma unroll
      for (int mf = 0; mf < 4; ++mf)
#pragma unroll
        for (int f = 0; f < 2; ++f)
          acc[mf][f] = __builtin_amdgcn_mfma_f32_16x16x32_f16(al[mf], bh[f], acc[mf][f], 0, 0, 0);
    }
  }

  // ---- epilogue: C frag col=lane&15 (pixel x), row=kg*4+r (cout) ----
  const int x = x0 + xl;
  if (x >= HW) return;
#pragma unroll
  for (int mf = 0; mf < 4; ++mf) {
    const int cobase = h * 64 + mf * 16 + kg * 4;
    f32x4 q0 = *(const f32x4*)(p0 + cobase);
    f32x4 q1 = (EPI == 1) ? *(const f32x4*)(p1 + cobase) : (f32x4){0.f,0.f,0.f,0.f};
#pragma unroll
    for (int f = 0; f < 2; ++f) {
      const int y = y0 + 2 * wave + f;
      if (y >= HW) continue;
      if (EPI == 0) {
        f32x4 v;
        f16x4 h4, l4;
#pragma unroll
        for (int r = 0; r < 4; ++r) {
          float z = acc[mf][f][r] + q0[r];
          v[r] = z;
          _Float16 hh = (_Float16)z;
          h4[r] = hh;
          l4[r] = (_Float16)(z - (float)hh);
        }
        const int kso = cobase >> 5, c32 = cobase & 31;
        size_t nidx = ((size_t)(b * 4 + kso) * NPIX + (size_t)y * 180 + x) * 32 + c32;
        *(f32x4*)(out0 + nidx) = v;
        *(f16x4*)(outX + nidx) = h4;
        *(f16x4*)(outX + 8294400u + nidx) = l4;
      } else {
#pragma unroll
        for (int r = 0; r < 4; ++r) {
          float z = fmaf(acc[mf][f][r], q0[r], q1[r]);
          z = fmaxf(z, 0.f);
          out0[((size_t)(b * 128 + cobase + r)) * NPIX + (size_t)y * 180 + x] = z;
        }
      }
    }
  }
}

// ---------- conv3 (128->60 pad 64) + head, fp32 (unchanged) ----------
__global__ __launch_bounds__(256, 3)
void conv3_head_kernel(const float* __restrict__ in, const float* __restrict__ wT,
                       const float* __restrict__ b_hm, const float* __restrict__ anchor_vecs,
                       const float* __restrict__ thr_scale, const float* __restrict__ logit_scale,
                       const float* __restrict__ logit_bias, float* __restrict__ heatmap) {
  const int CIN = 128;
  __shared__ float lds_in[2][1728];
  __shared__ float lds_w[2][4608];
  const int x0 = blockIdx.x * 32;
  const int y0 = blockIdx.y * 4;
  const int b  = blockIdx.z;
  const int tid  = threadIdx.x;
  const int co_g = tid & 15;
  const int pg   = tid >> 4;
  const int colg = pg & 3;
  const int rowg = pg >> 2;
  const int wave = tid >> 6;
  const int lane = tid & 63;

  unsigned off[7]; bool okf[7];
#pragma unroll
  for (int k = 0; k < 7; ++k) {
    int L = tid + k * 256;
    int ch = L / 216; int rem = L - ch * 216;
    int r = rem / 36; int x = rem - r * 36;
    int y = y0 + r - 1; int gx = x0 + x - 1;
    bool ok = (L < 1728) && ((unsigned)y < (unsigned)HW) && ((unsigned)gx < (unsigned)HW);
    okf[k] = ok;
    off[k] = ok ? (unsigned)(((b * CIN + ch) * HW + y) * HW + gx) : 0u;
  }

  float stg[7];
#pragma unroll
  for (int k = 0; k < 7; ++k) stg[k] = in[off[k]];
#pragma unroll
  for (int i = 0; i < 5; ++i) {
    int s = wave + (i << 2);
    if (s < 18) GLD_LDS16(wT + s * 256 + lane * 4, &lds_w[0][s * 256]);
  }
  {
    float* pb = lds_in[0];
#pragma unroll
    for (int k = 0; k < 7; ++k) {
      int L = tid + k * 256;
      if (L < 1728) pb[L] = okf[k] ? stg[k] : 0.f;
    }
  }
  __syncthreads();

  float acc[4][8];
#pragma unroll
  for (int a = 0; a < 4; ++a)
#pragma unroll
    for (int px = 0; px < 8; ++px) acc[a][px] = 0.f;

  const int CHUNKS = CIN / 8;
  unsigned chunkOff = 0;
  for (int c = 0; c < CHUNKS; ++c) {
    if (c + 1 < CHUNKS) {
      chunkOff += 8u * NPIX;
#pragma unroll
      for (int k = 0; k < 7; ++k) stg[k] = in[off[k] + chunkOff];
      const float* gw = wT + (size_t)(c + 1) * 4608;
      float* lw = lds_w[(c + 1) & 1];
#pragma unroll
      for (int i = 0; i < 5; ++i) {
        int s = wave + (i << 2);
        if (s < 18) GLD_LDS16(gw + s * 256 + lane * 4, lw + s * 256);
      }
    }
    const float* wch = lds_w[c & 1];
    const float* lbase = lds_in[c & 1] + rowg * 36 + colg * 8;
    for (int ch = 0; ch < 8; ++ch) {
      float rin[3][10];
#pragma unroll
      for (int rr = 0; rr < 3; ++rr) {
        const float* rp = lbase + ch * 216 + rr * 36;
        float4 q0 = *reinterpret_cast<const float4*>(rp);
        float4 q1 = *reinterpret_cast<const float4*>(rp + 4);
        float2 q2 = *reinterpret_cast<const float2*>(rp + 8);
        rin[rr][0] = q0.x; rin[rr][1] = q0.y; rin[rr][2] = q0.z; rin[rr][3] = q0.w;
        rin[rr][4] = q1.x; rin[rr][5] = q1.y; rin[rr][6] = q1.z; rin[rr][7] = q1.w;
        rin[rr][8] = q2.x; rin[rr][9] = q2.y;
      }
      const float* wrow = wch + ch * 576 + co_g * 4;
#pragma unroll
      for (int t = 0; t < 9; ++t) {
        const float4 w4 = *reinterpret_cast<const float4*>(wrow + t * 64);
        const int ky = t / 3, kx = t % 3;
#pragma unroll
        for (int px = 0; px < 8; ++px) {
          const float iv = rin[ky][px + kx];
          acc[0][px] = fmaf(iv, w4.x, acc[0][px]);
          acc[1][px] = fmaf(iv, w4.y, acc[1][px]);
          acc[2][px] = fmaf(iv, w4.z, acc[2][px]);
          acc[3][px] = fmaf(iv, w4.w, acc[3][px]);
        }
      }
    }
    if (c + 1 < CHUNKS) {
      float* pb = lds_in[(c + 1) & 1];
#pragma unroll
      for (int k = 0; k < 7; ++k) {
        int L = tid + k * 256;
        if (L < 1728) pb[L] = okf[k] ? stg[k] : 0.f;
      }
      __syncthreads();
    }
  }

  const int cbase = co_g * 4;
  float4 a4[10];
#pragma unroll
  for (int k = 0; k < 10; ++k) {
    if (cbase + 3 < TDIM) a4[k] = *reinterpret_cast<const float4*>(anchor_vecs + k * TDIM + cbase);
    else a4[k] = make_float4(0.f, 0.f, 0.f, 0.f);
  }
  float bh[4], th[4];
#pragma unroll
  for (int co = 0; co < 4; ++co) {
    int cc = cbase + co;
    bh[co] = (cc < TDIM) ? b_hm[cc] : 0.f;
    th[co] = (float)(TH_LO + (double)(cc % 20) * TH_STEP);
  }
  const float s  = thr_scale[0];
  const float ls = logit_scale[0];
  const float lb = logit_bias[0];

  float hmv[8];
#pragma unroll
  for (int px = 0; px < 8; ++px) {
    float v[4];
#pragma unroll
    for (int co = 0; co < 4; ++co) {
      if (cbase + co < TDIM) {
        float z = acc[co][px] + bh[co];
        float t = (z - th[co]) * s;
        v[co] = 1.f / (1.f + expf(-t));
      } else v[co] = 0.f;
    }
    float s2 = v[0]*v[0] + v[1]*v[1] + v[2]*v[2] + v[3]*v[3];
    float dp[10];
#pragma unroll
    for (int k = 0; k < 10; ++k)
      dp[k] = v[0]*a4[k].x + v[1]*a4[k].y + v[2]*a4[k].z + v[3]*a4[k].w;
#pragma unroll
    for (int o = 1; o < 16; o <<= 1) {
      s2 += __shfl_xor(s2, o, 16);
#pragma unroll
      for (int k = 0; k < 10; ++k) dp[k] += __shfl_xor(dp[k], o, 16);
    }
    float dk = dp[0];
#pragma unroll
    for (int k = 1; k < 10; ++k) if (co_g == k) dk = dp[k];
    float sim = dk / (1e-8f + sqrtf(s2));
    hmv[px] = 1.f / (1.f + expf(-fmaf(ls, sim, lb)));
  }

  const int xb = x0 + colg * 8;
  if (xb >= HW || co_g >= NCLS) return;
  const bool full = (xb + 8 <= HW);
  const int yo = y0 + rowg;
  float* op = heatmap + (((size_t)b * NCLS + co_g) * HW + yo) * HW + xb;
  *reinterpret_cast<float4*>(op) = make_float4(hmv[0], hmv[1], hmv[2], hmv[3]);
  if (full) *reinterpret_cast<float4*>(op + 4) = make_float4(hmv[4], hmv[5], hmv[6], hmv[7]);
}

__global__ void sims_kernel(float* __restrict__ out_sims) {
  int t = threadIdx.x;
  if (t < 100) {
    int i = t / 10, j = t % 10;
    float r = 1.f;
#pragma unroll
    for (int d = 0; d < 3; ++d) {
      float ai = c_anchors[i][d], aj = c_anchors[j][d];
      r *= fminf(ai, aj) / fmaxf(ai, aj);
    }
    out_sims[t] = r;
  }
}

// NMS + two-level compaction (LDS atomics, <=2 global atomics per block).
__global__ __launch_bounds__(256)
void nms_kernel(const float* __restrict__ hm, float* __restrict__ ckey,
                int* __restrict__ cidx, int* __restrict__ cnt) {
  __shared__ int lcnt[2];
  __shared__ int lbase[2];
  const int tid = threadIdx.x;
  if (tid < 2) lcnt[tid] = 0;
  __syncthreads();

  int i = blockIdx.x * 256 + tid;
  bool surv = false; float v = 0.f; int bk = 0, p = 0;
  if (i < 2 * NBIG) {
    int x = i % HW; int y = (i / HW) % HW; int plane = i / NPIX;
    v = hm[i];
    float m = v;
#pragma unroll
    for (int dy = -1; dy <= 1; ++dy)
#pragma unroll
      for (int dx = -1; dx <= 1; ++dx) {
        int yy = y + dy, xx = x + dx;
        if ((unsigned)yy < (unsigned)HW && (unsigned)xx < (unsigned)HW)
          m = fmaxf(m, hm[((size_t)plane * NPIX) + yy * HW + xx]);
      }
    if (v == m) {
      surv = true;
      bk = i / NBIG;
      p = atomicAdd(&lcnt[bk], 1);
    }
  }
  __syncthreads();
  if (tid < 2 && lcnt[tid] > 0)
    lbase[tid] = atomicAdd(&cnt[tid], lcnt[tid]);
  __syncthreads();
  if (surv) {
    int slot = lbase[bk] + p;
    ckey[(size_t)bk * NBIG + slot] = v;
    cidx[(size_t)bk * NBIG + slot] = i - bk * NBIG;
  }
}

__global__ __launch_bounds__(1024)
void topk_kernel(const float* __restrict__ ckey, const int* __restrict__ cidx,
                 const int* __restrict__ cnt, const float* __restrict__ heatmap,
                 const float* __restrict__ bev_pos, float* __restrict__ out,
                 int* __restrict__ iws) {
  const int b = blockIdx.x;
  const int tid = threadIdx.x;
  const float* keys = ckey + (size_t)b * NBIG;
  const int* idxs = cidx + (size_t)b * NBIG;

  __shared__ unsigned hist[256];
  __shared__ unsigned sh_prefix;
  __shared__ int sh_want, sh_n;
  __shared__ int cntGT, cntTie;
  __shared__ unsigned gt_key[256], gt_idx[256];
  __shared__ unsigned tie_idx[2048];

  if (tid == 0) sh_n = cnt[b];
  __syncthreads();
  const int n = sh_n;

  unsigned prefix = 0; int want = NPROP;
  for (int shift = 24; shift >= 0; shift -= 8) {
    if (tid < 256) hist[tid] = 0u;
    __syncthreads();
    for (int i = tid; i < n; i += 1024) {
      unsigned k = __float_as_uint(keys[i]);
      bool match = (shift == 24) || ((k >> (shift + 8)) == (prefix >> (shift + 8)));
      if (match) atomicAdd(&hist[(k >> shift) & 255], 1u);
    }
    __syncthreads();
    if (tid == 0) {
      int cum = 0; int bsel = 0; sh_want = want;
      for (int bin = 255; bin >= 0; --bin) {
        cum += (int)hist[bin];
        if (cum >= want) { bsel = bin; sh_want = want - (cum - (int)hist[bin]); break; }
      }
      sh_prefix = prefix | ((unsigned)bsel << shift);
      cntGT = 0; cntTie = 0;
    }
    __syncthreads();
    prefix = sh_prefix; want = sh_want;
    __syncthreads();
  }
  const unsigned T = prefix;

  for (int i = tid; i < n; i += 1024) {
    unsigned k = __float_as_uint(keys[i]);
    if (k > T) {
      int p = atomicAdd(&cntGT, 1);
      if (p < 256) { gt_key[p] = k; gt_idx[p] = (unsigned)idxs[i]; }
    } else if (k == T) {
      int p = atomicAdd(&cntTie, 1);
      if (p < 2048) tie_idx[p] = (unsigned)idxs[i];
    }
  }
  __syncthreads();
  const int nGT = min(cntGT, 256);
  const int nTie = min(cntTie, 2048);

  for (int i = tid; i < 256; i += 1024)
    if (i >= nGT) { gt_key[i] = 0u; gt_idx[i] = 0xFFFFFFFFu; }
  for (int i = tid; i < 2048; i += 1024)
    if (i >= nTie) tie_idx[i] = 0xFFFFFFFFu;
  __syncthreads();

  for (int k2 = 2; k2 <= 256; k2 <<= 1) {
    for (int j = k2 >> 1; j > 0; j >>= 1) {
      for (int i = tid; i < 256; i += 1024) {
        int ixj = i ^ j;
        if (ixj > i) {
          unsigned ka = gt_key[i], kb = gt_key[ixj];
          unsigned ia = gt_idx[i], ib = gt_idx[ixj];
          bool firstA = (ka > kb) || (ka == kb && ia < ib);
          bool up = ((i & k2) == 0);
          if (up ? !firstA : firstA) {
            gt_key[i] = kb; gt_key[ixj] = ka;
            gt_idx[i] = ib; gt_idx[ixj] = ia;
          }
        }
      }
      __syncthreads();
    }
  }
  for (int k2 = 2; k2 <= 2048; k2 <<= 1) {
    for (int j = k2 >> 1; j > 0; j >>= 1) {
      for (int i = tid; i < 2048; i += 1024) {
        int ixj = i ^ j;
        if (ixj > i) {
          unsigned ia = tie_idx[i], ib = tie_idx[ixj];
          bool firstA = ia < ib;
          bool up = ((i & k2) == 0);
          if (up ? !firstA : firstA) { tie_idx[i] = ib; tie_idx[ixj] = ia; }
        }
      }
      __syncthreads();
    }
  }

  for (int r = tid; r < NPROP; r += 1024) {
    unsigned idx; float score;
    if (r < nGT) { idx = gt_idx[r]; score = __uint_as_float(gt_key[r]); }
    else         { idx = tie_idx[r - nGT]; score = __uint_as_float(T); }
    int label = (int)(idx / NPIX);
    int pos = (int)(idx - (unsigned)label * NPIX);
    out[648000 + b * NPROP + r] = score;
    out[648400 + b * NPROP + r] = (float)label;
    out[700000 + (b * NPROP + r) * 2 + 0] = bev_pos[pos * 2 + 0];
    out[700000 + (b * NPROP + r) * 2 + 1] = bev_pos[pos * 2 + 1];
#pragma unroll
    for (int k = 0; k < NCLS; ++k)
      out[700800 + (b * NCLS + k) * NPROP + r] = heatmap[(size_t)(b * NCLS + k) * NPIX + pos];
    iws[b * NPROP + r] = pos;
    iws[2 * NPROP + b * NPROP + r] = label;
  }
}

// lidar is NHWC-chunked fp32: [b][4][px][32]
__global__ void gather_qf_kernel(const float* __restrict__ lidar, const float* __restrict__ w_enc,
                                 const int* __restrict__ iws, float* __restrict__ out_qf) {
  int p = blockIdx.x % NPROP;
  int b = blockIdx.x / NPROP;
  int c = threadIdx.x;
  int pos = iws[b * NPROP + p];
  int label = iws[2 * NPROP + b * NPROP + p];
  float la0 = logf(c_anchors[label][0]);
  float la1 = logf(c_anchors[label][1]);
  float la2 = logf(c_anchors[label][2]);
  float dot = w_enc[c * 3 + 0] * la0 + w_enc[c * 3 + 1] * la1 + w_enc[c * 3 + 2] * la2;
  float g = lidar[((size_t)(b * 4 + (c >> 5)) * NPIX + pos) * 32 + (c & 31)];
  out_qf[((size_t)b * HID + c) * NPROP + p] = g + dot;
}

extern "C" void kernel_launch(void* const* d_in, const int* in_sizes, int n_in,
                              void* d_out, int out_size, void* d_ws, size_t ws_size,
                              hipStream_t stream) {
  (void)in_sizes; (void)n_in; (void)out_size; (void)ws_size;
  const float* feats       = (const float*)d_in[0];
  const float* w_shared    = (const float*)d_in[1];
  const float* b_shared    = (const float*)d_in[2];
  const float* w_bb        = (const float*)d_in[3];
  const float* gamma_bb    = (const float*)d_in[4];
  const float* beta_bb     = (const float*)d_in[5];
  const float* w_hm        = (const float*)d_in[6];
  const float* b_hm        = (const float*)d_in[7];
  const float* thr_scale   = (const float*)d_in[8];
  const float* logit_scale = (const float*)d_in[9];
  const float* logit_bias  = (const float*)d_in[10];
  const float* w_enc       = (const float*)d_in[11];
  const float* anchor_vecs = (const float*)d_in[12];
  const float* bev_pos     = (const float*)d_in[13];
  float* out = (float*)d_out;

  float* ws = (float*)d_ws;
  size_t off = 0;
  _Float16* X1 = (_Float16*)(ws + off); off += 33177600;   // 2 planes x 33.18M f16
  _Float16* X2 = (_Float16*)(ws + off); off += 8294400;    // 2 planes x 8.29M f16
  float* lidarN = ws + off; off += 8294400;                // NHWC fp32
  float* xbb    = ws + off; off += 8294400;                // NCHW fp32
  _Float16* W1 = (_Float16*)(ws + off); off += 589824;     // 2h x 16ks x 36864 f16
  _Float16* W2 = (_Float16*)(ws + off); off += 147456;     // 2h x 4ks  x 36864 f16
  float* wT3   = ws + off; off += 73728;
  float* ckey  = ws + off; off += (size_t)2 * NBIG;
  int*   cidx  = (int*)(ws + off); off += (size_t)2 * NBIG;
  int*   iws   = (int*)(ws + off); off += 800;
  int*   cnt   = (int*)(ws + off);

  transpose_w_kernel<<<(128*9*64 + 255)/256, 256, 0, stream>>>(w_hm, wT3, 128, 60, 1);
  transpose_w_mfma<512,16,2><<<(2*16*36864 + 255)/256, 256, 0, stream>>>(w_shared, W1);
  transpose_w_mfma<128, 4,2><<<(2*4*36864  + 255)/256, 256, 0, stream>>>(w_bb, W2);
  convert_feats<<<dim3(127, 32), 256, 0, stream>>>(feats, X1);

  dim3 cgrid(12, 23, 4);   // x-tiles(16), y-tiles(8), b*half
  conv_mfma<16,0><<<cgrid, 256, 0, stream>>>(X1, W1, b_shared, nullptr, lidarN, X2);
  conv_mfma<4, 1><<<cgrid, 256, 0, stream>>>(X2, W2, gamma_bb, beta_bb, xbb, nullptr);

  dim3 hgrid(6, 45, 2);
  conv3_head_kernel<<<hgrid, 256, 0, stream>>>(xbb, wT3, b_hm, anchor_vecs,
                                               thr_scale, logit_scale, logit_bias, out);

  sims_kernel<<<1, 128, 0, stream>>>(out + 704800);
  hipMemsetAsync(cnt, 0, 2 * sizeof(int), stream);
  nms_kernel<<<(2*NBIG + 255)/256, 256, 0, stream>>>(out, ckey, cidx, cnt);
  topk_kernel<<<2, 1024, 0, stream>>>(ckey, cidx, cnt, out, bev_pos, out, iws);
  gather_qf_kernel<<<2*NPROP, 128, 0, stream>>>(lidarN, w_enc, iws, out + 648800);
}

// Round 10
// 727.989 us; speedup vs baseline: 4.5569x; 1.0022x over previous
//
#include <hip/hip_runtime.h>
#include <math.h>

// TransFusionHead anchor matching — round 10: 16x16 MFMA conv tile + dynamic LDS.
// r9: conv1 43.8% MfmaUtil, 4 vmcnt(0) drains per ks vs only ~216 MFMA/wave.
// r10: tile 16x16 px (r6's verified staging map/epilogue) + r9's W-through-LDS
// phases; X(41.5K)+W-plane(36K) = 78,336 B dynamic LDS, 2 blocks/CU.
// Compute per barrier doubles; W DMA per MFMA halves. Rest unchanged.

#define HW 180
#define NPIX 32400
#define NCLS 10
#define NPROP 200
#define HID 128
#define TDIM 60
#define NBIG (NCLS*NPIX)

#define TH_LO  (-0.9915981193)
#define TH_STEP (0.1789675812)

__constant__ float c_anchors[10][3] = {
  {4.63f,1.97f,1.74f},{6.93f,2.51f,2.84f},{6.37f,2.85f,3.19f},{10.5f,2.94f,3.47f},
  {12.29f,2.9f,3.87f},{0.5f,2.53f,0.98f},{2.11f,0.77f,1.47f},{1.7f,0.6f,1.28f},
  {0.73f,0.67f,1.77f},{0.41f,0.41f,1.07f}};

using f16x8 = _Float16 __attribute__((ext_vector_type(8)));
using f16x4 = _Float16 __attribute__((ext_vector_type(4)));
using f32x4 = float    __attribute__((ext_vector_type(4)));

#define GLD_LDS16(g, l) __builtin_amdgcn_global_load_lds( \
    (__attribute__((address_space(1))) void*)(g), \
    (__attribute__((address_space(3))) void*)(l), 16, 0, 0)

// ---------- conv3 weight transpose ----------
__global__ void transpose_w_kernel(const float* __restrict__ src, float* __restrict__ dst,
                                   int cin, int cout, int halves) {
  int i = blockIdx.x * 256 + threadIdx.x;
  int n = halves * cin * 9 * 64;
  if (i >= n) return;
  int cq = i & 63;
  int t  = (i >> 6) % 9;
  int rest = i / (64 * 9);
  int c = rest % cin;
  int h = rest / cin;
  int co = h * 64 + cq;
  dst[i] = (co < cout) ? src[((size_t)co * cin + c) * 9 + t] : 0.f;
}

// ---------- MFMA weight prepack: [h][ks][plane][t][mf][lane][8] ----------
// per-(h,ks) slice = 2*9*4*512 = 36864 f16.
template<int CIN, int KS, int HALVES>
__global__ void transpose_w_mfma(const float* __restrict__ w, _Float16* __restrict__ dst) {
  const int N = HALVES * KS * 36864;
  int i = blockIdx.x * 256 + threadIdx.x;
  if (i >= N) return;
  int j = i & 7;
  int lane = (i >> 3) & 63;
  int mf = (i >> 9) & 3;
  int rest = i >> 11;
  int t = rest % 9; rest /= 9;
  int plane = rest & 1; rest >>= 1;
  int ks = rest % KS; int h = rest / KS;
  int co = h * 64 + mf * 16 + (lane & 15);
  int ch = ks * 32 + (lane >> 4) * 8 + j;
  float v = w[((size_t)co * CIN + ch) * 9 + t];
  _Float16 hi = (_Float16)v;
  dst[i] = plane ? (_Float16)(v - (float)hi) : hi;
}

// ---------- feats fp32 NCHW -> X1 hi/lo f16 [b][16ks][px][32] ----------
__global__ __launch_bounds__(256)
void convert_feats(const float* __restrict__ feats, _Float16* __restrict__ X1) {
  int px = blockIdx.x * 256 + threadIdx.x;
  int b = blockIdx.y >> 4, ks = blockIdx.y & 15;
  if (px >= NPIX) return;
  const float* src = feats + ((size_t)(b * 512 + ks * 32)) * NPIX + px;
  float v[32];
#pragma unroll
  for (int c = 0; c < 32; ++c) v[c] = src[(size_t)c * NPIX];
  f16x8 hv[4], lv[4];
#pragma unroll
  for (int c = 0; c < 32; ++c) {
    _Float16 h = (_Float16)v[c];
    hv[c >> 3][c & 7] = h;
    lv[c >> 3][c & 7] = (_Float16)(v[c] - (float)h);
  }
  size_t ob = ((size_t)(b * 16 + ks) * NPIX + px) * 32;
#pragma unroll
  for (int i = 0; i < 4; ++i) {
    *(f16x8*)(X1 + ob + i * 8) = hv[i];
    *(f16x8*)(X1 + 33177600u + ob + i * 8) = lv[i];
  }
}

// ---------- split-fp16 MFMA conv3x3, tile 16x16 px x 64 co ----------
// Dynamic LDS: X 18x18x32ch x2pl (41472 B) + ONE W plane (36864 B) = 78336 B.
// 4 waves; wave w rows 4w..4w+3 (f 0..3), 4 m-frags.
// Per ks: [A] DMA X+Whi [B] hi-phase (ah*bh + ah*bl) [C] DMA Wlo [D] lo (al*bh).
template<int KS, int EPI>
__global__ __launch_bounds__(256, 2)
void conv_mfma(const _Float16* __restrict__ X, const _Float16* __restrict__ W,
               const float* __restrict__ p0, const float* __restrict__ p1,
               float* __restrict__ out0, _Float16* __restrict__ outX) {
  constexpr unsigned XPS = 2u * KS * NPIX * 32;   // f16 per activation plane
  extern __shared__ _Float16 dlds[];
  _Float16* lds_x = dlds;            // hi [0,10368), lo [10368,20736)
  _Float16* lds_w = dlds + 20736;    // 18432 f16 (one W plane)

  const int x0 = blockIdx.x * 16;
  const int y0 = blockIdx.y * 16;
  const int b  = blockIdx.z >> 1;
  const int h  = blockIdx.z & 1;
  const int tid = threadIdx.x;
  const int wave = tid >> 6;
  const int lane = tid & 63;
  const int xl = lane & 15, kg = lane >> 4;

  // zero X region once (halo slots stay zero; masked DMA lanes never write)
  {
    unsigned* p = (unsigned*)lds_x;
    for (int i = tid; i < 10368; i += 256) p[i] = 0u;
  }

  // X staging map: 2592 16B-chunks (hi 1296 + lo 1296), 41 wave-insts.
  unsigned offs[11]; unsigned okb = 0;
#pragma unroll
  for (int s = 0; s < 11; ++s) {
    int inst = wave + 4 * s;
    int c = inst * 64 + lane;
    bool valid = (inst < 41) && (c < 2592);
    int plane = (c >= 1296) ? 1 : 0;
    int cc = c - plane * 1296;
    int px = cc >> 2, q = cc & 3;
    int r = px / 18, xx = px - r * 18;
    int gy = y0 - 1 + r, gx = x0 - 1 + xx;
    bool ok = valid && ((unsigned)gy < 180u) && ((unsigned)gx < 180u);
    offs[s] = ok ? ((unsigned)((b * KS) * NPIX + gy * 180 + gx) * 32u + (unsigned)q * 8u
                    + (unsigned)plane * XPS) : 0u;
    okb |= (ok ? 1u : 0u) << s;
  }

  f32x4 acc[4][4];
#pragma unroll
  for (int mf = 0; mf < 4; ++mf)
#pragma unroll
    for (int f = 0; f < 4; ++f) acc[mf][f] = (f32x4){0.f, 0.f, 0.f, 0.f};

  const _Float16* gwb = W + (size_t)(h * KS) * 36864;
  for (int ks = 0; ks < KS; ++ks) {
    __syncthreads();                       // A: prior reads of X/W done
    const unsigned kof = (unsigned)ks * (NPIX * 32u);
#pragma unroll
    for (int s = 0; s < 11; ++s) {
      if (okb & (1u << s))
        GLD_LDS16(X + (size_t)(offs[s] + kof), lds_x + (wave + 4 * s) * 512);
    }
    const _Float16* gw = gwb + (size_t)ks * 36864;
#pragma unroll
    for (int s = 0; s < 9; ++s) {          // W-hi plane: 36 chunks
      int c2 = wave + 4 * s;
      GLD_LDS16(gw + c2 * 512 + lane * 8, lds_w + c2 * 512);
    }
    __syncthreads();                       // B: X + W-hi ready

#pragma unroll
    for (int t = 0; t < 9; ++t) {
      const int ky = t / 3, kx = t % 3;
      f16x8 bh[4], bl[4];
#pragma unroll
      for (int f = 0; f < 4; ++f) {
        int R = 4 * wave + f;
        int lo = ((R + ky) * 18 + xl + kx) * 32 + kg * 8;
        bh[f] = *(const f16x8*)(lds_x + lo);
        bl[f] = *(const f16x8*)(lds_x + 10368 + lo);
      }
      const _Float16* wt = lds_w + t * 2048 + lane * 8;
      f16x8 ah[4];
#pragma unroll
      for (int mf = 0; mf < 4; ++mf) ah[mf] = *(const f16x8*)(wt + mf * 512);
#pragma unroll
      for (int mf = 0; mf < 4; ++mf)
#pragma unroll
        for (int f = 0; f < 4; ++f) {
          acc[mf][f] = __builtin_amdgcn_mfma_f32_16x16x32_f16(ah[mf], bh[f], acc[mf][f], 0, 0, 0);
          acc[mf][f] = __builtin_amdgcn_mfma_f32_16x16x32_f16(ah[mf], bl[f], acc[mf][f], 0, 0, 0);
        }
    }
    __syncthreads();                       // C: W-hi reads done
#pragma unroll
    for (int s = 0; s < 9; ++s) {          // W-lo plane into same buffer
      int c2 = wave + 4 * s;
      GLD_LDS16(gw + 18432 + c2 * 512 + lane * 8, lds_w + c2 * 512);
    }
    __syncthreads();                       // D: W-lo ready

#pragma unroll
    for (int t = 0; t < 9; ++t) {
      const int ky = t / 3, kx = t % 3;
      f16x8 bh[4];
#pragma unroll
      for (int f = 0; f < 4; ++f) {
        int R = 4 * wave + f;
        int lo = ((R + ky) * 18 + xl + kx) * 32 + kg * 8;
        bh[f] = *(const f16x8*)(lds_x + lo);
      }
      const _Float16* wt = lds_w + t * 2048 + lane * 8;
      f16x8 al[4];
#pragma unroll
      for (int mf = 0; mf < 4; ++mf) al[mf] = *(const f16x8*)(wt + mf * 512);
#pragma unroll
      for (int mf = 0; mf < 4; ++mf)
#pragma unroll
        for (int f = 0; f < 4; ++f)
          acc[mf][f] = __builtin_amdgcn_mfma_f32_16x16x32_f16(al[mf], bh[f], acc[mf][f], 0, 0, 0);
    }
  }

  // ---- epilogue: C frag col=lane&15 (pixel x), row=kg*4+r (cout) ----
  const int x = x0 + xl;
  if (x >= HW) return;
#pragma unroll
  for (int mf = 0; mf < 4; ++mf) {
    const int cobase = h * 64 + mf * 16 + kg * 4;
    f32x4 q0 = *(const f32x4*)(p0 + cobase);
    f32x4 q1 = (EPI == 1) ? *(const f32x4*)(p1 + cobase) : (f32x4){0.f,0.f,0.f,0.f};
#pragma unroll
    for (int f = 0; f < 4; ++f) {
      const int y = y0 + 4 * wave + f;
      if (y >= HW) continue;
      if (EPI == 0) {
        f32x4 v;
        f16x4 h4, l4;
#pragma unroll
        for (int r = 0; r < 4; ++r) {
          float z = acc[mf][f][r] + q0[r];
          v[r] = z;
          _Float16 hh = (_Float16)z;
          h4[r] = hh;
          l4[r] = (_Float16)(z - (float)hh);
        }
        const int kso = cobase >> 5, c32 = cobase & 31;
        size_t nidx = ((size_t)(b * 4 + kso) * NPIX + (size_t)y * 180 + x) * 32 + c32;
        *(f32x4*)(out0 + nidx) = v;
        *(f16x4*)(outX + nidx) = h4;
        *(f16x4*)(outX + 8294400u + nidx) = l4;
      } else {
#pragma unroll
        for (int r = 0; r < 4; ++r) {
          float z = fmaf(acc[mf][f][r], q0[r], q1[r]);
          z = fmaxf(z, 0.f);
          out0[((size_t)(b * 128 + cobase + r)) * NPIX + (size_t)y * 180 + x] = z;
        }
      }
    }
  }
}

// ---------- conv3 (128->60 pad 64) + head, fp32 (unchanged) ----------
__global__ __launch_bounds__(256, 3)
void conv3_head_kernel(const float* __restrict__ in, const float* __restrict__ wT,
                       const float* __restrict__ b_hm, const float* __restrict__ anchor_vecs,
                       const float* __restrict__ thr_scale, const float* __restrict__ logit_scale,
                       const float* __restrict__ logit_bias, float* __restrict__ heatmap) {
  const int CIN = 128;
  __shared__ float lds_in[2][1728];
  __shared__ float lds_w[2][4608];
  const int x0 = blockIdx.x * 32;
  const int y0 = blockIdx.y * 4;
  const int b  = blockIdx.z;
  const int tid  = threadIdx.x;
  const int co_g = tid & 15;
  const int pg   = tid >> 4;
  const int colg = pg & 3;
  const int rowg = pg >> 2;
  const int wave = tid >> 6;
  const int lane = tid & 63;

  unsigned off[7]; bool okf[7];
#pragma unroll
  for (int k = 0; k < 7; ++k) {
    int L = tid + k * 256;
    int ch = L / 216; int rem = L - ch * 216;
    int r = rem / 36; int x = rem - r * 36;
    int y = y0 + r - 1; int gx = x0 + x - 1;
    bool ok = (L < 1728) && ((unsigned)y < (unsigned)HW) && ((unsigned)gx < (unsigned)HW);
    okf[k] = ok;
    off[k] = ok ? (unsigned)(((b * CIN + ch) * HW + y) * HW + gx) : 0u;
  }

  float stg[7];
#pragma unroll
  for (int k = 0; k < 7; ++k) stg[k] = in[off[k]];
#pragma unroll
  for (int i = 0; i < 5; ++i) {
    int s = wave + (i << 2);
    if (s < 18) GLD_LDS16(wT + s * 256 + lane * 4, &lds_w[0][s * 256]);
  }
  {
    float* pb = lds_in[0];
#pragma unroll
    for (int k = 0; k < 7; ++k) {
      int L = tid + k * 256;
      if (L < 1728) pb[L] = okf[k] ? stg[k] : 0.f;
    }
  }
  __syncthreads();

  float acc[4][8];
#pragma unroll
  for (int a = 0; a < 4; ++a)
#pragma unroll
    for (int px = 0; px < 8; ++px) acc[a][px] = 0.f;

  const int CHUNKS = CIN / 8;
  unsigned chunkOff = 0;
  for (int c = 0; c < CHUNKS; ++c) {
    if (c + 1 < CHUNKS) {
      chunkOff += 8u * NPIX;
#pragma unroll
      for (int k = 0; k < 7; ++k) stg[k] = in[off[k] + chunkOff];
      const float* gw = wT + (size_t)(c + 1) * 4608;
      float* lw = lds_w[(c + 1) & 1];
#pragma unroll
      for (int i = 0; i < 5; ++i) {
        int s = wave + (i << 2);
        if (s < 18) GLD_LDS16(gw + s * 256 + lane * 4, lw + s * 256);
      }
    }
    const float* wch = lds_w[c & 1];
    const float* lbase = lds_in[c & 1] + rowg * 36 + colg * 8;
    for (int ch = 0; ch < 8; ++ch) {
      float rin[3][10];
#pragma unroll
      for (int rr = 0; rr < 3; ++rr) {
        const float* rp = lbase + ch * 216 + rr * 36;
        float4 q0 = *reinterpret_cast<const float4*>(rp);
        float4 q1 = *reinterpret_cast<const float4*>(rp + 4);
        float2 q2 = *reinterpret_cast<const float2*>(rp + 8);
        rin[rr][0] = q0.x; rin[rr][1] = q0.y; rin[rr][2] = q0.z; rin[rr][3] = q0.w;
        rin[rr][4] = q1.x; rin[rr][5] = q1.y; rin[rr][6] = q1.z; rin[rr][7] = q1.w;
        rin[rr][8] = q2.x; rin[rr][9] = q2.y;
      }
      const float* wrow = wch + ch * 576 + co_g * 4;
#pragma unroll
      for (int t = 0; t < 9; ++t) {
        const float4 w4 = *reinterpret_cast<const float4*>(wrow + t * 64);
        const int ky = t / 3, kx = t % 3;
#pragma unroll
        for (int px = 0; px < 8; ++px) {
          const float iv = rin[ky][px + kx];
          acc[0][px] = fmaf(iv, w4.x, acc[0][px]);
          acc[1][px] = fmaf(iv, w4.y, acc[1][px]);
          acc[2][px] = fmaf(iv, w4.z, acc[2][px]);
          acc[3][px] = fmaf(iv, w4.w, acc[3][px]);
        }
      }
    }
    if (c + 1 < CHUNKS) {
      float* pb = lds_in[(c + 1) & 1];
#pragma unroll
      for (int k = 0; k < 7; ++k) {
        int L = tid + k * 256;
        if (L < 1728) pb[L] = okf[k] ? stg[k] : 0.f;
      }
      __syncthreads();
    }
  }

  const int cbase = co_g * 4;
  float4 a4[10];
#pragma unroll
  for (int k = 0; k < 10; ++k) {
    if (cbase + 3 < TDIM) a4[k] = *reinterpret_cast<const float4*>(anchor_vecs + k * TDIM + cbase);
    else a4[k] = make_float4(0.f, 0.f, 0.f, 0.f);
  }
  float bh[4], th[4];
#pragma unroll
  for (int co = 0; co < 4; ++co) {
    int cc = cbase + co;
    bh[co] = (cc < TDIM) ? b_hm[cc] : 0.f;
    th[co] = (float)(TH_LO + (double)(cc % 20) * TH_STEP);
  }
  const float s  = thr_scale[0];
  const float ls = logit_scale[0];
  const float lb = logit_bias[0];

  float hmv[8];
#pragma unroll
  for (int px = 0; px < 8; ++px) {
    float v[4];
#pragma unroll
    for (int co = 0; co < 4; ++co) {
      if (cbase + co < TDIM) {
        float z = acc[co][px] + bh[co];
        float t = (z - th[co]) * s;
        v[co] = 1.f / (1.f + expf(-t));
      } else v[co] = 0.f;
    }
    float s2 = v[0]*v[0] + v[1]*v[1] + v[2]*v[2] + v[3]*v[3];
    float dp[10];
#pragma unroll
    for (int k = 0; k < 10; ++k)
      dp[k] = v[0]*a4[k].x + v[1]*a4[k].y + v[2]*a4[k].z + v[3]*a4[k].w;
#pragma unroll
    for (int o = 1; o < 16; o <<= 1) {
      s2 += __shfl_xor(s2, o, 16);
#pragma unroll
      for (int k = 0; k < 10; ++k) dp[k] += __shfl_xor(dp[k], o, 16);
    }
    float dk = dp[0];
#pragma unroll
    for (int k = 1; k < 10; ++k) if (co_g == k) dk = dp[k];
    float sim = dk / (1e-8f + sqrtf(s2));
    hmv[px] = 1.f / (1.f + expf(-fmaf(ls, sim, lb)));
  }

  const int xb = x0 + colg * 8;
  if (xb >= HW || co_g >= NCLS) return;
  const bool full = (xb + 8 <= HW);
  const int yo = y0 + rowg;
  float* op = heatmap + (((size_t)b * NCLS + co_g) * HW + yo) * HW + xb;
  *reinterpret_cast<float4*>(op) = make_float4(hmv[0], hmv[1], hmv[2], hmv[3]);
  if (full) *reinterpret_cast<float4*>(op + 4) = make_float4(hmv[4], hmv[5], hmv[6], hmv[7]);
}

__global__ void sims_kernel(float* __restrict__ out_sims) {
  int t = threadIdx.x;
  if (t < 100) {
    int i = t / 10, j = t % 10;
    float r = 1.f;
#pragma unroll
    for (int d = 0; d < 3; ++d) {
      float ai = c_anchors[i][d], aj = c_anchors[j][d];
      r *= fminf(ai, aj) / fmaxf(ai, aj);
    }
    out_sims[t] = r;
  }
}

// NMS + two-level compaction (LDS atomics, <=2 global atomics per block).
__global__ __launch_bounds__(256)
void nms_kernel(const float* __restrict__ hm, float* __restrict__ ckey,
                int* __restrict__ cidx, int* __restrict__ cnt) {
  __shared__ int lcnt[2];
  __shared__ int lbase[2];
  const int tid = threadIdx.x;
  if (tid < 2) lcnt[tid] = 0;
  __syncthreads();

  int i = blockIdx.x * 256 + tid;
  bool surv = false; float v = 0.f; int bk = 0, p = 0;
  if (i < 2 * NBIG) {
    int x = i % HW; int y = (i / HW) % HW; int plane = i / NPIX;
    v = hm[i];
    float m = v;
#pragma unroll
    for (int dy = -1; dy <= 1; ++dy)
#pragma unroll
      for (int dx = -1; dx <= 1; ++dx) {
        int yy = y + dy, xx = x + dx;
        if ((unsigned)yy < (unsigned)HW && (unsigned)xx < (unsigned)HW)
          m = fmaxf(m, hm[((size_t)plane * NPIX) + yy * HW + xx]);
      }
    if (v == m) {
      surv = true;
      bk = i / NBIG;
      p = atomicAdd(&lcnt[bk], 1);
    }
  }
  __syncthreads();
  if (tid < 2 && lcnt[tid] > 0)
    lbase[tid] = atomicAdd(&cnt[tid], lcnt[tid]);
  __syncthreads();
  if (surv) {
    int slot = lbase[bk] + p;
    ckey[(size_t)bk * NBIG + slot] = v;
    cidx[(size_t)bk * NBIG + slot] = i - bk * NBIG;
  }
}

__global__ __launch_bounds__(1024)
void topk_kernel(const float* __restrict__ ckey, const int* __restrict__ cidx,
                 const int* __restrict__ cnt, const float* __restrict__ heatmap,
                 const float* __restrict__ bev_pos, float* __restrict__ out,
                 int* __restrict__ iws) {
  const int b = blockIdx.x;
  const int tid = threadIdx.x;
  const float* keys = ckey + (size_t)b * NBIG;
  const int* idxs = cidx + (size_t)b * NBIG;

  __shared__ unsigned hist[256];
  __shared__ unsigned sh_prefix;
  __shared__ int sh_want, sh_n;
  __shared__ int cntGT, cntTie;
  __shared__ unsigned gt_key[256], gt_idx[256];
  __shared__ unsigned tie_idx[2048];

  if (tid == 0) sh_n = cnt[b];
  __syncthreads();
  const int n = sh_n;

  unsigned prefix = 0; int want = NPROP;
  for (int shift = 24; shift >= 0; shift -= 8) {
    if (tid < 256) hist[tid] = 0u;
    __syncthreads();
    for (int i = tid; i < n; i += 1024) {
      unsigned k = __float_as_uint(keys[i]);
      bool match = (shift == 24) || ((k >> (shift + 8)) == (prefix >> (shift + 8)));
      if (match) atomicAdd(&hist[(k >> shift) & 255], 1u);
    }
    __syncthreads();
    if (tid == 0) {
      int cum = 0; int bsel = 0; sh_want = want;
      for (int bin = 255; bin >= 0; --bin) {
        cum += (int)hist[bin];
        if (cum >= want) { bsel = bin; sh_want = want - (cum - (int)hist[bin]); break; }
      }
      sh_prefix = prefix | ((unsigned)bsel << shift);
      cntGT = 0; cntTie = 0;
    }
    __syncthreads();
    prefix = sh_prefix; want = sh_want;
    __syncthreads();
  }
  const unsigned T = prefix;

  for (int i = tid; i < n; i += 1024) {
    unsigned k = __float_as_uint(keys[i]);
    if (k > T) {
      int p = atomicAdd(&cntGT, 1);
      if (p < 256) { gt_key[p] = k; gt_idx[p] = (unsigned)idxs[i]; }
    } else if (k == T) {
      int p = atomicAdd(&cntTie, 1);
      if (p < 2048) tie_idx[p] = (unsigned)idxs[i];
    }
  }
  __syncthreads();
  const int nGT = min(cntGT, 256);
  const int nTie = min(cntTie, 2048);

  for (int i = tid; i < 256; i += 1024)
    if (i >= nGT) { gt_key[i] = 0u; gt_idx[i] = 0xFFFFFFFFu; }
  for (int i = tid; i < 2048; i += 1024)
    if (i >= nTie) tie_idx[i] = 0xFFFFFFFFu;
  __syncthreads();

  for (int k2 = 2; k2 <= 256; k2 <<= 1) {
    for (int j = k2 >> 1; j > 0; j >>= 1) {
      for (int i = tid; i < 256; i += 1024) {
        int ixj = i ^ j;
        if (ixj > i) {
          unsigned ka = gt_key[i], kb = gt_key[ixj];
          unsigned ia = gt_idx[i], ib = gt_idx[ixj];
          bool firstA = (ka > kb) || (ka == kb && ia < ib);
          bool up = ((i & k2) == 0);
          if (up ? !firstA : firstA) {
            gt_key[i] = kb; gt_key[ixj] = ka;
            gt_idx[i] = ib; gt_idx[ixj] = ia;
          }
        }
      }
      __syncthreads();
    }
  }
  for (int k2 = 2; k2 <= 2048; k2 <<= 1) {
    for (int j = k2 >> 1; j > 0; j >>= 1) {
      for (int i = tid; i < 2048; i += 1024) {
        int ixj = i ^ j;
        if (ixj > i) {
          unsigned ia = tie_idx[i], ib = tie_idx[ixj];
          bool firstA = ia < ib;
          bool up = ((i & k2) == 0);
          if (up ? !firstA : firstA) { tie_idx[i] = ib; tie_idx[ixj] = ia; }
        }
      }
      __syncthreads();
    }
  }

  for (int r = tid; r < NPROP; r += 1024) {
    unsigned idx; float score;
    if (r < nGT) { idx = gt_idx[r]; score = __uint_as_float(gt_key[r]); }
    else         { idx = tie_idx[r - nGT]; score = __uint_as_float(T); }
    int label = (int)(idx / NPIX);
    int pos = (int)(idx - (unsigned)label * NPIX);
    out[648000 + b * NPROP + r] = score;
    out[648400 + b * NPROP + r] = (float)label;
    out[700000 + (b * NPROP + r) * 2 + 0] = bev_pos[pos * 2 + 0];
    out[700000 + (b * NPROP + r) * 2 + 1] = bev_pos[pos * 2 + 1];
#pragma unroll
    for (int k = 0; k < NCLS; ++k)
      out[700800 + (b * NCLS + k) * NPROP + r] = heatmap[(size_t)(b * NCLS + k) * NPIX + pos];
    iws[b * NPROP + r] = pos;
    iws[2 * NPROP + b * NPROP + r] = label;
  }
}

// lidar is NHWC-chunked fp32: [b][4][px][32]
__global__ void gather_qf_kernel(const float* __restrict__ lidar, const float* __restrict__ w_enc,
                                 const int* __restrict__ iws, float* __restrict__ out_qf) {
  int p = blockIdx.x % NPROP;
  int b = blockIdx.x / NPROP;
  int c = threadIdx.x;
  int pos = iws[b * NPROP + p];
  int label = iws[2 * NPROP + b * NPROP + p];
  float la0 = logf(c_anchors[label][0]);
  float la1 = logf(c_anchors[label][1]);
  float la2 = logf(c_anchors[label][2]);
  float dot = w_enc[c * 3 + 0] * la0 + w_enc[c * 3 + 1] * la1 + w_enc[c * 3 + 2] * la2;
  float g = lidar[((size_t)(b * 4 + (c >> 5)) * NPIX + pos) * 32 + (c & 31)];
  out_qf[((size_t)b * HID + c) * NPROP + p] = g + dot;
}

extern "C" void kernel_launch(void* const* d_in, const int* in_sizes, int n_in,
                              void* d_out, int out_size, void* d_ws, size_t ws_size,
                              hipStream_t stream) {
  (void)in_sizes; (void)n_in; (void)out_size; (void)ws_size;
  const float* feats       = (const float*)d_in[0];
  const float* w_shared    = (const float*)d_in[1];
  const float* b_shared    = (const float*)d_in[2];
  const float* w_bb        = (const float*)d_in[3];
  const float* gamma_bb    = (const float*)d_in[4];
  const float* beta_bb     = (const float*)d_in[5];
  const float* w_hm        = (const float*)d_in[6];
  const float* b_hm        = (const float*)d_in[7];
  const float* thr_scale   = (const float*)d_in[8];
  const float* logit_scale = (const float*)d_in[9];
  const float* logit_bias  = (const float*)d_in[10];
  const float* w_enc       = (const float*)d_in[11];
  const float* anchor_vecs = (const float*)d_in[12];
  const float* bev_pos     = (const float*)d_in[13];
  float* out = (float*)d_out;

  float* ws = (float*)d_ws;
  size_t off = 0;
  _Float16* X1 = (_Float16*)(ws + off); off += 33177600;   // 2 planes x 33.18M f16
  _Float16* X2 = (_Float16*)(ws + off); off += 8294400;    // 2 planes x 8.29M f16
  float* lidarN = ws + off; off += 8294400;                // NHWC fp32
  float* xbb    = ws + off; off += 8294400;                // NCHW fp32
  _Float16* W1 = (_Float16*)(ws + off); off += 589824;     // 2h x 16ks x 36864 f16
  _Float16* W2 = (_Float16*)(ws + off); off += 147456;     // 2h x 4ks  x 36864 f16
  float* wT3   = ws + off; off += 73728;
  float* ckey  = ws + off; off += (size_t)2 * NBIG;
  int*   cidx  = (int*)(ws + off); off += (size_t)2 * NBIG;
  int*   iws   = (int*)(ws + off); off += 800;
  int*   cnt   = (int*)(ws + off);

  transpose_w_kernel<<<(128*9*64 + 255)/256, 256, 0, stream>>>(w_hm, wT3, 128, 60, 1);
  transpose_w_mfma<512,16,2><<<(2*16*36864 + 255)/256, 256, 0, stream>>>(w_shared, W1);
  transpose_w_mfma<128, 4,2><<<(2*4*36864  + 255)/256, 256, 0, stream>>>(w_bb, W2);
  convert_feats<<<dim3(127, 32), 256, 0, stream>>>(feats, X1);

  const unsigned CONV_LDS = (20736 + 18432) * sizeof(_Float16);   // 78336 B
  dim3 cgrid(12, 12, 4);   // x-tiles(16), y-tiles(16), b*half
  conv_mfma<16,0><<<cgrid, 256, CONV_LDS, stream>>>(X1, W1, b_shared, nullptr, lidarN, X2);
  conv_mfma<4, 1><<<cgrid, 256, CONV_LDS, stream>>>(X2, W2, gamma_bb, beta_bb, xbb, nullptr);

  dim3 hgrid(6, 45, 2);
  conv3_head_kernel<<<hgrid, 256, 0, stream>>>(xbb, wT3, b_hm, anchor_vecs,
                                               thr_scale, logit_scale, logit_bias, out);

  sims_kernel<<<1, 128, 0, stream>>>(out + 704800);
  hipMemsetAsync(cnt, 0, 2 * sizeof(int), stream);
  nms_kernel<<<(2*NBIG + 255)/256, 256, 0, stream>>>(out, ckey, cidx, cnt);
  topk_kernel<<<2, 1024, 0, stream>>>(ckey, cidx, cnt, out, bev_pos, out, iws);
  gather_qf_kernel<<<2*NPROP, 128, 0, stream>>>(lidarN, w_enc, iws, out + 648800);
}

// Round 11
// 586.277 us; speedup vs baseline: 5.6584x; 1.2417x over previous
//
#include <hip/hip_runtime.h>
#include <math.h>

// TransFusionHead anchor matching — round 11: conv3+head onto MFMA.
// r10 analysis: conv_mfma is LDS-read-BW bound (~45% MfmaUtil, model match).
// This round removes the last fp32 conv: conv2 now emits hi/lo f16 planes only
// (no NCHW f32 stores), conv3+head is conv_mfma<4,2> with the head math done
// in C-fragment layout (shfl_xor(16/32) cross-kg reduce, anchors in LDS).

#define HW 180
#define NPIX 32400
#define NCLS 10
#define NPROP 200
#define HID 128
#define TDIM 60
#define NBIG (NCLS*NPIX)

#define TH_LO  (-0.9915981193)
#define TH_STEP (0.1789675812)

__constant__ float c_anchors[10][3] = {
  {4.63f,1.97f,1.74f},{6.93f,2.51f,2.84f},{6.37f,2.85f,3.19f},{10.5f,2.94f,3.47f},
  {12.29f,2.9f,3.87f},{0.5f,2.53f,0.98f},{2.11f,0.77f,1.47f},{1.7f,0.6f,1.28f},
  {0.73f,0.67f,1.77f},{0.41f,0.41f,1.07f}};

using f16x8 = _Float16 __attribute__((ext_vector_type(8)));
using f16x4 = _Float16 __attribute__((ext_vector_type(4)));
using f32x4 = float    __attribute__((ext_vector_type(4)));

#define GLD_LDS16(g, l) __builtin_amdgcn_global_load_lds( \
    (__attribute__((address_space(1))) void*)(g), \
    (__attribute__((address_space(3))) void*)(l), 16, 0, 0)

// ---------- MFMA weight prepack: [h][ks][plane][t][mf][lane][8] ----------
// per-(h,ks) slice = 2*9*4*512 = 36864 f16.  cout-guarded (w_hm has 60 rows).
template<int CIN, int KS, int HALVES>
__global__ void transpose_w_mfma(const float* __restrict__ w, _Float16* __restrict__ dst,
                                 int cout) {
  const int N = HALVES * KS * 36864;
  int i = blockIdx.x * 256 + threadIdx.x;
  if (i >= N) return;
  int j = i & 7;
  int lane = (i >> 3) & 63;
  int mf = (i >> 9) & 3;
  int rest = i >> 11;
  int t = rest % 9; rest /= 9;
  int plane = rest & 1; rest >>= 1;
  int ks = rest % KS; int h = rest / KS;
  int co = h * 64 + mf * 16 + (lane & 15);
  int ch = ks * 32 + (lane >> 4) * 8 + j;
  float v = (co < cout) ? w[((size_t)co * CIN + ch) * 9 + t] : 0.f;
  _Float16 hi = (_Float16)v;
  dst[i] = plane ? (_Float16)(v - (float)hi) : hi;
}

// ---------- feats fp32 NCHW -> X1 hi/lo f16 [b][16ks][px][32] ----------
__global__ __launch_bounds__(256)
void convert_feats(const float* __restrict__ feats, _Float16* __restrict__ X1) {
  int px = blockIdx.x * 256 + threadIdx.x;
  int b = blockIdx.y >> 4, ks = blockIdx.y & 15;
  if (px >= NPIX) return;
  const float* src = feats + ((size_t)(b * 512 + ks * 32)) * NPIX + px;
  float v[32];
#pragma unroll
  for (int c = 0; c < 32; ++c) v[c] = src[(size_t)c * NPIX];
  f16x8 hv[4], lv[4];
#pragma unroll
  for (int c = 0; c < 32; ++c) {
    _Float16 h = (_Float16)v[c];
    hv[c >> 3][c & 7] = h;
    lv[c >> 3][c & 7] = (_Float16)(v[c] - (float)h);
  }
  size_t ob = ((size_t)(b * 16 + ks) * NPIX + px) * 32;
#pragma unroll
  for (int i = 0; i < 4; ++i) {
    *(f16x8*)(X1 + ob + i * 8) = hv[i];
    *(f16x8*)(X1 + 33177600u + ob + i * 8) = lv[i];
  }
}

// ---------- split-fp16 MFMA conv3x3, tile 16x16 px x 64 co ----------
// Dynamic LDS: X 18x18x32ch x2pl (41472 B) + ONE W plane (36864 B) [+ anchors
// 2400 B for EPI=2]. Per ks: [A] DMA X+Whi [B] hi (ah*bh + ah*bl) [C] DMA Wlo
// [D] lo (al*bh).
// EPI 0: +bias -> lidarN f32 NHWC + X2 hi/lo.  EPI 1: relu(bn) -> X3 hi/lo only.
// EPI 2: conv3 + threshold-sigmoid + L2-norm + anchor-sim + sigmoid -> heatmap.
template<int KS, int EPI>
__global__ __launch_bounds__(256, 2)
void conv_mfma(const _Float16* __restrict__ X, const _Float16* __restrict__ W,
               const float* __restrict__ p0, const float* __restrict__ p1,
               float* __restrict__ out0, _Float16* __restrict__ outX,
               const float* __restrict__ thr_scale, const float* __restrict__ logit_scale,
               const float* __restrict__ logit_bias, const float* __restrict__ anchor_vecs) {
  constexpr unsigned XPS = 2u * KS * NPIX * 32;   // f16 per activation plane
  extern __shared__ _Float16 dlds[];
  _Float16* lds_x = dlds;            // hi [0,10368), lo [10368,20736)
  _Float16* lds_w = dlds + 20736;    // 18432 f16 (one W plane)
  float* lds_av = (float*)(dlds + 39168);  // 600 f32 (EPI=2 only)

  const int x0 = blockIdx.x * 16;
  const int y0 = blockIdx.y * 16;
  const int b  = (EPI == 2) ? blockIdx.z : (blockIdx.z >> 1);
  const int h  = (EPI == 2) ? 0 : (blockIdx.z & 1);
  const int tid = threadIdx.x;
  const int wave = tid >> 6;
  const int lane = tid & 63;
  const int xl = lane & 15, kg = lane >> 4;

  // zero X region + stage anchors (first barrier orders these vs DMA)
  {
    unsigned* p = (unsigned*)lds_x;
    for (int i = tid; i < 10368; i += 256) p[i] = 0u;
    if (EPI == 2)
      for (int i = tid; i < 600; i += 256) lds_av[i] = anchor_vecs[i];
  }

  // X staging map: 2592 16B-chunks (hi 1296 + lo 1296), 41 wave-insts.
  unsigned offs[11]; unsigned okb = 0;
#pragma unroll
  for (int s = 0; s < 11; ++s) {
    int inst = wave + 4 * s;
    int c = inst * 64 + lane;
    bool valid = (inst < 41) && (c < 2592);
    int plane = (c >= 1296) ? 1 : 0;
    int cc = c - plane * 1296;
    int px = cc >> 2, q = cc & 3;
    int r = px / 18, xx = px - r * 18;
    int gy = y0 - 1 + r, gx = x0 - 1 + xx;
    bool ok = valid && ((unsigned)gy < 180u) && ((unsigned)gx < 180u);
    offs[s] = ok ? ((unsigned)((b * KS) * NPIX + gy * 180 + gx) * 32u + (unsigned)q * 8u
                    + (unsigned)plane * XPS) : 0u;
    okb |= (ok ? 1u : 0u) << s;
  }

  f32x4 acc[4][4];
#pragma unroll
  for (int mf = 0; mf < 4; ++mf)
#pragma unroll
    for (int f = 0; f < 4; ++f) acc[mf][f] = (f32x4){0.f, 0.f, 0.f, 0.f};

  const _Float16* gwb = W + (size_t)(h * KS) * 36864;
  for (int ks = 0; ks < KS; ++ks) {
    __syncthreads();                       // A: prior reads of X/W done
    const unsigned kof = (unsigned)ks * (NPIX * 32u);
#pragma unroll
    for (int s = 0; s < 11; ++s) {
      if (okb & (1u << s))
        GLD_LDS16(X + (size_t)(offs[s] + kof), lds_x + (wave + 4 * s) * 512);
    }
    const _Float16* gw = gwb + (size_t)ks * 36864;
#pragma unroll
    for (int s = 0; s < 9; ++s) {          // W-hi plane: 36 chunks
      int c2 = wave + 4 * s;
      GLD_LDS16(gw + c2 * 512 + lane * 8, lds_w + c2 * 512);
    }
    __syncthreads();                       // B: X + W-hi ready

#pragma unroll
    for (int t = 0; t < 9; ++t) {
      const int ky = t / 3, kx = t % 3;
      f16x8 bh[4], bl[4];
#pragma unroll
      for (int f = 0; f < 4; ++f) {
        int R = 4 * wave + f;
        int lo = ((R + ky) * 18 + xl + kx) * 32 + kg * 8;
        bh[f] = *(const f16x8*)(lds_x + lo);
        bl[f] = *(const f16x8*)(lds_x + 10368 + lo);
      }
      const _Float16* wt = lds_w + t * 2048 + lane * 8;
      f16x8 ah[4];
#pragma unroll
      for (int mf = 0; mf < 4; ++mf) ah[mf] = *(const f16x8*)(wt + mf * 512);
#pragma unroll
      for (int mf = 0; mf < 4; ++mf)
#pragma unroll
        for (int f = 0; f < 4; ++f) {
          acc[mf][f] = __builtin_amdgcn_mfma_f32_16x16x32_f16(ah[mf], bh[f], acc[mf][f], 0, 0, 0);
          acc[mf][f] = __builtin_amdgcn_mfma_f32_16x16x32_f16(ah[mf], bl[f], acc[mf][f], 0, 0, 0);
        }
    }
    __syncthreads();                       // C: W-hi reads done
#pragma unroll
    for (int s = 0; s < 9; ++s) {          // W-lo plane into same buffer
      int c2 = wave + 4 * s;
      GLD_LDS16(gw + 18432 + c2 * 512 + lane * 8, lds_w + c2 * 512);
    }
    __syncthreads();                       // D: W-lo ready

#pragma unroll
    for (int t = 0; t < 9; ++t) {
      const int ky = t / 3, kx = t % 3;
      f16x8 bh[4];
#pragma unroll
      for (int f = 0; f < 4; ++f) {
        int R = 4 * wave + f;
        int lo = ((R + ky) * 18 + xl + kx) * 32 + kg * 8;
        bh[f] = *(const f16x8*)(lds_x + lo);
      }
      const _Float16* wt = lds_w + t * 2048 + lane * 8;
      f16x8 al[4];
#pragma unroll
      for (int mf = 0; mf < 4; ++mf) al[mf] = *(const f16x8*)(wt + mf * 512);
#pragma unroll
      for (int mf = 0; mf < 4; ++mf)
#pragma unroll
        for (int f = 0; f < 4; ++f)
          acc[mf][f] = __builtin_amdgcn_mfma_f32_16x16x32_f16(al[mf], bh[f], acc[mf][f], 0, 0, 0);
    }
  }

  // ---- epilogue: C frag col=lane&15 (pixel x), row=kg*4+r (cout) ----
  const int x = x0 + xl;
  if (EPI != 2) {
    if (x >= HW) return;
#pragma unroll
    for (int mf = 0; mf < 4; ++mf) {
      const int cobase = h * 64 + mf * 16 + kg * 4;
      f32x4 q0 = *(const f32x4*)(p0 + cobase);
      f32x4 q1 = (EPI == 1) ? *(const f32x4*)(p1 + cobase) : (f32x4){0.f,0.f,0.f,0.f};
#pragma unroll
      for (int f = 0; f < 4; ++f) {
        const int y = y0 + 4 * wave + f;
        if (y >= HW) continue;
        const int kso = cobase >> 5, c32 = cobase & 31;
        size_t nidx = ((size_t)(b * 4 + kso) * NPIX + (size_t)y * 180 + x) * 32 + c32;
        if (EPI == 0) {
          f32x4 v;
          f16x4 h4, l4;
#pragma unroll
          for (int r = 0; r < 4; ++r) {
            float z = acc[mf][f][r] + q0[r];
            v[r] = z;
            _Float16 hh = (_Float16)z;
            h4[r] = hh;
            l4[r] = (_Float16)(z - (float)hh);
          }
          *(f32x4*)(out0 + nidx) = v;
          *(f16x4*)(outX + nidx) = h4;
          *(f16x4*)(outX + 8294400u + nidx) = l4;
        } else {
          f16x4 h4, l4;
#pragma unroll
          for (int r = 0; r < 4; ++r) {
            float z = fmaf(acc[mf][f][r], q0[r], q1[r]);
            z = fmaxf(z, 0.f);
            _Float16 hh = (_Float16)z;
            h4[r] = hh;
            l4[r] = (_Float16)(z - (float)hh);
          }
          *(f16x4*)(outX + nidx) = h4;
          *(f16x4*)(outX + 8294400u + nidx) = l4;
        }
      }
    }
  } else {
    // ---- fused head: threshold-sigmoid, L2 norm, anchor sim, sigmoid ----
    const float s  = thr_scale[0];
    const float ls = logit_scale[0];
    const float lb = logit_bias[0];
    float bh4[4][4], th4[4][4];
    bool vmask[4];
#pragma unroll
    for (int mf = 0; mf < 4; ++mf) {
      const int cb = mf * 16 + kg * 4;
      vmask[mf] = (cb < TDIM);           // cb==60 only for mf=3,kg=3
#pragma unroll
      for (int r = 0; r < 4; ++r) {
        bh4[mf][r] = vmask[mf] ? p0[cb + r] : 0.f;
        th4[mf][r] = (float)(TH_LO + (double)((cb + r) % 20) * TH_STEP);
      }
    }
#pragma unroll
    for (int f = 0; f < 4; ++f) {
      const int y = y0 + 4 * wave + f;
      float v[4][4];
      float s2 = 0.f;
#pragma unroll
      for (int mf = 0; mf < 4; ++mf)
#pragma unroll
        for (int r = 0; r < 4; ++r) {
          float z = acc[mf][f][r] + bh4[mf][r];
          float t = (z - th4[mf][r]) * s;
          float vv = vmask[mf] ? 1.f / (1.f + expf(-t)) : 0.f;
          v[mf][r] = vv;
          s2 = fmaf(vv, vv, s2);
        }
      s2 += __shfl_xor(s2, 16);
      s2 += __shfl_xor(s2, 32);
      const float rs = 1.f / (1e-8f + sqrtf(s2));
      float hm[10];
#pragma unroll
      for (int k = 0; k < 10; ++k) {
        float d = 0.f;
#pragma unroll
        for (int mf = 0; mf < 4; ++mf) {
          if (true) {
            const int cb = mf * 16 + kg * 4;
            f32x4 a = vmask[mf] ? *(const f32x4*)(lds_av + k * TDIM + cb)
                                : (f32x4){0.f, 0.f, 0.f, 0.f};
#pragma unroll
            for (int r = 0; r < 4; ++r) d = fmaf(v[mf][r], a[r], d);
          }
        }
        d += __shfl_xor(d, 16);
        d += __shfl_xor(d, 32);
        hm[k] = 1.f / (1.f + expf(-fmaf(ls, d * rs, lb)));
      }
      if (y < HW && x < HW) {
#pragma unroll
        for (int j = 0; j < 3; ++j) {
          int k = kg + 4 * j;
          if (k < NCLS)
            out0[((size_t)(b * NCLS + k) * HW + y) * HW + x] = hm[k];
        }
      }
    }
  }
}

__global__ void sims_kernel(float* __restrict__ out_sims) {
  int t = threadIdx.x;
  if (t < 100) {
    int i = t / 10, j = t % 10;
    float r = 1.f;
#pragma unroll
    for (int d = 0; d < 3; ++d) {
      float ai = c_anchors[i][d], aj = c_anchors[j][d];
      r *= fminf(ai, aj) / fmaxf(ai, aj);
    }
    out_sims[t] = r;
  }
}

// NMS + two-level compaction (LDS atomics, <=2 global atomics per block).
__global__ __launch_bounds__(256)
void nms_kernel(const float* __restrict__ hm, float* __restrict__ ckey,
                int* __restrict__ cidx, int* __restrict__ cnt) {
  __shared__ int lcnt[2];
  __shared__ int lbase[2];
  const int tid = threadIdx.x;
  if (tid < 2) lcnt[tid] = 0;
  __syncthreads();

  int i = blockIdx.x * 256 + tid;
  bool surv = false; float v = 0.f; int bk = 0, p = 0;
  if (i < 2 * NBIG) {
    int x = i % HW; int y = (i / HW) % HW; int plane = i / NPIX;
    v = hm[i];
    float m = v;
#pragma unroll
    for (int dy = -1; dy <= 1; ++dy)
#pragma unroll
      for (int dx = -1; dx <= 1; ++dx) {
        int yy = y + dy, xx = x + dx;
        if ((unsigned)yy < (unsigned)HW && (unsigned)xx < (unsigned)HW)
          m = fmaxf(m, hm[((size_t)plane * NPIX) + yy * HW + xx]);
      }
    if (v == m) {
      surv = true;
      bk = i / NBIG;
      p = atomicAdd(&lcnt[bk], 1);
    }
  }
  __syncthreads();
  if (tid < 2 && lcnt[tid] > 0)
    lbase[tid] = atomicAdd(&cnt[tid], lcnt[tid]);
  __syncthreads();
  if (surv) {
    int slot = lbase[bk] + p;
    ckey[(size_t)bk * NBIG + slot] = v;
    cidx[(size_t)bk * NBIG + slot] = i - bk * NBIG;
  }
}

__global__ __launch_bounds__(1024)
void topk_kernel(const float* __restrict__ ckey, const int* __restrict__ cidx,
                 const int* __restrict__ cnt, const float* __restrict__ heatmap,
                 const float* __restrict__ bev_pos, float* __restrict__ out,
                 int* __restrict__ iws) {
  const int b = blockIdx.x;
  const int tid = threadIdx.x;
  const float* keys = ckey + (size_t)b * NBIG;
  const int* idxs = cidx + (size_t)b * NBIG;

  __shared__ unsigned hist[256];
  __shared__ unsigned sh_prefix;
  __shared__ int sh_want, sh_n;
  __shared__ int cntGT, cntTie;
  __shared__ unsigned gt_key[256], gt_idx[256];
  __shared__ unsigned tie_idx[2048];

  if (tid == 0) sh_n = cnt[b];
  __syncthreads();
  const int n = sh_n;

  unsigned prefix = 0; int want = NPROP;
  for (int shift = 24; shift >= 0; shift -= 8) {
    if (tid < 256) hist[tid] = 0u;
    __syncthreads();
    for (int i = tid; i < n; i += 1024) {
      unsigned k = __float_as_uint(keys[i]);
      bool match = (shift == 24) || ((k >> (shift + 8)) == (prefix >> (shift + 8)));
      if (match) atomicAdd(&hist[(k >> shift) & 255], 1u);
    }
    __syncthreads();
    if (tid == 0) {
      int cum = 0; int bsel = 0; sh_want = want;
      for (int bin = 255; bin >= 0; --bin) {
        cum += (int)hist[bin];
        if (cum >= want) { bsel = bin; sh_want = want - (cum - (int)hist[bin]); break; }
      }
      sh_prefix = prefix | ((unsigned)bsel << shift);
      cntGT = 0; cntTie = 0;
    }
    __syncthreads();
    prefix = sh_prefix; want = sh_want;
    __syncthreads();
  }
  const unsigned T = prefix;

  for (int i = tid; i < n; i += 1024) {
    unsigned k = __float_as_uint(keys[i]);
    if (k > T) {
      int p = atomicAdd(&cntGT, 1);
      if (p < 256) { gt_key[p] = k; gt_idx[p] = (unsigned)idxs[i]; }
    } else if (k == T) {
      int p = atomicAdd(&cntTie, 1);
      if (p < 2048) tie_idx[p] = (unsigned)idxs[i];
    }
  }
  __syncthreads();
  const int nGT = min(cntGT, 256);
  const int nTie = min(cntTie, 2048);

  for (int i = tid; i < 256; i += 1024)
    if (i >= nGT) { gt_key[i] = 0u; gt_idx[i] = 0xFFFFFFFFu; }
  for (int i = tid; i < 2048; i += 1024)
    if (i >= nTie) tie_idx[i] = 0xFFFFFFFFu;
  __syncthreads();

  for (int k2 = 2; k2 <= 256; k2 <<= 1) {
    for (int j = k2 >> 1; j > 0; j >>= 1) {
      for (int i = tid; i < 256; i += 1024) {
        int ixj = i ^ j;
        if (ixj > i) {
          unsigned ka = gt_key[i], kb = gt_key[ixj];
          unsigned ia = gt_idx[i], ib = gt_idx[ixj];
          bool firstA = (ka > kb) || (ka == kb && ia < ib);
          bool up = ((i & k2) == 0);
          if (up ? !firstA : firstA) {
            gt_key[i] = kb; gt_key[ixj] = ka;
            gt_idx[i] = ib; gt_idx[ixj] = ia;
          }
        }
      }
      __syncthreads();
    }
  }
  for (int k2 = 2; k2 <= 2048; k2 <<= 1) {
    for (int j = k2 >> 1; j > 0; j >>= 1) {
      for (int i = tid; i < 2048; i += 1024) {
        int ixj = i ^ j;
        if (ixj > i) {
          unsigned ia = tie_idx[i], ib = tie_idx[ixj];
          bool firstA = ia < ib;
          bool up = ((i & k2) == 0);
          if (up ? !firstA : firstA) { tie_idx[i] = ib; tie_idx[ixj] = ia; }
        }
      }
      __syncthreads();
    }
  }

  for (int r = tid; r < NPROP; r += 1024) {
    unsigned idx; float score;
    if (r < nGT) { idx = gt_idx[r]; score = __uint_as_float(gt_key[r]); }
    else         { idx = tie_idx[r - nGT]; score = __uint_as_float(T); }
    int label = (int)(idx / NPIX);
    int pos = (int)(idx - (unsigned)label * NPIX);
    out[648000 + b * NPROP + r] = score;
    out[648400 + b * NPROP + r] = (float)label;
    out[700000 + (b * NPROP + r) * 2 + 0] = bev_pos[pos * 2 + 0];
    out[700000 + (b * NPROP + r) * 2 + 1] = bev_pos[pos * 2 + 1];
#pragma unroll
    for (int k = 0; k < NCLS; ++k)
      out[700800 + (b * NCLS + k) * NPROP + r] = heatmap[(size_t)(b * NCLS + k) * NPIX + pos];
    iws[b * NPROP + r] = pos;
    iws[2 * NPROP + b * NPROP + r] = label;
  }
}

// lidar is NHWC-chunked fp32: [b][4][px][32]
__global__ void gather_qf_kernel(const float* __restrict__ lidar, const float* __restrict__ w_enc,
                                 const int* __restrict__ iws, float* __restrict__ out_qf) {
  int p = blockIdx.x % NPROP;
  int b = blockIdx.x / NPROP;
  int c = threadIdx.x;
  int pos = iws[b * NPROP + p];
  int label = iws[2 * NPROP + b * NPROP + p];
  float la0 = logf(c_anchors[label][0]);
  float la1 = logf(c_anchors[label][1]);
  float la2 = logf(c_anchors[label][2]);
  float dot = w_enc[c * 3 + 0] * la0 + w_enc[c * 3 + 1] * la1 + w_enc[c * 3 + 2] * la2;
  float g = lidar[((size_t)(b * 4 + (c >> 5)) * NPIX + pos) * 32 + (c & 31)];
  out_qf[((size_t)b * HID + c) * NPROP + p] = g + dot;
}

extern "C" void kernel_launch(void* const* d_in, const int* in_sizes, int n_in,
                              void* d_out, int out_size, void* d_ws, size_t ws_size,
                              hipStream_t stream) {
  (void)in_sizes; (void)n_in; (void)out_size; (void)ws_size;
  const float* feats       = (const float*)d_in[0];
  const float* w_shared    = (const float*)d_in[1];
  const float* b_shared    = (const float*)d_in[2];
  const float* w_bb        = (const float*)d_in[3];
  const float* gamma_bb    = (const float*)d_in[4];
  const float* beta_bb     = (const float*)d_in[5];
  const float* w_hm        = (const float*)d_in[6];
  const float* b_hm        = (const float*)d_in[7];
  const float* thr_scale   = (const float*)d_in[8];
  const float* logit_scale = (const float*)d_in[9];
  const float* logit_bias  = (const float*)d_in[10];
  const float* w_enc       = (const float*)d_in[11];
  const float* anchor_vecs = (const float*)d_in[12];
  const float* bev_pos     = (const float*)d_in[13];
  float* out = (float*)d_out;

  float* ws = (float*)d_ws;
  size_t off = 0;
  _Float16* X1 = (_Float16*)(ws + off); off += 33177600;   // 2 planes x 33.18M f16
  _Float16* X2 = (_Float16*)(ws + off); off += 8294400;    // 2 planes x 8.29M f16
  float* lidarN = ws + off; off += 8294400;                // NHWC fp32
  _Float16* X3 = (_Float16*)(ws + off); off += 8294400;    // 2 planes x 8.29M f16
  _Float16* W1 = (_Float16*)(ws + off); off += 589824;     // 2h x 16ks x 36864 f16
  _Float16* W2 = (_Float16*)(ws + off); off += 147456;     // 2h x 4ks  x 36864 f16
  _Float16* W3 = (_Float16*)(ws + off); off += 73728;      // 1h x 4ks  x 36864 f16
  float* ckey  = ws + off; off += (size_t)2 * NBIG;
  int*   cidx  = (int*)(ws + off); off += (size_t)2 * NBIG;
  int*   iws   = (int*)(ws + off); off += 800;
  int*   cnt   = (int*)(ws + off);

  transpose_w_mfma<512,16,2><<<(2*16*36864 + 255)/256, 256, 0, stream>>>(w_shared, W1, 128);
  transpose_w_mfma<128, 4,2><<<(2*4*36864  + 255)/256, 256, 0, stream>>>(w_bb, W2, 128);
  transpose_w_mfma<128, 4,1><<<(1*4*36864  + 255)/256, 256, 0, stream>>>(w_hm, W3, 60);
  convert_feats<<<dim3(127, 32), 256, 0, stream>>>(feats, X1);

  const unsigned CONV_LDS = (20736 + 18432) * sizeof(_Float16);        // 78336 B
  const unsigned HEAD_LDS = CONV_LDS + 600 * sizeof(float);            // 80736 B
  dim3 cgrid(12, 12, 4);   // x-tiles(16), y-tiles(16), b*half
  conv_mfma<16,0><<<cgrid, 256, CONV_LDS, stream>>>(X1, W1, b_shared, nullptr, lidarN, X2,
                                                    nullptr, nullptr, nullptr, nullptr);
  conv_mfma<4, 1><<<cgrid, 256, CONV_LDS, stream>>>(X2, W2, gamma_bb, beta_bb, nullptr, X3,
                                                    nullptr, nullptr, nullptr, nullptr);
  dim3 hgrid(12, 12, 2);   // b only (single 64-cout half)
  conv_mfma<4, 2><<<hgrid, 256, HEAD_LDS, stream>>>(X3, W3, b_hm, nullptr, out, nullptr,
                                                    thr_scale, logit_scale, logit_bias,
                                                    anchor_vecs);

  sims_kernel<<<1, 128, 0, stream>>>(out + 704800);
  hipMemsetAsync(cnt, 0, 2 * sizeof(int), stream);
  nms_kernel<<<(2*NBIG + 255)/256, 256, 0, stream>>>(out, ckey, cidx, cnt);
  topk_kernel<<<2, 1024, 0, stream>>>(ckey, cidx, cnt, out, bev_pos, out, iws);
  gather_qf_kernel<<<2*NPROP, 128, 0, stream>>>(lidarN, w_enc, iws, out + 648800);
}

// Round 12
// 585.936 us; speedup vs baseline: 5.6617x; 1.0006x over previous
//
#include <hip/hip_runtime.h>
#include <math.h>

// TransFusionHead anchor matching — round 12: cut LDS reads per MFMA.
// r10/r11: conv_mfma pinned at ~46% MfmaUtil = LDS-read-port bound
// (180 ds_read_b128 per ks per wave). r12: W prepack tap axis kx-major;
// per ks, 3 groups (g=kx): DMA both W planes of the group (24KB), hoist the
// 6 rows x 2 planes of B-frags once (kx fixed -> reused across ky), fire all
// 3 split terms per tap. 108 reads/ks/wave (1.67x cut). LDS 66KB, 2 blk/CU.

#define HW 180
#define NPIX 32400
#define NCLS 10
#define NPROP 200
#define HID 128
#define TDIM 60
#define NBIG (NCLS*NPIX)

#define TH_LO  (-0.9915981193)
#define TH_STEP (0.1789675812)

__constant__ float c_anchors[10][3] = {
  {4.63f,1.97f,1.74f},{6.93f,2.51f,2.84f},{6.37f,2.85f,3.19f},{10.5f,2.94f,3.47f},
  {12.29f,2.9f,3.87f},{0.5f,2.53f,0.98f},{2.11f,0.77f,1.47f},{1.7f,0.6f,1.28f},
  {0.73f,0.67f,1.77f},{0.41f,0.41f,1.07f}};

using f16x8 = _Float16 __attribute__((ext_vector_type(8)));
using f16x4 = _Float16 __attribute__((ext_vector_type(4)));
using f32x4 = float    __attribute__((ext_vector_type(4)));

#define GLD_LDS16(g, l) __builtin_amdgcn_global_load_lds( \
    (__attribute__((address_space(1))) void*)(g), \
    (__attribute__((address_space(3))) void*)(l), 16, 0, 0)

// ---------- MFMA weight prepack: [h][ks][plane][tsl][mf][lane][8] ----------
// tsl is kx-major: tsl = kx*3+ky, source tap t = ky*3+kx. cout-guarded.
template<int CIN, int KS, int HALVES>
__global__ void transpose_w_mfma(const float* __restrict__ w, _Float16* __restrict__ dst,
                                 int cout) {
  const int N = HALVES * KS * 36864;
  int i = blockIdx.x * 256 + threadIdx.x;
  if (i >= N) return;
  int j = i & 7;
  int lane = (i >> 3) & 63;
  int mf = (i >> 9) & 3;
  int rest = i >> 11;
  int tsl = rest % 9; rest /= 9;
  int t = (tsl % 3) * 3 + (tsl / 3);     // ky = tsl%3, kx = tsl/3
  int plane = rest & 1; rest >>= 1;
  int ks = rest % KS; int h = rest / KS;
  int co = h * 64 + mf * 16 + (lane & 15);
  int ch = ks * 32 + (lane >> 4) * 8 + j;
  float v = (co < cout) ? w[((size_t)co * CIN + ch) * 9 + t] : 0.f;
  _Float16 hi = (_Float16)v;
  dst[i] = plane ? (_Float16)(v - (float)hi) : hi;
}

// ---------- feats fp32 NCHW -> X1 hi/lo f16 [b][16ks][px][32] ----------
__global__ __launch_bounds__(256)
void convert_feats(const float* __restrict__ feats, _Float16* __restrict__ X1) {
  int px = blockIdx.x * 256 + threadIdx.x;
  int b = blockIdx.y >> 4, ks = blockIdx.y & 15;
  if (px >= NPIX) return;
  const float* src = feats + ((size_t)(b * 512 + ks * 32)) * NPIX + px;
  float v[32];
#pragma unroll
  for (int c = 0; c < 32; ++c) v[c] = src[(size_t)c * NPIX];
  f16x8 hv[4], lv[4];
#pragma unroll
  for (int c = 0; c < 32; ++c) {
    _Float16 h = (_Float16)v[c];
    hv[c >> 3][c & 7] = h;
    lv[c >> 3][c & 7] = (_Float16)(v[c] - (float)h);
  }
  size_t ob = ((size_t)(b * 16 + ks) * NPIX + px) * 32;
#pragma unroll
  for (int i = 0; i < 4; ++i) {
    *(f16x8*)(X1 + ob + i * 8) = hv[i];
    *(f16x8*)(X1 + 33177600u + ob + i * 8) = lv[i];
  }
}

// ---------- split-fp16 MFMA conv3x3, tile 16x16 px x 64 co ----------
// Dynamic LDS: X 18x18x32ch x2pl (41472 B) + W group 3taps x 2pl (24576 B)
// [+ anchors 2400 B, EPI=2].  Per ks, per group g=kx:
//   [bar] DMA (X if g==0) + W group g  [bar]
//   hoist bfh/bfl rows 4w..4w+5 col xl+g (12 reads)
//   for ky: read ah/al (8), 48 MFMA (ah*bh + ah*bl + al*bh).
// EPI 0: +bias -> lidarN f32 NHWC + X2 hi/lo.  EPI 1: relu(bn) -> X3 hi/lo.
// EPI 2: conv3 head -> heatmap.
template<int KS, int EPI>
__global__ __launch_bounds__(256, 2)
void conv_mfma(const _Float16* __restrict__ X, const _Float16* __restrict__ W,
               const float* __restrict__ p0, const float* __restrict__ p1,
               float* __restrict__ out0, _Float16* __restrict__ outX,
               const float* __restrict__ thr_scale, const float* __restrict__ logit_scale,
               const float* __restrict__ logit_bias, const float* __restrict__ anchor_vecs) {
  constexpr unsigned XPS = 2u * KS * NPIX * 32;   // f16 per activation plane
  extern __shared__ _Float16 dlds[];
  _Float16* lds_x = dlds;            // hi [0,10368), lo [10368,20736)
  _Float16* lds_w = dlds + 20736;    // 12288 f16: plane0 [0,6144), plane1 [6144,12288)
  float* lds_av = (float*)(dlds + 33024);  // 600 f32 (EPI=2 only)

  const int x0 = blockIdx.x * 16;
  const int y0 = blockIdx.y * 16;
  const int b  = (EPI == 2) ? blockIdx.z : (blockIdx.z >> 1);
  const int h  = (EPI == 2) ? 0 : (blockIdx.z & 1);
  const int tid = threadIdx.x;
  const int wave = tid >> 6;
  const int lane = tid & 63;
  const int xl = lane & 15, kg = lane >> 4;

  // zero X region + stage anchors (first barrier orders these vs DMA)
  {
    unsigned* p = (unsigned*)lds_x;
    for (int i = tid; i < 10368; i += 256) p[i] = 0u;
    if (EPI == 2)
      for (int i = tid; i < 600; i += 256) lds_av[i] = anchor_vecs[i];
  }

  // X staging map: 2592 16B-chunks (hi 1296 + lo 1296), 41 wave-insts.
  unsigned offs[11]; unsigned okb = 0;
#pragma unroll
  for (int s = 0; s < 11; ++s) {
    int inst = wave + 4 * s;
    int c = inst * 64 + lane;
    bool valid = (inst < 41) && (c < 2592);
    int plane = (c >= 1296) ? 1 : 0;
    int cc = c - plane * 1296;
    int px = cc >> 2, q = cc & 3;
    int r = px / 18, xx = px - r * 18;
    int gy = y0 - 1 + r, gx = x0 - 1 + xx;
    bool ok = valid && ((unsigned)gy < 180u) && ((unsigned)gx < 180u);
    offs[s] = ok ? ((unsigned)((b * KS) * NPIX + gy * 180 + gx) * 32u + (unsigned)q * 8u
                    + (unsigned)plane * XPS) : 0u;
    okb |= (ok ? 1u : 0u) << s;
  }

  f32x4 acc[4][4];
#pragma unroll
  for (int mf = 0; mf < 4; ++mf)
#pragma unroll
    for (int f = 0; f < 4; ++f) acc[mf][f] = (f32x4){0.f, 0.f, 0.f, 0.f};

  const _Float16* gwb = W + (size_t)(h * KS) * 36864;
  for (int ks = 0; ks < KS; ++ks) {
    const unsigned kof = (unsigned)ks * (NPIX * 32u);
    const _Float16* gw = gwb + (size_t)ks * 36864;
#pragma unroll
    for (int g = 0; g < 3; ++g) {
      __syncthreads();                     // prior reads of lds_x/lds_w done
      if (g == 0) {
#pragma unroll
        for (int s = 0; s < 11; ++s) {
          if (okb & (1u << s))
            GLD_LDS16(X + (size_t)(offs[s] + kof), lds_x + (wave + 4 * s) * 512);
        }
      }
      // W group g: 24 chunks (12 per plane), 6 insts/wave
#pragma unroll
      for (int s = 0; s < 6; ++s) {
        int c2 = wave + 4 * s;             // 0..23
        int pl = c2 / 12, idx = c2 - pl * 12;
        GLD_LDS16(gw + pl * 18432 + g * 6144 + idx * 512 + lane * 8,
                  lds_w + pl * 6144 + idx * 512);
      }
      __syncthreads();                     // X + W group ready

      // hoisted B-frags: rows 4w..4w+5, col xl+g, both planes (12 reads)
      f16x8 bfh[6], bfl[6];
#pragma unroll
      for (int rr = 0; rr < 6; ++rr) {
        int lo = ((4 * wave + rr) * 18 + xl + g) * 32 + kg * 8;
        bfh[rr] = *(const f16x8*)(lds_x + lo);
        bfl[rr] = *(const f16x8*)(lds_x + 10368 + lo);
      }
#pragma unroll
      for (int ky = 0; ky < 3; ++ky) {
        const _Float16* wt = lds_w + ky * 2048 + lane * 8;
        f16x8 ah[4], al[4];
#pragma unroll
        for (int mf = 0; mf < 4; ++mf) {
          ah[mf] = *(const f16x8*)(wt + mf * 512);
          al[mf] = *(const f16x8*)(wt + 6144 + mf * 512);
        }
#pragma unroll
        for (int mf = 0; mf < 4; ++mf)
#pragma unroll
          for (int f = 0; f < 4; ++f) {
            acc[mf][f] = __builtin_amdgcn_mfma_f32_16x16x32_f16(ah[mf], bfh[f + ky], acc[mf][f], 0, 0, 0);
            acc[mf][f] = __builtin_amdgcn_mfma_f32_16x16x32_f16(ah[mf], bfl[f + ky], acc[mf][f], 0, 0, 0);
            acc[mf][f] = __builtin_amdgcn_mfma_f32_16x16x32_f16(al[mf], bfh[f + ky], acc[mf][f], 0, 0, 0);
          }
      }
    }
  }

  // ---- epilogue: C frag col=lane&15 (pixel x), row=kg*4+r (cout) ----
  const int x = x0 + xl;
  if (EPI != 2) {
    if (x >= HW) return;
#pragma unroll
    for (int mf = 0; mf < 4; ++mf) {
      const int cobase = h * 64 + mf * 16 + kg * 4;
      f32x4 q0 = *(const f32x4*)(p0 + cobase);
      f32x4 q1 = (EPI == 1) ? *(const f32x4*)(p1 + cobase) : (f32x4){0.f,0.f,0.f,0.f};
#pragma unroll
      for (int f = 0; f < 4; ++f) {
        const int y = y0 + 4 * wave + f;
        if (y >= HW) continue;
        const int kso = cobase >> 5, c32 = cobase & 31;
        size_t nidx = ((size_t)(b * 4 + kso) * NPIX + (size_t)y * 180 + x) * 32 + c32;
        if (EPI == 0) {
          f32x4 v;
          f16x4 h4, l4;
#pragma unroll
          for (int r = 0; r < 4; ++r) {
            float z = acc[mf][f][r] + q0[r];
            v[r] = z;
            _Float16 hh = (_Float16)z;
            h4[r] = hh;
            l4[r] = (_Float16)(z - (float)hh);
          }
          *(f32x4*)(out0 + nidx) = v;
          *(f16x4*)(outX + nidx) = h4;
          *(f16x4*)(outX + 8294400u + nidx) = l4;
        } else {
          f16x4 h4, l4;
#pragma unroll
          for (int r = 0; r < 4; ++r) {
            float z = fmaf(acc[mf][f][r], q0[r], q1[r]);
            z = fmaxf(z, 0.f);
            _Float16 hh = (_Float16)z;
            h4[r] = hh;
            l4[r] = (_Float16)(z - (float)hh);
          }
          *(f16x4*)(outX + nidx) = h4;
          *(f16x4*)(outX + 8294400u + nidx) = l4;
        }
      }
    }
  } else {
    // ---- fused head: threshold-sigmoid, L2 norm, anchor sim, sigmoid ----
    const float s  = thr_scale[0];
    const float ls = logit_scale[0];
    const float lb = logit_bias[0];
    float bh4[4][4], th4[4][4];
    bool vmask[4];
#pragma unroll
    for (int mf = 0; mf < 4; ++mf) {
      const int cb = mf * 16 + kg * 4;
      vmask[mf] = (cb < TDIM);
#pragma unroll
      for (int r = 0; r < 4; ++r) {
        bh4[mf][r] = vmask[mf] ? p0[cb + r] : 0.f;
        th4[mf][r] = (float)(TH_LO + (double)((cb + r) % 20) * TH_STEP);
      }
    }
#pragma unroll
    for (int f = 0; f < 4; ++f) {
      const int y = y0 + 4 * wave + f;
      float v[4][4];
      float s2 = 0.f;
#pragma unroll
      for (int mf = 0; mf < 4; ++mf)
#pragma unroll
        for (int r = 0; r < 4; ++r) {
          float z = acc[mf][f][r] + bh4[mf][r];
          float t = (z - th4[mf][r]) * s;
          float vv = vmask[mf] ? 1.f / (1.f + expf(-t)) : 0.f;
          v[mf][r] = vv;
          s2 = fmaf(vv, vv, s2);
        }
      s2 += __shfl_xor(s2, 16);
      s2 += __shfl_xor(s2, 32);
      const float rs = 1.f / (1e-8f + sqrtf(s2));
      float hm[10];
#pragma unroll
      for (int k = 0; k < 10; ++k) {
        float d = 0.f;
#pragma unroll
        for (int mf = 0; mf < 4; ++mf) {
          const int cb = mf * 16 + kg * 4;
          f32x4 a = vmask[mf] ? *(const f32x4*)(lds_av + k * TDIM + cb)
                              : (f32x4){0.f, 0.f, 0.f, 0.f};
#pragma unroll
          for (int r = 0; r < 4; ++r) d = fmaf(v[mf][r], a[r], d);
        }
        d += __shfl_xor(d, 16);
        d += __shfl_xor(d, 32);
        hm[k] = 1.f / (1.f + expf(-fmaf(ls, d * rs, lb)));
      }
      if (y < HW && x < HW) {
#pragma unroll
        for (int j = 0; j < 3; ++j) {
          int k = kg + 4 * j;
          if (k < NCLS)
            out0[((size_t)(b * NCLS + k) * HW + y) * HW + x] = hm[k];
        }
      }
    }
  }
}

__global__ void sims_kernel(float* __restrict__ out_sims) {
  int t = threadIdx.x;
  if (t < 100) {
    int i = t / 10, j = t % 10;
    float r = 1.f;
#pragma unroll
    for (int d = 0; d < 3; ++d) {
      float ai = c_anchors[i][d], aj = c_anchors[j][d];
      r *= fminf(ai, aj) / fmaxf(ai, aj);
    }
    out_sims[t] = r;
  }
}

// NMS + two-level compaction (LDS atomics, <=2 global atomics per block).
__global__ __launch_bounds__(256)
void nms_kernel(const float* __restrict__ hm, float* __restrict__ ckey,
                int* __restrict__ cidx, int* __restrict__ cnt) {
  __shared__ int lcnt[2];
  __shared__ int lbase[2];
  const int tid = threadIdx.x;
  if (tid < 2) lcnt[tid] = 0;
  __syncthreads();

  int i = blockIdx.x * 256 + tid;
  bool surv = false; float v = 0.f; int bk = 0, p = 0;
  if (i < 2 * NBIG) {
    int x = i % HW; int y = (i / HW) % HW; int plane = i / NPIX;
    v = hm[i];
    float m = v;
#pragma unroll
    for (int dy = -1; dy <= 1; ++dy)
#pragma unroll
      for (int dx = -1; dx <= 1; ++dx) {
        int yy = y + dy, xx = x + dx;
        if ((unsigned)yy < (unsigned)HW && (unsigned)xx < (unsigned)HW)
          m = fmaxf(m, hm[((size_t)plane * NPIX) + yy * HW + xx]);
      }
    if (v == m) {
      surv = true;
      bk = i / NBIG;
      p = atomicAdd(&lcnt[bk], 1);
    }
  }
  __syncthreads();
  if (tid < 2 && lcnt[tid] > 0)
    lbase[tid] = atomicAdd(&cnt[tid], lcnt[tid]);
  __syncthreads();
  if (surv) {
    int slot = lbase[bk] + p;
    ckey[(size_t)bk * NBIG + slot] = v;
    cidx[(size_t)bk * NBIG + slot] = i - bk * NBIG;
  }
}

__global__ __launch_bounds__(1024)
void topk_kernel(const float* __restrict__ ckey, const int* __restrict__ cidx,
                 const int* __restrict__ cnt, const float* __restrict__ heatmap,
                 const float* __restrict__ bev_pos, float* __restrict__ out,
                 int* __restrict__ iws) {
  const int b = blockIdx.x;
  const int tid = threadIdx.x;
  const float* keys = ckey + (size_t)b * NBIG;
  const int* idxs = cidx + (size_t)b * NBIG;

  __shared__ unsigned hist[256];
  __shared__ unsigned sh_prefix;
  __shared__ int sh_want, sh_n;
  __shared__ int cntGT, cntTie;
  __shared__ unsigned gt_key[256], gt_idx[256];
  __shared__ unsigned tie_idx[2048];

  if (tid == 0) sh_n = cnt[b];
  __syncthreads();
  const int n = sh_n;

  unsigned prefix = 0; int want = NPROP;
  for (int shift = 24; shift >= 0; shift -= 8) {
    if (tid < 256) hist[tid] = 0u;
    __syncthreads();
    for (int i = tid; i < n; i += 1024) {
      unsigned k = __float_as_uint(keys[i]);
      bool match = (shift == 24) || ((k >> (shift + 8)) == (prefix >> (shift + 8)));
      if (match) atomicAdd(&hist[(k >> shift) & 255], 1u);
    }
    __syncthreads();
    if (tid == 0) {
      int cum = 0; int bsel = 0; sh_want = want;
      for (int bin = 255; bin >= 0; --bin) {
        cum += (int)hist[bin];
        if (cum >= want) { bsel = bin; sh_want = want - (cum - (int)hist[bin]); break; }
      }
      sh_prefix = prefix | ((unsigned)bsel << shift);
      cntGT = 0; cntTie = 0;
    }
    __syncthreads();
    prefix = sh_prefix; want = sh_want;
    __syncthreads();
  }
  const unsigned T = prefix;

  for (int i = tid; i < n; i += 1024) {
    unsigned k = __float_as_uint(keys[i]);
    if (k > T) {
      int p = atomicAdd(&cntGT, 1);
      if (p < 256) { gt_key[p] = k; gt_idx[p] = (unsigned)idxs[i]; }
    } else if (k == T) {
      int p = atomicAdd(&cntTie, 1);
      if (p < 2048) tie_idx[p] = (unsigned)idxs[i];
    }
  }
  __syncthreads();
  const int nGT = min(cntGT, 256);
  const int nTie = min(cntTie, 2048);

  for (int i = tid; i < 256; i += 1024)
    if (i >= nGT) { gt_key[i] = 0u; gt_idx[i] = 0xFFFFFFFFu; }
  for (int i = tid; i < 2048; i += 1024)
    if (i >= nTie) tie_idx[i] = 0xFFFFFFFFu;
  __syncthreads();

  for (int k2 = 2; k2 <= 256; k2 <<= 1) {
    for (int j = k2 >> 1; j > 0; j >>= 1) {
      for (int i = tid; i < 256; i += 1024) {
        int ixj = i ^ j;
        if (ixj > i) {
          unsigned ka = gt_key[i], kb = gt_key[ixj];
          unsigned ia = gt_idx[i], ib = gt_idx[ixj];
          bool firstA = (ka > kb) || (ka == kb && ia < ib);
          bool up = ((i & k2) == 0);
          if (up ? !firstA : firstA) {
            gt_key[i] = kb; gt_key[ixj] = ka;
            gt_idx[i] = ib; gt_idx[ixj] = ia;
          }
        }
      }
      __syncthreads();
    }
  }
  for (int k2 = 2; k2 <= 2048; k2 <<= 1) {
    for (int j = k2 >> 1; j > 0; j >>= 1) {
      for (int i = tid; i < 2048; i += 1024) {
        int ixj = i ^ j;
        if (ixj > i) {
          unsigned ia = tie_idx[i], ib = tie_idx[ixj];
          bool firstA = ia < ib;
          bool up = ((i & k2) == 0);
          if (up ? !firstA : firstA) { tie_idx[i] = ib; tie_idx[ixj] = ia; }
        }
      }
      __syncthreads();
    }
  }

  for (int r = tid; r < NPROP; r += 1024) {
    unsigned idx; float score;
    if (r < nGT) { idx = gt_idx[r]; score = __uint_as_float(gt_key[r]); }
    else         { idx = tie_idx[r - nGT]; score = __uint_as_float(T); }
    int label = (int)(idx / NPIX);
    int pos = (int)(idx - (unsigned)label * NPIX);
    out[648000 + b * NPROP + r] = score;
    out[648400 + b * NPROP + r] = (float)label;
    out[700000 + (b * NPROP + r) * 2 + 0] = bev_pos[pos * 2 + 0];
    out[700000 + (b * NPROP + r) * 2 + 1] = bev_pos[pos * 2 + 1];
#pragma unroll
    for (int k = 0; k < NCLS; ++k)
      out[700800 + (b * NCLS + k) * NPROP + r] = heatmap[(size_t)(b * NCLS + k) * NPIX + pos];
    iws[b * NPROP + r] = pos;
    iws[2 * NPROP + b * NPROP + r] = label;
  }
}

// lidar is NHWC-chunked fp32: [b][4][px][32]
__global__ void gather_qf_kernel(const float* __restrict__ lidar, const float* __restrict__ w_enc,
                                 const int* __restrict__ iws, float* __restrict__ out_qf) {
  int p = blockIdx.x % NPROP;
  int b = blockIdx.x / NPROP;
  int c = threadIdx.x;
  int pos = iws[b * NPROP + p];
  int label = iws[2 * NPROP + b * NPROP + p];
  float la0 = logf(c_anchors[label][0]);
  float la1 = logf(c_anchors[label][1]);
  float la2 = logf(c_anchors[label][2]);
  float dot = w_enc[c * 3 + 0] * la0 + w_enc[c * 3 + 1] * la1 + w_enc[c * 3 + 2] * la2;
  float g = lidar[((size_t)(b * 4 + (c >> 5)) * NPIX + pos) * 32 + (c & 31)];
  out_qf[((size_t)b * HID + c) * NPROP + p] = g + dot;
}

extern "C" void kernel_launch(void* const* d_in, const int* in_sizes, int n_in,
                              void* d_out, int out_size, void* d_ws, size_t ws_size,
                              hipStream_t stream) {
  (void)in_sizes; (void)n_in; (void)out_size; (void)ws_size;
  const float* feats       = (const float*)d_in[0];
  const float* w_shared    = (const float*)d_in[1];
  const float* b_shared    = (const float*)d_in[2];
  const float* w_bb        = (const float*)d_in[3];
  const float* gamma_bb    = (const float*)d_in[4];
  const float* beta_bb     = (const float*)d_in[5];
  const float* w_hm        = (const float*)d_in[6];
  const float* b_hm        = (const float*)d_in[7];
  const float* thr_scale   = (const float*)d_in[8];
  const float* logit_scale = (const float*)d_in[9];
  const float* logit_bias  = (const float*)d_in[10];
  const float* w_enc       = (const float*)d_in[11];
  const float* anchor_vecs = (const float*)d_in[12];
  const float* bev_pos     = (const float*)d_in[13];
  float* out = (float*)d_out;

  float* ws = (float*)d_ws;
  size_t off = 0;
  _Float16* X1 = (_Float16*)(ws + off); off += 33177600;   // 2 planes x 33.18M f16
  _Float16* X2 = (_Float16*)(ws + off); off += 8294400;    // 2 planes x 8.29M f16
  float* lidarN = ws + off; off += 8294400;                // NHWC fp32
  _Float16* X3 = (_Float16*)(ws + off); off += 8294400;    // 2 planes x 8.29M f16
  _Float16* W1 = (_Float16*)(ws + off); off += 589824;     // 2h x 16ks x 36864 f16
  _Float16* W2 = (_Float16*)(ws + off); off += 147456;     // 2h x 4ks  x 36864 f16
  _Float16* W3 = (_Float16*)(ws + off); off += 73728;      // 1h x 4ks  x 36864 f16
  float* ckey  = ws + off; off += (size_t)2 * NBIG;
  int*   cidx  = (int*)(ws + off); off += (size_t)2 * NBIG;
  int*   iws   = (int*)(ws + off); off += 800;
  int*   cnt   = (int*)(ws + off);

  transpose_w_mfma<512,16,2><<<(2*16*36864 + 255)/256, 256, 0, stream>>>(w_shared, W1, 128);
  transpose_w_mfma<128, 4,2><<<(2*4*36864  + 255)/256, 256, 0, stream>>>(w_bb, W2, 128);
  transpose_w_mfma<128, 4,1><<<(1*4*36864  + 255)/256, 256, 0, stream>>>(w_hm, W3, 60);
  convert_feats<<<dim3(127, 32), 256, 0, stream>>>(feats, X1);

  const unsigned CONV_LDS = (20736 + 12288) * sizeof(_Float16);        // 66048 B
  const unsigned HEAD_LDS = CONV_LDS + 600 * sizeof(float);            // 68448 B
  dim3 cgrid(12, 12, 4);   // x-tiles(16), y-tiles(16), b*half
  conv_mfma<16,0><<<cgrid, 256, CONV_LDS, stream>>>(X1, W1, b_shared, nullptr, lidarN, X2,
                                                    nullptr, nullptr, nullptr, nullptr);
  conv_mfma<4, 1><<<cgrid, 256, CONV_LDS, stream>>>(X2, W2, gamma_bb, beta_bb, nullptr, X3,
                                                    nullptr, nullptr, nullptr, nullptr);
  dim3 hgrid(12, 12, 2);   // b only (single 64-cout half)
  conv_mfma<4, 2><<<hgrid, 256, HEAD_LDS, stream>>>(X3, W3, b_hm, nullptr, out, nullptr,
                                                    thr_scale, logit_scale, logit_bias,
                                                    anchor_vecs);

  sims_kernel<<<1, 128, 0, stream>>>(out + 704800);
  hipMemsetAsync(cnt, 0, 2 * sizeof(int), stream);
  nms_kernel<<<(2*NBIG + 255)/256, 256, 0, stream>>>(out, ckey, cidx, cnt);
  topk_kernel<<<2, 1024, 0, stream>>>(ckey, cidx, cnt, out, bev_pos, out, iws);
  gather_qf_kernel<<<2*NPROP, 128, 0, stream>>>(lidarN, w_enc, iws, out + 648800);
}

// Round 13
// 539.047 us; speedup vs baseline: 6.1542x; 1.0870x over previous
//
#include <hip/hip_runtime.h>
#include <math.h>

// TransFusionHead anchor matching — round 13: kill the dispatch tail.
// r12 refuted the LDS-port model (reads cut 40%, util flat 46%). New model:
// 576 blocks @ 2/CU (512 slots) -> 1.125 rounds -> 56-75% CU ceiling, matches
// 247us vs 126us floor. r13: tile 16x20 -> 432 blocks (<=512, all resident,
// 84% ceiling), 180 = 9*20 exact (no y padding), 5 rows/wave.

#define HW 180
#define NPIX 32400
#define NCLS 10
#define NPROP 200
#define HID 128
#define TDIM 60
#define NBIG (NCLS*NPIX)

#define TH_LO  (-0.9915981193)
#define TH_STEP (0.1789675812)

__constant__ float c_anchors[10][3] = {
  {4.63f,1.97f,1.74f},{6.93f,2.51f,2.84f},{6.37f,2.85f,3.19f},{10.5f,2.94f,3.47f},
  {12.29f,2.9f,3.87f},{0.5f,2.53f,0.98f},{2.11f,0.77f,1.47f},{1.7f,0.6f,1.28f},
  {0.73f,0.67f,1.77f},{0.41f,0.41f,1.07f}};

using f16x8 = _Float16 __attribute__((ext_vector_type(8)));
using f16x4 = _Float16 __attribute__((ext_vector_type(4)));
using f32x4 = float    __attribute__((ext_vector_type(4)));

#define GLD_LDS16(g, l) __builtin_amdgcn_global_load_lds( \
    (__attribute__((address_space(1))) void*)(g), \
    (__attribute__((address_space(3))) void*)(l), 16, 0, 0)

// ---------- MFMA weight prepack: [h][ks][plane][tsl][mf][lane][8] ----------
// tsl kx-major: tsl = kx*3+ky, source tap t = ky*3+kx. cout-guarded.
template<int CIN, int KS, int HALVES>
__global__ void transpose_w_mfma(const float* __restrict__ w, _Float16* __restrict__ dst,
                                 int cout) {
  const int N = HALVES * KS * 36864;
  int i = blockIdx.x * 256 + threadIdx.x;
  if (i >= N) return;
  int j = i & 7;
  int lane = (i >> 3) & 63;
  int mf = (i >> 9) & 3;
  int rest = i >> 11;
  int tsl = rest % 9; rest /= 9;
  int t = (tsl % 3) * 3 + (tsl / 3);     // ky = tsl%3, kx = tsl/3
  int plane = rest & 1; rest >>= 1;
  int ks = rest % KS; int h = rest / KS;
  int co = h * 64 + mf * 16 + (lane & 15);
  int ch = ks * 32 + (lane >> 4) * 8 + j;
  float v = (co < cout) ? w[((size_t)co * CIN + ch) * 9 + t] : 0.f;
  _Float16 hi = (_Float16)v;
  dst[i] = plane ? (_Float16)(v - (float)hi) : hi;
}

// ---------- feats fp32 NCHW -> X1 hi/lo f16 [b][16ks][px][32] ----------
__global__ __launch_bounds__(256)
void convert_feats(const float* __restrict__ feats, _Float16* __restrict__ X1) {
  int px = blockIdx.x * 256 + threadIdx.x;
  int b = blockIdx.y >> 4, ks = blockIdx.y & 15;
  if (px >= NPIX) return;
  const float* src = feats + ((size_t)(b * 512 + ks * 32)) * NPIX + px;
  float v[32];
#pragma unroll
  for (int c = 0; c < 32; ++c) v[c] = src[(size_t)c * NPIX];
  f16x8 hv[4], lv[4];
#pragma unroll
  for (int c = 0; c < 32; ++c) {
    _Float16 h = (_Float16)v[c];
    hv[c >> 3][c & 7] = h;
    lv[c >> 3][c & 7] = (_Float16)(v[c] - (float)h);
  }
  size_t ob = ((size_t)(b * 16 + ks) * NPIX + px) * 32;
#pragma unroll
  for (int i = 0; i < 4; ++i) {
    *(f16x8*)(X1 + ob + i * 8) = hv[i];
    *(f16x8*)(X1 + 33177600u + ob + i * 8) = lv[i];
  }
}

// ---------- split-fp16 MFMA conv3x3, tile 16x20 px x 64 co ----------
// Dynamic LDS: X 22x18 px x 32ch x2pl (50688 B) + W group 3taps x2pl (24576 B)
// [+ anchors 2400 B, EPI=2]. 4 waves, wave w rows 5w..5w+4.
// Per ks, group g=kx: [bar] DMA (X if g==0) + W group [bar], hoist 7x2 B-frags,
// per ky 8 A-frags + 60 MFMA.
template<int KS, int EPI>
__global__ __launch_bounds__(256, 2)
void conv_mfma(const _Float16* __restrict__ X, const _Float16* __restrict__ W,
               const float* __restrict__ p0, const float* __restrict__ p1,
               float* __restrict__ out0, _Float16* __restrict__ outX,
               const float* __restrict__ thr_scale, const float* __restrict__ logit_scale,
               const float* __restrict__ logit_bias, const float* __restrict__ anchor_vecs) {
  constexpr unsigned XPS = 2u * KS * NPIX * 32;   // f16 per activation plane
  extern __shared__ _Float16 dlds[];
  _Float16* lds_x = dlds;            // hi [0,12672), lo [12672,25344)
  _Float16* lds_w = dlds + 25344;    // 12288 f16: plane0 [0,6144), plane1 [6144,12288)
  float* lds_av = (float*)(dlds + 37632);  // 600 f32 (EPI=2 only)

  const int x0 = blockIdx.x * 16;
  const int y0 = blockIdx.y * 20;
  const int b  = (EPI == 2) ? blockIdx.z : (blockIdx.z >> 1);
  const int h  = (EPI == 2) ? 0 : (blockIdx.z & 1);
  const int tid = threadIdx.x;
  const int wave = tid >> 6;
  const int lane = tid & 63;
  const int xl = lane & 15, kg = lane >> 4;

  // zero X region + stage anchors (first barrier orders these vs DMA)
  {
    unsigned* p = (unsigned*)lds_x;
    for (int i = tid; i < 12672; i += 256) p[i] = 0u;
    if (EPI == 2)
      for (int i = tid; i < 600; i += 256) lds_av[i] = anchor_vecs[i];
  }

  // X staging: 3168 16B-chunks (hi 1584 + lo 1584), 50 wave-insts, 13/wave.
  unsigned offs[13]; unsigned okb = 0;
#pragma unroll
  for (int s = 0; s < 13; ++s) {
    int inst = wave + 4 * s;
    int c = inst * 64 + lane;
    bool valid = (inst < 50) && (c < 3168);
    int plane = (c >= 1584) ? 1 : 0;
    int cc = c - plane * 1584;
    int px = cc >> 2, q = cc & 3;
    int r = px / 18, xx = px - r * 18;
    int gy = y0 - 1 + r, gx = x0 - 1 + xx;
    bool ok = valid && ((unsigned)gy < 180u) && ((unsigned)gx < 180u);
    offs[s] = ok ? ((unsigned)((b * KS) * NPIX + gy * 180 + gx) * 32u + (unsigned)q * 8u
                    + (unsigned)plane * XPS) : 0u;
    okb |= (ok ? 1u : 0u) << s;
  }

  f32x4 acc[4][5];
#pragma unroll
  for (int mf = 0; mf < 4; ++mf)
#pragma unroll
    for (int f = 0; f < 5; ++f) acc[mf][f] = (f32x4){0.f, 0.f, 0.f, 0.f};

  const _Float16* gwb = W + (size_t)(h * KS) * 36864;
  for (int ks = 0; ks < KS; ++ks) {
    const unsigned kof = (unsigned)ks * (NPIX * 32u);
    const _Float16* gw = gwb + (size_t)ks * 36864;
#pragma unroll
    for (int g = 0; g < 3; ++g) {
      __syncthreads();                     // prior reads of lds_x/lds_w done
      if (g == 0) {
#pragma unroll
        for (int s = 0; s < 13; ++s) {
          if (okb & (1u << s))
            GLD_LDS16(X + (size_t)(offs[s] + kof), lds_x + (wave + 4 * s) * 512);
        }
      }
      // W group g: 24 chunks (12 per plane), 6 insts/wave
#pragma unroll
      for (int s = 0; s < 6; ++s) {
        int c2 = wave + 4 * s;             // 0..23
        int pl = c2 / 12, idx = c2 - pl * 12;
        GLD_LDS16(gw + pl * 18432 + g * 6144 + idx * 512 + lane * 8,
                  lds_w + pl * 6144 + idx * 512);
      }
      __syncthreads();                     // X + W group ready

      // hoisted B-frags: rows 5w..5w+6, col xl+g, both planes (14 reads)
      f16x8 bfh[7], bfl[7];
#pragma unroll
      for (int rr = 0; rr < 7; ++rr) {
        int lo = ((5 * wave + rr) * 18 + xl + g) * 32 + kg * 8;
        bfh[rr] = *(const f16x8*)(lds_x + lo);
        bfl[rr] = *(const f16x8*)(lds_x + 12672 + lo);
      }
#pragma unroll
      for (int ky = 0; ky < 3; ++ky) {
        const _Float16* wt = lds_w + ky * 2048 + lane * 8;
        f16x8 ah[4], al[4];
#pragma unroll
        for (int mf = 0; mf < 4; ++mf) {
          ah[mf] = *(const f16x8*)(wt + mf * 512);
          al[mf] = *(const f16x8*)(wt + 6144 + mf * 512);
        }
#pragma unroll
        for (int mf = 0; mf < 4; ++mf)
#pragma unroll
          for (int f = 0; f < 5; ++f) {
            acc[mf][f] = __builtin_amdgcn_mfma_f32_16x16x32_f16(ah[mf], bfh[f + ky], acc[mf][f], 0, 0, 0);
            acc[mf][f] = __builtin_amdgcn_mfma_f32_16x16x32_f16(ah[mf], bfl[f + ky], acc[mf][f], 0, 0, 0);
            acc[mf][f] = __builtin_amdgcn_mfma_f32_16x16x32_f16(al[mf], bfh[f + ky], acc[mf][f], 0, 0, 0);
          }
      }
    }
  }

  // ---- epilogue: C frag col=lane&15 (pixel x), row=kg*4+r (cout) ----
  const int x = x0 + xl;
  if (EPI != 2) {
    if (x >= HW) return;
#pragma unroll
    for (int mf = 0; mf < 4; ++mf) {
      const int cobase = h * 64 + mf * 16 + kg * 4;
      f32x4 q0 = *(const f32x4*)(p0 + cobase);
      f32x4 q1 = (EPI == 1) ? *(const f32x4*)(p1 + cobase) : (f32x4){0.f,0.f,0.f,0.f};
#pragma unroll
      for (int f = 0; f < 5; ++f) {
        const int y = y0 + 5 * wave + f;
        const int kso = cobase >> 5, c32 = cobase & 31;
        size_t nidx = ((size_t)(b * 4 + kso) * NPIX + (size_t)y * 180 + x) * 32 + c32;
        if (EPI == 0) {
          f32x4 v;
          f16x4 h4, l4;
#pragma unroll
          for (int r = 0; r < 4; ++r) {
            float z = acc[mf][f][r] + q0[r];
            v[r] = z;
            _Float16 hh = (_Float16)z;
            h4[r] = hh;
            l4[r] = (_Float16)(z - (float)hh);
          }
          *(f32x4*)(out0 + nidx) = v;
          *(f16x4*)(outX + nidx) = h4;
          *(f16x4*)(outX + 8294400u + nidx) = l4;
        } else {
          f16x4 h4, l4;
#pragma unroll
          for (int r = 0; r < 4; ++r) {
            float z = fmaf(acc[mf][f][r], q0[r], q1[r]);
            z = fmaxf(z, 0.f);
            _Float16 hh = (_Float16)z;
            h4[r] = hh;
            l4[r] = (_Float16)(z - (float)hh);
          }
          *(f16x4*)(outX + nidx) = h4;
          *(f16x4*)(outX + 8294400u + nidx) = l4;
        }
      }
    }
  } else {
    // ---- fused head: threshold-sigmoid, L2 norm, anchor sim, sigmoid ----
    const float s  = thr_scale[0];
    const float ls = logit_scale[0];
    const float lb = logit_bias[0];
    float bh4[4][4], th4[4][4];
    bool vmask[4];
#pragma unroll
    for (int mf = 0; mf < 4; ++mf) {
      const int cb = mf * 16 + kg * 4;
      vmask[mf] = (cb < TDIM);
#pragma unroll
      for (int r = 0; r < 4; ++r) {
        bh4[mf][r] = vmask[mf] ? p0[cb + r] : 0.f;
        th4[mf][r] = (float)(TH_LO + (double)((cb + r) % 20) * TH_STEP);
      }
    }
#pragma unroll
    for (int f = 0; f < 5; ++f) {
      const int y = y0 + 5 * wave + f;
      float v[4][4];
      float s2 = 0.f;
#pragma unroll
      for (int mf = 0; mf < 4; ++mf)
#pragma unroll
        for (int r = 0; r < 4; ++r) {
          float z = acc[mf][f][r] + bh4[mf][r];
          float t = (z - th4[mf][r]) * s;
          float vv = vmask[mf] ? 1.f / (1.f + expf(-t)) : 0.f;
          v[mf][r] = vv;
          s2 = fmaf(vv, vv, s2);
        }
      s2 += __shfl_xor(s2, 16);
      s2 += __shfl_xor(s2, 32);
      const float rs = 1.f / (1e-8f + sqrtf(s2));
      float hm[10];
#pragma unroll
      for (int k = 0; k < 10; ++k) {
        float d = 0.f;
#pragma unroll
        for (int mf = 0; mf < 4; ++mf) {
          const int cb = mf * 16 + kg * 4;
          f32x4 a = vmask[mf] ? *(const f32x4*)(lds_av + k * TDIM + cb)
                              : (f32x4){0.f, 0.f, 0.f, 0.f};
#pragma unroll
          for (int r = 0; r < 4; ++r) d = fmaf(v[mf][r], a[r], d);
        }
        d += __shfl_xor(d, 16);
        d += __shfl_xor(d, 32);
        hm[k] = 1.f / (1.f + expf(-fmaf(ls, d * rs, lb)));
      }
      if (y < HW && x < HW) {
#pragma unroll
        for (int j = 0; j < 3; ++j) {
          int k = kg + 4 * j;
          if (k < NCLS)
            out0[((size_t)(b * NCLS + k) * HW + y) * HW + x] = hm[k];
        }
      }
    }
  }
}

__global__ void sims_kernel(float* __restrict__ out_sims) {
  int t = threadIdx.x;
  if (t < 100) {
    int i = t / 10, j = t % 10;
    float r = 1.f;
#pragma unroll
    for (int d = 0; d < 3; ++d) {
      float ai = c_anchors[i][d], aj = c_anchors[j][d];
      r *= fminf(ai, aj) / fmaxf(ai, aj);
    }
    out_sims[t] = r;
  }
}

// NMS + two-level compaction (LDS atomics, <=2 global atomics per block).
__global__ __launch_bounds__(256)
void nms_kernel(const float* __restrict__ hm, float* __restrict__ ckey,
                int* __restrict__ cidx, int* __restrict__ cnt) {
  __shared__ int lcnt[2];
  __shared__ int lbase[2];
  const int tid = threadIdx.x;
  if (tid < 2) lcnt[tid] = 0;
  __syncthreads();

  int i = blockIdx.x * 256 + tid;
  bool surv = false; float v = 0.f; int bk = 0, p = 0;
  if (i < 2 * NBIG) {
    int x = i % HW; int y = (i / HW) % HW; int plane = i / NPIX;
    v = hm[i];
    float m = v;
#pragma unroll
    for (int dy = -1; dy <= 1; ++dy)
#pragma unroll
      for (int dx = -1; dx <= 1; ++dx) {
        int yy = y + dy, xx = x + dx;
        if ((unsigned)yy < (unsigned)HW && (unsigned)xx < (unsigned)HW)
          m = fmaxf(m, hm[((size_t)plane * NPIX) + yy * HW + xx]);
      }
    if (v == m) {
      surv = true;
      bk = i / NBIG;
      p = atomicAdd(&lcnt[bk], 1);
    }
  }
  __syncthreads();
  if (tid < 2 && lcnt[tid] > 0)
    lbase[tid] = atomicAdd(&cnt[tid], lcnt[tid]);
  __syncthreads();
  if (surv) {
    int slot = lbase[bk] + p;
    ckey[(size_t)bk * NBIG + slot] = v;
    cidx[(size_t)bk * NBIG + slot] = i - bk * NBIG;
  }
}

__global__ __launch_bounds__(1024)
void topk_kernel(const float* __restrict__ ckey, const int* __restrict__ cidx,
                 const int* __restrict__ cnt, const float* __restrict__ heatmap,
                 const float* __restrict__ bev_pos, float* __restrict__ out,
                 int* __restrict__ iws) {
  const int b = blockIdx.x;
  const int tid = threadIdx.x;
  const float* keys = ckey + (size_t)b * NBIG;
  const int* idxs = cidx + (size_t)b * NBIG;

  __shared__ unsigned hist[256];
  __shared__ unsigned sh_prefix;
  __shared__ int sh_want, sh_n;
  __shared__ int cntGT, cntTie;
  __shared__ unsigned gt_key[256], gt_idx[256];
  __shared__ unsigned tie_idx[2048];

  if (tid == 0) sh_n = cnt[b];
  __syncthreads();
  const int n = sh_n;

  unsigned prefix = 0; int want = NPROP;
  for (int shift = 24; shift >= 0; shift -= 8) {
    if (tid < 256) hist[tid] = 0u;
    __syncthreads();
    for (int i = tid; i < n; i += 1024) {
      unsigned k = __float_as_uint(keys[i]);
      bool match = (shift == 24) || ((k >> (shift + 8)) == (prefix >> (shift + 8)));
      if (match) atomicAdd(&hist[(k >> shift) & 255], 1u);
    }
    __syncthreads();
    if (tid == 0) {
      int cum = 0; int bsel = 0; sh_want = want;
      for (int bin = 255; bin >= 0; --bin) {
        cum += (int)hist[bin];
        if (cum >= want) { bsel = bin; sh_want = want - (cum - (int)hist[bin]); break; }
      }
      sh_prefix = prefix | ((unsigned)bsel << shift);
      cntGT = 0; cntTie = 0;
    }
    __syncthreads();
    prefix = sh_prefix; want = sh_want;
    __syncthreads();
  }
  const unsigned T = prefix;

  for (int i = tid; i < n; i += 1024) {
    unsigned k = __float_as_uint(keys[i]);
    if (k > T) {
      int p = atomicAdd(&cntGT, 1);
      if (p < 256) { gt_key[p] = k; gt_idx[p] = (unsigned)idxs[i]; }
    } else if (k == T) {
      int p = atomicAdd(&cntTie, 1);
      if (p < 2048) tie_idx[p] = (unsigned)idxs[i];
    }
  }
  __syncthreads();
  const int nGT = min(cntGT, 256);
  const int nTie = min(cntTie, 2048);

  for (int i = tid; i < 256; i += 1024)
    if (i >= nGT) { gt_key[i] = 0u; gt_idx[i] = 0xFFFFFFFFu; }
  for (int i = tid; i < 2048; i += 1024)
    if (i >= nTie) tie_idx[i] = 0xFFFFFFFFu;
  __syncthreads();

  for (int k2 = 2; k2 <= 256; k2 <<= 1) {
    for (int j = k2 >> 1; j > 0; j >>= 1) {
      for (int i = tid; i < 256; i += 1024) {
        int ixj = i ^ j;
        if (ixj > i) {
          unsigned ka = gt_key[i], kb = gt_key[ixj];
          unsigned ia = gt_idx[i], ib = gt_idx[ixj];
          bool firstA = (ka > kb) || (ka == kb && ia < ib);
          bool up = ((i & k2) == 0);
          if (up ? !firstA : firstA) {
            gt_key[i] = kb; gt_key[ixj] = ka;
            gt_idx[i] = ib; gt_idx[ixj] = ia;
          }
        }
      }
      __syncthreads();
    }
  }
  for (int k2 = 2; k2 <= 2048; k2 <<= 1) {
    for (int j = k2 >> 1; j > 0; j >>= 1) {
      for (int i = tid; i < 2048; i += 1024) {
        int ixj = i ^ j;
        if (ixj > i) {
          unsigned ia = tie_idx[i], ib = tie_idx[ixj];
          bool firstA = ia < ib;
          bool up = ((i & k2) == 0);
          if (up ? !firstA : firstA) { tie_idx[i] = ib; tie_idx[ixj] = ia; }
        }
      }
      __syncthreads();
    }
  }

  for (int r = tid; r < NPROP; r += 1024) {
    unsigned idx; float score;
    if (r < nGT) { idx = gt_idx[r]; score = __uint_as_float(gt_key[r]); }
    else         { idx = tie_idx[r - nGT]; score = __uint_as_float(T); }
    int label = (int)(idx / NPIX);
    int pos = (int)(idx - (unsigned)label * NPIX);
    out[648000 + b * NPROP + r] = score;
    out[648400 + b * NPROP + r] = (float)label;
    out[700000 + (b * NPROP + r) * 2 + 0] = bev_pos[pos * 2 + 0];
    out[700000 + (b * NPROP + r) * 2 + 1] = bev_pos[pos * 2 + 1];
#pragma unroll
    for (int k = 0; k < NCLS; ++k)
      out[700800 + (b * NCLS + k) * NPROP + r] = heatmap[(size_t)(b * NCLS + k) * NPIX + pos];
    iws[b * NPROP + r] = pos;
    iws[2 * NPROP + b * NPROP + r] = label;
  }
}

// lidar is NHWC-chunked fp32: [b][4][px][32]
__global__ void gather_qf_kernel(const float* __restrict__ lidar, const float* __restrict__ w_enc,
                                 const int* __restrict__ iws, float* __restrict__ out_qf) {
  int p = blockIdx.x % NPROP;
  int b = blockIdx.x / NPROP;
  int c = threadIdx.x;
  int pos = iws[b * NPROP + p];
  int label = iws[2 * NPROP + b * NPROP + p];
  float la0 = logf(c_anchors[label][0]);
  float la1 = logf(c_anchors[label][1]);
  float la2 = logf(c_anchors[label][2]);
  float dot = w_enc[c * 3 + 0] * la0 + w_enc[c * 3 + 1] * la1 + w_enc[c * 3 + 2] * la2;
  float g = lidar[((size_t)(b * 4 + (c >> 5)) * NPIX + pos) * 32 + (c & 31)];
  out_qf[((size_t)b * HID + c) * NPROP + p] = g + dot;
}

extern "C" void kernel_launch(void* const* d_in, const int* in_sizes, int n_in,
                              void* d_out, int out_size, void* d_ws, size_t ws_size,
                              hipStream_t stream) {
  (void)in_sizes; (void)n_in; (void)out_size; (void)ws_size;
  const float* feats       = (const float*)d_in[0];
  const float* w_shared    = (const float*)d_in[1];
  const float* b_shared    = (const float*)d_in[2];
  const float* w_bb        = (const float*)d_in[3];
  const float* gamma_bb    = (const float*)d_in[4];
  const float* beta_bb     = (const float*)d_in[5];
  const float* w_hm        = (const float*)d_in[6];
  const float* b_hm        = (const float*)d_in[7];
  const float* thr_scale   = (const float*)d_in[8];
  const float* logit_scale = (const float*)d_in[9];
  const float* logit_bias  = (const float*)d_in[10];
  const float* w_enc       = (const float*)d_in[11];
  const float* anchor_vecs = (const float*)d_in[12];
  const float* bev_pos     = (const float*)d_in[13];
  float* out = (float*)d_out;

  float* ws = (float*)d_ws;
  size_t off = 0;
  _Float16* X1 = (_Float16*)(ws + off); off += 33177600;   // 2 planes x 33.18M f16
  _Float16* X2 = (_Float16*)(ws + off); off += 8294400;    // 2 planes x 8.29M f16
  float* lidarN = ws + off; off += 8294400;                // NHWC fp32
  _Float16* X3 = (_Float16*)(ws + off); off += 8294400;    // 2 planes x 8.29M f16
  _Float16* W1 = (_Float16*)(ws + off); off += 589824;     // 2h x 16ks x 36864 f16
  _Float16* W2 = (_Float16*)(ws + off); off += 147456;     // 2h x 4ks  x 36864 f16
  _Float16* W3 = (_Float16*)(ws + off); off += 73728;      // 1h x 4ks  x 36864 f16
  float* ckey  = ws + off; off += (size_t)2 * NBIG;
  int*   cidx  = (int*)(ws + off); off += (size_t)2 * NBIG;
  int*   iws   = (int*)(ws + off); off += 800;
  int*   cnt   = (int*)(ws + off);

  transpose_w_mfma<512,16,2><<<(2*16*36864 + 255)/256, 256, 0, stream>>>(w_shared, W1, 128);
  transpose_w_mfma<128, 4,2><<<(2*4*36864  + 255)/256, 256, 0, stream>>>(w_bb, W2, 128);
  transpose_w_mfma<128, 4,1><<<(1*4*36864  + 255)/256, 256, 0, stream>>>(w_hm, W3, 60);
  convert_feats<<<dim3(127, 32), 256, 0, stream>>>(feats, X1);

  const unsigned CONV_LDS = (25344 + 12288) * sizeof(_Float16);        // 75264 B
  const unsigned HEAD_LDS = CONV_LDS + 600 * sizeof(float);            // 77664 B
  dim3 cgrid(12, 9, 4);    // x-tiles(16), y-tiles(20), b*half -> 432 blocks
  conv_mfma<16,0><<<cgrid, 256, CONV_LDS, stream>>>(X1, W1, b_shared, nullptr, lidarN, X2,
                                                    nullptr, nullptr, nullptr, nullptr);
  conv_mfma<4, 1><<<cgrid, 256, CONV_LDS, stream>>>(X2, W2, gamma_bb, beta_bb, nullptr, X3,
                                                    nullptr, nullptr, nullptr, nullptr);
  dim3 hgrid(12, 9, 2);    // 216 blocks
  conv_mfma<4, 2><<<hgrid, 256, HEAD_LDS, stream>>>(X3, W3, b_hm, nullptr, out, nullptr,
                                                    thr_scale, logit_scale, logit_bias,
                                                    anchor_vecs);

  sims_kernel<<<1, 128, 0, stream>>>(out + 704800);
  hipMemsetAsync(cnt, 0, 2 * sizeof(int), stream);
  nms_kernel<<<(2*NBIG + 255)/256, 256, 0, stream>>>(out, ckey, cidx, cnt);
  topk_kernel<<<2, 1024, 0, stream>>>(ckey, cidx, cnt, out, bev_pos, out, iws);
  gather_qf_kernel<<<2*NPROP, 128, 0, stream>>>(lidarN, w_enc, iws, out + 648800);
}

// Round 14
// 519.816 us; speedup vs baseline: 6.3819x; 1.0370x over previous
//
#include <hip/hip_runtime.h>
#include <math.h>

// TransFusionHead anchor matching — round 14.
// r13 calibration: t = floor/(inner x fill); inner loss = vmcnt(0) drains
// (X ~600-900cy + 3x W ~250cy vs 2619cy MFMA), fill = 432/512.
// r14: tile 16x12 (15 y-tiles exact, 720 blocks) + W-group LDS double-buffer
// (W drains issued one compute-phase early -> off critical path, 4 bars/ks).
// LDS 81408 B = 2 blocks/CU. Prep kernels merged into one.

#define HW 180
#define NPIX 32400
#define NCLS 10
#define NPROP 200
#define HID 128
#define TDIM 60
#define NBIG (NCLS*NPIX)

#define TH_LO  (-0.9915981193)
#define TH_STEP (0.1789675812)

__constant__ float c_anchors[10][3] = {
  {4.63f,1.97f,1.74f},{6.93f,2.51f,2.84f},{6.37f,2.85f,3.19f},{10.5f,2.94f,3.47f},
  {12.29f,2.9f,3.87f},{0.5f,2.53f,0.98f},{2.11f,0.77f,1.47f},{1.7f,0.6f,1.28f},
  {0.73f,0.67f,1.77f},{0.41f,0.41f,1.07f}};

using f16x8 = _Float16 __attribute__((ext_vector_type(8)));
using f16x4 = _Float16 __attribute__((ext_vector_type(4)));
using f32x4 = float    __attribute__((ext_vector_type(4)));

#define GLD_LDS16(g, l) __builtin_amdgcn_global_load_lds( \
    (__attribute__((address_space(1))) void*)(g), \
    (__attribute__((address_space(3))) void*)(l), 16, 0, 0)

// ---------- merged prep ----------
// W prepack layout: [h][ks][plane][tsl][mf][lane][8], tsl kx-major (tsl=kx*3+ky).
__device__ __forceinline__ void w_tr(const float* __restrict__ w, _Float16* __restrict__ dst,
                                     int CIN, int KS, int HALVES, int cout, int i) {
  int N = HALVES * KS * 36864;
  if (i >= N) return;
  int j = i & 7;
  int lane = (i >> 3) & 63;
  int mf = (i >> 9) & 3;
  int rest = i >> 11;
  int tsl = rest % 9; rest /= 9;
  int t = (tsl % 3) * 3 + (tsl / 3);
  int plane = rest & 1; rest >>= 1;
  int ks = rest % KS; int h = rest / KS;
  int co = h * 64 + mf * 16 + (lane & 15);
  int ch = ks * 32 + (lane >> 4) * 8 + j;
  float v = (co < cout) ? w[((size_t)co * CIN + ch) * 9 + t] : 0.f;
  _Float16 hi = (_Float16)v;
  dst[i] = plane ? (_Float16)(v - (float)hi) : hi;
}

__global__ __launch_bounds__(256)
void prep_kernel(const float* __restrict__ w_shared, const float* __restrict__ w_bb,
                 const float* __restrict__ w_hm, const float* __restrict__ feats,
                 _Float16* __restrict__ W1, _Float16* __restrict__ W2,
                 _Float16* __restrict__ W3, _Float16* __restrict__ X1,
                 float* __restrict__ out_sims, int* __restrict__ cnt) {
  int bid = blockIdx.x;
  const int tid = threadIdx.x;
  if (bid < 4608) { w_tr(w_shared, W1, 512, 16, 2, 128, bid * 256 + tid); return; }
  bid -= 4608;
  if (bid < 1152) { w_tr(w_bb, W2, 128, 4, 2, 128, bid * 256 + tid); return; }
  bid -= 1152;
  if (bid < 576)  { w_tr(w_hm, W3, 128, 4, 1, 60, bid * 256 + tid); return; }
  bid -= 576;
  if (bid < 4064) {
    // feats fp32 NCHW -> X1 hi/lo f16 [b][16ks][px][32]
    int px = (bid % 127) * 256 + tid;
    int bks = bid / 127; int b = bks >> 4; int ks = bks & 15;
    if (px >= NPIX) return;
    const float* src = feats + ((size_t)(b * 512 + ks * 32)) * NPIX + px;
    float v[32];
#pragma unroll
    for (int c = 0; c < 32; ++c) v[c] = src[(size_t)c * NPIX];
    f16x8 hv[4], lv[4];
#pragma unroll
    for (int c = 0; c < 32; ++c) {
      _Float16 h = (_Float16)v[c];
      hv[c >> 3][c & 7] = h;
      lv[c >> 3][c & 7] = (_Float16)(v[c] - (float)h);
    }
    size_t ob = ((size_t)(b * 16 + ks) * NPIX + px) * 32;
#pragma unroll
    for (int i = 0; i < 4; ++i) {
      *(f16x8*)(X1 + ob + i * 8) = hv[i];
      *(f16x8*)(X1 + 33177600u + ob + i * 8) = lv[i];
    }
    return;
  }
  // last block: anchor IoU sims + counter zeroing
  if (tid < 100) {
    int i = tid / 10, j = tid % 10;
    float r = 1.f;
#pragma unroll
    for (int d = 0; d < 3; ++d) {
      float ai = c_anchors[i][d], aj = c_anchors[j][d];
      r *= fminf(ai, aj) / fmaxf(ai, aj);
    }
    out_sims[tid] = r;
  }
  if (tid == 128) { cnt[0] = 0; cnt[1] = 0; }
}

// ---------- split-fp16 MFMA conv3x3, tile 16x12 px x 64 co ----------
// LDS (f16 units): X [0,16128) = 14x18x32 x2pl; wA +16128 (12288); wB +28416
// (12288, EPI<2 only). EPI=2: anchors at +28416 (600 f32).
// DBUF pipeline per ks: bar | X+Wg0->A | bar | g1->B, comp g0(A) | bar |
// g2->A, comp g1(B) | bar | comp g2(A).
template<int KS, int EPI>
__global__ __launch_bounds__(256, 2)
void conv_mfma(const _Float16* __restrict__ X, const _Float16* __restrict__ W,
               const float* __restrict__ p0, const float* __restrict__ p1,
               float* __restrict__ out0, _Float16* __restrict__ outX,
               const float* __restrict__ thr_scale, const float* __restrict__ logit_scale,
               const float* __restrict__ logit_bias, const float* __restrict__ anchor_vecs) {
  constexpr unsigned XPS = 2u * KS * NPIX * 32;   // f16 per activation plane
  constexpr bool DBUF = (EPI != 2);
  extern __shared__ _Float16 dlds[];
  _Float16* lds_x = dlds;
  _Float16* wA = dlds + 16128;
  _Float16* wB = dlds + 28416;
  float* lds_av = (float*)(dlds + 28416);

  const int x0 = blockIdx.x * 16;
  const int y0 = blockIdx.y * 12;
  const int b  = (EPI == 2) ? blockIdx.z : (blockIdx.z >> 1);
  const int h  = (EPI == 2) ? 0 : (blockIdx.z & 1);
  const int tid = threadIdx.x;
  const int wave = tid >> 6;
  const int lane = tid & 63;
  const int xl = lane & 15, kg = lane >> 4;

  // zero X region + stage anchors (first barrier orders these vs DMA)
  {
    unsigned* p = (unsigned*)lds_x;
    for (int i = tid; i < 8064; i += 256) p[i] = 0u;
    if (EPI == 2)
      for (int i = tid; i < 600; i += 256) lds_av[i] = anchor_vecs[i];
  }

  // X staging: 2016 16B-chunks (hi 1008 + lo 1008), 32 wave-insts, 8/wave.
  unsigned offs[8]; unsigned okb = 0;
#pragma unroll
  for (int s = 0; s < 8; ++s) {
    int inst = wave + 4 * s;
    int c = inst * 64 + lane;
    bool valid = (c < 2016);
    int plane = (c >= 1008) ? 1 : 0;
    int cc = c - plane * 1008;
    int px = cc >> 2, q = cc & 3;
    int r = px / 18, xx = px - r * 18;
    int gy = y0 - 1 + r, gx = x0 - 1 + xx;
    bool ok = valid && ((unsigned)gy < 180u) && ((unsigned)gx < 180u);
    offs[s] = ok ? ((unsigned)((b * KS) * NPIX + gy * 180 + gx) * 32u + (unsigned)q * 8u
                    + (unsigned)plane * XPS) : 0u;
    okb |= (ok ? 1u : 0u) << s;
  }

  f32x4 acc[4][3];
#pragma unroll
  for (int mf = 0; mf < 4; ++mf)
#pragma unroll
    for (int f = 0; f < 3; ++f) acc[mf][f] = (f32x4){0.f, 0.f, 0.f, 0.f};

  // one tap-group (3 kys) of MFMA from wbuf, B-frags hoisted per group
  auto COMPUTE = [&](int g, const _Float16* wbuf) {
    f16x8 bfh[5], bfl[5];
#pragma unroll
    for (int rr = 0; rr < 5; ++rr) {
      int lo = ((3 * wave + rr) * 18 + xl + g) * 32 + kg * 8;
      bfh[rr] = *(const f16x8*)(lds_x + lo);
      bfl[rr] = *(const f16x8*)(lds_x + 8064 + lo);
    }
#pragma unroll
    for (int ky = 0; ky < 3; ++ky) {
      const _Float16* wt = wbuf + ky * 2048 + lane * 8;
      f16x8 ah[4], al[4];
#pragma unroll
      for (int mf = 0; mf < 4; ++mf) {
        ah[mf] = *(const f16x8*)(wt + mf * 512);
        al[mf] = *(const f16x8*)(wt + 6144 + mf * 512);
      }
#pragma unroll
      for (int mf = 0; mf < 4; ++mf)
#pragma unroll
        for (int f = 0; f < 3; ++f) {
          acc[mf][f] = __builtin_amdgcn_mfma_f32_16x16x32_f16(ah[mf], bfh[f + ky], acc[mf][f], 0, 0, 0);
          acc[mf][f] = __builtin_amdgcn_mfma_f32_16x16x32_f16(ah[mf], bfl[f + ky], acc[mf][f], 0, 0, 0);
          acc[mf][f] = __builtin_amdgcn_mfma_f32_16x16x32_f16(al[mf], bfh[f + ky], acc[mf][f], 0, 0, 0);
        }
    }
  };
  auto WDMA = [&](const _Float16* gw, int g, _Float16* wbuf) {
#pragma unroll
    for (int s = 0; s < 6; ++s) {
      int c2 = wave + 4 * s;             // 0..23
      int pl = c2 / 12, idx = c2 - pl * 12;
      GLD_LDS16(gw + pl * 18432 + g * 6144 + idx * 512 + lane * 8,
                wbuf + pl * 6144 + idx * 512);
    }
  };
  auto XDMA = [&](unsigned kof) {
#pragma unroll
    for (int s = 0; s < 8; ++s) {
      if (okb & (1u << s))
        GLD_LDS16(X + (size_t)(offs[s] + kof), lds_x + (wave + 4 * s) * 512);
    }
  };

  const _Float16* gwb = W + (size_t)(h * KS) * 36864;
  for (int ks = 0; ks < KS; ++ks) {
    const unsigned kof = (unsigned)ks * (NPIX * 32u);
    const _Float16* gw = gwb + (size_t)ks * 36864;
    if (DBUF) {
      __syncthreads();            // prev ks g2 compute done: X, wA free
      XDMA(kof);
      WDMA(gw, 0, wA);
      __syncthreads();            // X + g0 ready (X drain exposed)
      WDMA(gw, 1, wB);            // lands during g0 compute
      COMPUTE(0, wA);
      __syncthreads();            // g1 ready; g0 reads of wA done
      WDMA(gw, 2, wA);            // lands during g1 compute
      COMPUTE(1, wB);
      __syncthreads();            // g2 ready; g1 reads of wB done
      COMPUTE(2, wA);
    } else {
#pragma unroll
      for (int g = 0; g < 3; ++g) {
        __syncthreads();
        if (g == 0) XDMA(kof);
        WDMA(gw, g, wA);
        __syncthreads();
        COMPUTE(g, wA);
      }
    }
  }

  // ---- epilogue: C frag col=lane&15 (pixel x), row=kg*4+r (cout) ----
  const int x = x0 + xl;
  if (EPI != 2) {
    if (x >= HW) return;
#pragma unroll
    for (int mf = 0; mf < 4; ++mf) {
      const int cobase = h * 64 + mf * 16 + kg * 4;
      f32x4 q0 = *(const f32x4*)(p0 + cobase);
      f32x4 q1 = (EPI == 1) ? *(const f32x4*)(p1 + cobase) : (f32x4){0.f,0.f,0.f,0.f};
#pragma unroll
      for (int f = 0; f < 3; ++f) {
        const int y = y0 + 3 * wave + f;     // always < 180 (exact tiling)
        const int kso = cobase >> 5, c32 = cobase & 31;
        size_t nidx = ((size_t)(b * 4 + kso) * NPIX + (size_t)y * 180 + x) * 32 + c32;
        if (EPI == 0) {
          f32x4 v;
          f16x4 h4, l4;
#pragma unroll
          for (int r = 0; r < 4; ++r) {
            float z = acc[mf][f][r] + q0[r];
            v[r] = z;
            _Float16 hh = (_Float16)z;
            h4[r] = hh;
            l4[r] = (_Float16)(z - (float)hh);
          }
          *(f32x4*)(out0 + nidx) = v;
          *(f16x4*)(outX + nidx) = h4;
          *(f16x4*)(outX + 8294400u + nidx) = l4;
        } else {
          f16x4 h4, l4;
#pragma unroll
          for (int r = 0; r < 4; ++r) {
            float z = fmaf(acc[mf][f][r], q0[r], q1[r]);
            z = fmaxf(z, 0.f);
            _Float16 hh = (_Float16)z;
            h4[r] = hh;
            l4[r] = (_Float16)(z - (float)hh);
          }
          *(f16x4*)(outX + nidx) = h4;
          *(f16x4*)(outX + 8294400u + nidx) = l4;
        }
      }
    }
  } else {
    // ---- fused head: threshold-sigmoid, L2 norm, anchor sim, sigmoid ----
    const float s  = thr_scale[0];
    const float ls = logit_scale[0];
    const float lb = logit_bias[0];
    float bh4[4][4], th4[4][4];
    bool vmask[4];
#pragma unroll
    for (int mf = 0; mf < 4; ++mf) {
      const int cb = mf * 16 + kg * 4;
      vmask[mf] = (cb < TDIM);
#pragma unroll
      for (int r = 0; r < 4; ++r) {
        bh4[mf][r] = vmask[mf] ? p0[cb + r] : 0.f;
        th4[mf][r] = (float)(TH_LO + (double)((cb + r) % 20) * TH_STEP);
      }
    }
#pragma unroll
    for (int f = 0; f < 3; ++f) {
      const int y = y0 + 3 * wave + f;
      float v[4][4];
      float s2 = 0.f;
#pragma unroll
      for (int mf = 0; mf < 4; ++mf)
#pragma unroll
        for (int r = 0; r < 4; ++r) {
          float z = acc[mf][f][r] + bh4[mf][r];
          float t = (z - th4[mf][r]) * s;
          float vv = vmask[mf] ? 1.f / (1.f + expf(-t)) : 0.f;
          v[mf][r] = vv;
          s2 = fmaf(vv, vv, s2);
        }
      s2 += __shfl_xor(s2, 16);
      s2 += __shfl_xor(s2, 32);
      const float rs = 1.f / (1e-8f + sqrtf(s2));
      float hm[10];
#pragma unroll
      for (int k = 0; k < 10; ++k) {
        float d = 0.f;
#pragma unroll
        for (int mf = 0; mf < 4; ++mf) {
          const int cb = mf * 16 + kg * 4;
          f32x4 a = vmask[mf] ? *(const f32x4*)(lds_av + k * TDIM + cb)
                              : (f32x4){0.f, 0.f, 0.f, 0.f};
#pragma unroll
          for (int r = 0; r < 4; ++r) d = fmaf(v[mf][r], a[r], d);
        }
        d += __shfl_xor(d, 16);
        d += __shfl_xor(d, 32);
        hm[k] = 1.f / (1.f + expf(-fmaf(ls, d * rs, lb)));
      }
      if (x < HW) {
#pragma unroll
        for (int j = 0; j < 3; ++j) {
          int k = kg + 4 * j;
          if (k < NCLS)
            out0[((size_t)(b * NCLS + k) * HW + y) * HW + x] = hm[k];
        }
      }
    }
  }
}

// NMS + two-level compaction (LDS atomics, <=2 global atomics per block).
__global__ __launch_bounds__(256)
void nms_kernel(const float* __restrict__ hm, float* __restrict__ ckey,
                int* __restrict__ cidx, int* __restrict__ cnt) {
  __shared__ int lcnt[2];
  __shared__ int lbase[2];
  const int tid = threadIdx.x;
  if (tid < 2) lcnt[tid] = 0;
  __syncthreads();

  int i = blockIdx.x * 256 + tid;
  bool surv = false; float v = 0.f; int bk = 0, p = 0;
  if (i < 2 * NBIG) {
    int x = i % HW; int y = (i / HW) % HW; int plane = i / NPIX;
    v = hm[i];
    float m = v;
#pragma unroll
    for (int dy = -1; dy <= 1; ++dy)
#pragma unroll
      for (int dx = -1; dx <= 1; ++dx) {
        int yy = y + dy, xx = x + dx;
        if ((unsigned)yy < (unsigned)HW && (unsigned)xx < (unsigned)HW)
          m = fmaxf(m, hm[((size_t)plane * NPIX) + yy * HW + xx]);
      }
    if (v == m) {
      surv = true;
      bk = i / NBIG;
      p = atomicAdd(&lcnt[bk], 1);
    }
  }
  __syncthreads();
  if (tid < 2 && lcnt[tid] > 0)
    lbase[tid] = atomicAdd(&cnt[tid], lcnt[tid]);
  __syncthreads();
  if (surv) {
    int slot = lbase[bk] + p;
    ckey[(size_t)bk * NBIG + slot] = v;
    cidx[(size_t)bk * NBIG + slot] = i - bk * NBIG;
  }
}

__global__ __launch_bounds__(1024)
void topk_kernel(const float* __restrict__ ckey, const int* __restrict__ cidx,
                 const int* __restrict__ cnt, const float* __restrict__ heatmap,
                 const float* __restrict__ bev_pos, float* __restrict__ out,
                 int* __restrict__ iws) {
  const int b = blockIdx.x;
  const int tid = threadIdx.x;
  const float* keys = ckey + (size_t)b * NBIG;
  const int* idxs = cidx + (size_t)b * NBIG;

  __shared__ unsigned hist[256];
  __shared__ unsigned sh_prefix;
  __shared__ int sh_want, sh_n;
  __shared__ int cntGT, cntTie;
  __shared__ unsigned gt_key[256], gt_idx[256];
  __shared__ unsigned tie_idx[2048];

  if (tid == 0) sh_n = cnt[b];
  __syncthreads();
  const int n = sh_n;

  unsigned prefix = 0; int want = NPROP;
  for (int shift = 24; shift >= 0; shift -= 8) {
    if (tid < 256) hist[tid] = 0u;
    __syncthreads();
    for (int i = tid; i < n; i += 1024) {
      unsigned k = __float_as_uint(keys[i]);
      bool match = (shift == 24) || ((k >> (shift + 8)) == (prefix >> (shift + 8)));
      if (match) atomicAdd(&hist[(k >> shift) & 255], 1u);
    }
    __syncthreads();
    if (tid == 0) {
      int cum = 0; int bsel = 0; sh_want = want;
      for (int bin = 255; bin >= 0; --bin) {
        cum += (int)hist[bin];
        if (cum >= want) { bsel = bin; sh_want = want - (cum - (int)hist[bin]); break; }
      }
      sh_prefix = prefix | ((unsigned)bsel << shift);
      cntGT = 0; cntTie = 0;
    }
    __syncthreads();
    prefix = sh_prefix; want = sh_want;
    __syncthreads();
  }
  const unsigned T = prefix;

  for (int i = tid; i < n; i += 1024) {
    unsigned k = __float_as_uint(keys[i]);
    if (k > T) {
      int p = atomicAdd(&cntGT, 1);
      if (p < 256) { gt_key[p] = k; gt_idx[p] = (unsigned)idxs[i]; }
    } else if (k == T) {
      int p = atomicAdd(&cntTie, 1);
      if (p < 2048) tie_idx[p] = (unsigned)idxs[i];
    }
  }
  __syncthreads();
  const int nGT = min(cntGT, 256);
  const int nTie = min(cntTie, 2048);

  for (int i = tid; i < 256; i += 1024)
    if (i >= nGT) { gt_key[i] = 0u; gt_idx[i] = 0xFFFFFFFFu; }
  for (int i = tid; i < 2048; i += 1024)
    if (i >= nTie) tie_idx[i] = 0xFFFFFFFFu;
  __syncthreads();

  for (int k2 = 2; k2 <= 256; k2 <<= 1) {
    for (int j = k2 >> 1; j > 0; j >>= 1) {
      for (int i = tid; i < 256; i += 1024) {
        int ixj = i ^ j;
        if (ixj > i) {
          unsigned ka = gt_key[i], kb = gt_key[ixj];
          unsigned ia = gt_idx[i], ib = gt_idx[ixj];
          bool firstA = (ka > kb) || (ka == kb && ia < ib);
          bool up = ((i & k2) == 0);
          if (up ? !firstA : firstA) {
            gt_key[i] = kb; gt_key[ixj] = ka;
            gt_idx[i] = ib; gt_idx[ixj] = ia;
          }
        }
      }
      __syncthreads();
    }
  }
  for (int k2 = 2; k2 <= 2048; k2 <<= 1) {
    for (int j = k2 >> 1; j > 0; j >>= 1) {
      for (int i = tid; i < 2048; i += 1024) {
        int ixj = i ^ j;
        if (ixj > i) {
          unsigned ia = tie_idx[i], ib = tie_idx[ixj];
          bool firstA = ia < ib;
          bool up = ((i & k2) == 0);
          if (up ? !firstA : firstA) { tie_idx[i] = ib; tie_idx[ixj] = ia; }
        }
      }
      __syncthreads();
    }
  }

  for (int r = tid; r < NPROP; r += 1024) {
    unsigned idx; float score;
    if (r < nGT) { idx = gt_idx[r]; score = __uint_as_float(gt_key[r]); }
    else         { idx = tie_idx[r - nGT]; score = __uint_as_float(T); }
    int label = (int)(idx / NPIX);
    int pos = (int)(idx - (unsigned)label * NPIX);
    out[648000 + b * NPROP + r] = score;
    out[648400 + b * NPROP + r] = (float)label;
    out[700000 + (b * NPROP + r) * 2 + 0] = bev_pos[pos * 2 + 0];
    out[700000 + (b * NPROP + r) * 2 + 1] = bev_pos[pos * 2 + 1];
#pragma unroll
    for (int k = 0; k < NCLS; ++k)
      out[700800 + (b * NCLS + k) * NPROP + r] = heatmap[(size_t)(b * NCLS + k) * NPIX + pos];
    iws[b * NPROP + r] = pos;
    iws[2 * NPROP + b * NPROP + r] = label;
  }
}

// lidar is NHWC-chunked fp32: [b][4][px][32]
__global__ void gather_qf_kernel(const float* __restrict__ lidar, const float* __restrict__ w_enc,
                                 const int* __restrict__ iws, float* __restrict__ out_qf) {
  int p = blockIdx.x % NPROP;
  int b = blockIdx.x / NPROP;
  int c = threadIdx.x;
  int pos = iws[b * NPROP + p];
  int label = iws[2 * NPROP + b * NPROP + p];
  float la0 = logf(c_anchors[label][0]);
  float la1 = logf(c_anchors[label][1]);
  float la2 = logf(c_anchors[label][2]);
  float dot = w_enc[c * 3 + 0] * la0 + w_enc[c * 3 + 1] * la1 + w_enc[c * 3 + 2] * la2;
  float g = lidar[((size_t)(b * 4 + (c >> 5)) * NPIX + pos) * 32 + (c & 31)];
  out_qf[((size_t)b * HID + c) * NPROP + p] = g + dot;
}

extern "C" void kernel_launch(void* const* d_in, const int* in_sizes, int n_in,
                              void* d_out, int out_size, void* d_ws, size_t ws_size,
                              hipStream_t stream) {
  (void)in_sizes; (void)n_in; (void)out_size; (void)ws_size;
  const float* feats       = (const float*)d_in[0];
  const float* w_shared    = (const float*)d_in[1];
  const float* b_shared    = (const float*)d_in[2];
  const float* w_bb        = (const float*)d_in[3];
  const float* gamma_bb    = (const float*)d_in[4];
  const float* beta_bb     = (const float*)d_in[5];
  const float* w_hm        = (const float*)d_in[6];
  const float* b_hm        = (const float*)d_in[7];
  const float* thr_scale   = (const float*)d_in[8];
  const float* logit_scale = (const float*)d_in[9];
  const float* logit_bias  = (const float*)d_in[10];
  const float* w_enc       = (const float*)d_in[11];
  const float* anchor_vecs = (const float*)d_in[12];
  const float* bev_pos     = (const float*)d_in[13];
  float* out = (float*)d_out;

  float* ws = (float*)d_ws;
  size_t off = 0;
  _Float16* X1 = (_Float16*)(ws + off); off += 33177600;   // 2 planes x 33.18M f16
  _Float16* X2 = (_Float16*)(ws + off); off += 8294400;    // 2 planes x 8.29M f16
  float* lidarN = ws + off; off += 8294400;                // NHWC fp32
  _Float16* X3 = (_Float16*)(ws + off); off += 8294400;    // 2 planes x 8.29M f16
  _Float16* W1 = (_Float16*)(ws + off); off += 589824;     // 2h x 16ks x 36864 f16
  _Float16* W2 = (_Float16*)(ws + off); off += 147456;     // 2h x 4ks  x 36864 f16
  _Float16* W3 = (_Float16*)(ws + off); off += 73728;      // 1h x 4ks  x 36864 f16
  float* ckey  = ws + off; off += (size_t)2 * NBIG;
  int*   cidx  = (int*)(ws + off); off += (size_t)2 * NBIG;
  int*   iws   = (int*)(ws + off); off += 800;
  int*   cnt   = (int*)(ws + off);

  // merged prep: W1(4608) + W2(1152) + W3(576) + convert(4064) + sims/cnt(1)
  prep_kernel<<<10401, 256, 0, stream>>>(w_shared, w_bb, w_hm, feats,
                                         W1, W2, W3, X1, out + 704800, cnt);

  const unsigned CONV_LDS = 81408;   // X 32256 + 2x W-group 24576
  const unsigned HEAD_LDS = 59232;   // X 32256 + W-group 24576 + anchors 2400
  dim3 cgrid(12, 15, 4);   // x-tiles(16), y-tiles(12 exact), b*half -> 720
  conv_mfma<16,0><<<cgrid, 256, CONV_LDS, stream>>>(X1, W1, b_shared, nullptr, lidarN, X2,
                                                    nullptr, nullptr, nullptr, nullptr);
  conv_mfma<4, 1><<<cgrid, 256, CONV_LDS, stream>>>(X2, W2, gamma_bb, beta_bb, nullptr, X3,
                                                    nullptr, nullptr, nullptr, nullptr);
  dim3 hgrid(12, 15, 2);   // 360 blocks
  conv_mfma<4, 2><<<hgrid, 256, HEAD_LDS, stream>>>(X3, W3, b_hm, nullptr, out, nullptr,
                                                    thr_scale, logit_scale, logit_bias,
                                                    anchor_vecs);

  nms_kernel<<<(2*NBIG + 255)/256, 256, 0, stream>>>(out, ckey, cidx, cnt);
  topk_kernel<<<2, 1024, 0, stream>>>(ckey, cidx, cnt, out, bev_pos, out, iws);
  gather_qf_kernel<<<2*NPROP, 128, 0, stream>>>(lidarN, w_enc, iws, out + 648800);
}